// Round 4
// baseline (2788.375 us; speedup 1.0000x reference)
//
#include <hip/hip_runtime.h>

// ---------------------------------------------------------------------------
// VolumeAttention: 4 feature levels x 6 decoder depths, B=4, NQ=100, C=256, H=8
// Round 4:
//  - CA flash rewritten on MFMA (swapped S^T = K·Q^T, O^T = V^T·P^T), split-bf16
//  - KV projection writes split-bf16 KV directly; Q pre-scaled+split
//  - SA flash / small GEMMs unchanged
// ---------------------------------------------------------------------------

#define DI __device__ __forceinline__

typedef __attribute__((ext_vector_type(8))) short bf16x8;
typedef __attribute__((ext_vector_type(8))) unsigned short u16x8;
typedef __attribute__((ext_vector_type(4))) float f32x4;

// ws offsets in floats
constexpr long O_KVH   = 0;                        // [21760][512] ushort hi
constexpr long O_KVL   = O_KVH  + 5570560;         // [21760][512] ushort lo
constexpr long O_QBUF  = O_KVL  + 5570560;         // [1600][256] current q
constexpr long O_QKV   = O_QBUF + 409600;          // [1600][768]
constexpr long O_QSA   = O_QKV  + 1228800;         // [1600][256]
constexpr long O_QHAT  = O_QSA  + 409600;          // [1600][256]
constexpr long O_QN    = O_QHAT + 409600;          // [1600][256]
constexpr long O_SAO   = O_QN   + 409600;          // [1600][256]
constexpr long O_OCA   = O_SAO  + 409600;          // [2][1600][256]
constexpr long O_Q12   = O_OCA  + 819200;          // [2][1600][256]
constexpr long O_QH    = O_Q12  + 819200;          // [1616][256] ushort hi
constexpr long O_QL    = O_QH   + 206848;          // [1616][256] ushort lo
constexpr long O_WTH   = O_QL   + 206848;          // [6][512][256] ushort hi
constexpr long O_WTL   = O_WTH  + 393216;          // [6][512][256] ushort lo
constexpr long O_WQ    = O_WTL  + 393216;          // [6][256][256] fp32
constexpr long O_BKV   = O_WQ   + 393216;          // [6][512]
constexpr long O_BQ    = O_BKV  + 3072;            // [6][256]
constexpr long O_PO    = O_BQ   + 1536;            // [128][3200] SA partials
constexpr long O_PM    = O_PO   + 409600;          // [128][128]
constexpr long O_PL    = O_PM   + 16384;           // [128][128]
constexpr long O_PO2   = O_PL   + 16384;           // [2688][512] CA partials
constexpr long O_PM2   = O_PO2  + 1376256;         // [2688][16]
constexpr long O_PL2   = O_PM2  + 43008;           // [2688][16]
constexpr long O_MS    = O_PL2  + 43008;           // [16][128][128]
constexpr long O_RST   = O_MS   + 262144;          // [4][16][128]
constexpr long O_STATS = O_RST  + 8192;            // [43520][2]
constexpr long WS_FLOATS = O_STATS + 87040;        // ~79.7 MB

DI int sel4(int4 v, int i) { return i == 0 ? v.x : (i == 1 ? v.y : (i == 2 ? v.z : v.w)); }
DI float dot4(float4 a, float4 b) {
  float s = a.x * b.x;
  s = fmaf(a.y, b.y, s); s = fmaf(a.z, b.z, s); s = fmaf(a.w, b.w, s);
  return s;
}
DI unsigned short bf_rne(float x) {
  unsigned u = __float_as_uint(x);
  u += 0x7fffu + ((u >> 16) & 1u);
  return (unsigned short)(u >> 16);
}
DI float bf2f(unsigned short h) { return __uint_as_float(((unsigned)h) << 16); }

// --- fold LN affine into projections; KV weights -> transposed split-bf16 --
__global__ void fold_w2_kernel(const float* __restrict__ ng, const float* __restrict__ wk,
                               const float* __restrict__ wv, const float* __restrict__ wq,
                               unsigned short* __restrict__ WTh, unsigned short* __restrict__ WTl,
                               float* __restrict__ wqo) {
  long idx = (long)blockIdx.x * 256 + threadIdx.x;
  const long T1 = 6L * 512 * 256;
  if (idx < T1) {
    int d = idx / (512 * 256); int r = idx % (512 * 256); int n = r / 256; int k = r % 256;
    float g = ng[d * 256 + k];
    float w = (n < 256) ? wk[((long)(d * 256 + k)) * 256 + n]
                        : wv[((long)(d * 256 + k)) * 256 + (n - 256)];
    w *= g;
    unsigned short h = bf_rne(w);
    WTh[idx] = h;
    WTl[idx] = bf_rne(w - bf2f(h));
  } else {
    long j = idx - T1;
    if (j < 6L * 256 * 256) {
      int d = j / 65536; int r = j % 65536; int c = r / 256; int n = r % 256;
      wqo[j] = ng[d * 256 + c] * wq[((long)(d * 256 + c)) * 256 + n];
    }
  }
}

__global__ void fold_b_kernel(const float* __restrict__ nb, const float* __restrict__ wk,
                              const float* __restrict__ wv, const float* __restrict__ wq,
                              float* __restrict__ bkvo, float* __restrict__ bqo) {
  int idx = blockIdx.x * 256 + threadIdx.x;
  if (idx >= 6 * 768) return;
  int d = idx / 768, j = idx % 768;
  float s = 0.f;
  if (j < 256) {
    for (int c = 0; c < 256; ++c) s = fmaf(nb[d * 256 + c], wk[(d * 256 + c) * 256 + j], s);
    bkvo[d * 512 + j] = s;
  } else if (j < 512) {
    int n = j - 256;
    for (int c = 0; c < 256; ++c) s = fmaf(nb[d * 256 + c], wv[(d * 256 + c) * 256 + n], s);
    bkvo[d * 512 + j] = s;
  } else {
    int n = j - 512;
    for (int c = 0; c < 256; ++c) s = fmaf(nb[d * 256 + c], wq[(d * 256 + c) * 256 + n], s);
    bqo[d * 256 + n] = s;
  }
}

// --- per-token LN statistics of feature maps ------------------------------
__global__ __launch_bounds__(256) void ln_stats_kernel(const float* __restrict__ feat,
                                                       float* __restrict__ stats,
                                                       int rowBase, int HW) {
  __shared__ float sred[4][64];
  __shared__ float qred[4][64];
  int b = blockIdx.y, t0 = blockIdx.x * 64;
  int tx = threadIdx.x & 63, ty = threadIdx.x >> 6;
  const float* fb = feat + (long)b * 256 * HW;
  float s = 0.f, q = 0.f;
  for (int k = 0; k < 64; ++k) {
    int c = ty * 64 + k;
    float v = fb[(long)c * HW + t0 + tx];
    s += v; q += v * v;
  }
  sred[ty][tx] = s; qred[ty][tx] = q;
  __syncthreads();
  if (ty == 0) {
    float ts = sred[0][tx] + sred[1][tx] + sred[2][tx] + sred[3][tx];
    float tq = qred[0][tx] + qred[1][tx] + qred[2][tx] + qred[3][tx];
    float m = ts * (1.f / 256.f);
    float var = tq * (1.f / 256.f) - m * m;
    int row = rowBase + b * HW + t0 + tx;
    stats[row * 2 + 0] = m;
    stats[row * 2 + 1] = rsqrtf(var + 1e-5f);
  }
}

__global__ void init_q_kernel(const float* __restrict__ qe, float* __restrict__ qb) {
  int idx = blockIdx.x * 256 + threadIdx.x;
  if (idx < 1600 * 256) {
    int row = idx >> 8, c = idx & 255;
    qb[idx] = qe[(row % 100) * 256 + c];
  }
}

// --- split/scale Q for CA flash: Qh/Ql [1616][256], pad rows zeroed --------
__global__ void split_q_kernel(const float* __restrict__ qn,
                               unsigned short* __restrict__ Qh,
                               unsigned short* __restrict__ Ql) {
  int idx = blockIdx.x * 256 + threadIdx.x;
  if (idx >= 1616 * 256) return;
  float v = (idx < 1600 * 256) ? qn[idx] * 0.17677669529663689f : 0.f;
  unsigned short hi = bf_rne(v);
  Qh[idx] = hi;
  Ql[idx] = bf_rne(v - bf2f(hi));
}

// --- generic fp32 GEMM: C[M,N] = A[M,256] @ W[256,N] (+bias) --------------
__global__ __launch_bounds__(256) void gemm256_kernel(const float* __restrict__ A,
                                                      const float* __restrict__ W,
                                                      const float* __restrict__ bias,
                                                      float* __restrict__ Co, int M, int N) {
  __shared__ float As[32][68];
  __shared__ float Ws[32][68];
  int tid = threadIdx.x;
  int tm = tid & 15, tn = tid >> 4;
  int m0 = blockIdx.y * 64, n0 = blockIdx.x * 64;
  float acc[4][4] = {};
  for (int kt = 0; kt < 8; ++kt) {
    __syncthreads();
#pragma unroll
    for (int it = 0; it < 2; ++it) {
      int i = tid + it * 256;
      int r = i >> 3, c4 = (i & 7) * 4;
      float4 f = *(const float4*)&A[(long)(m0 + r) * 256 + kt * 32 + c4];
      As[c4 + 0][r] = f.x; As[c4 + 1][r] = f.y; As[c4 + 2][r] = f.z; As[c4 + 3][r] = f.w;
    }
#pragma unroll
    for (int it = 0; it < 2; ++it) {
      int i = tid + it * 256;
      int r = i >> 4, c4 = (i & 15) * 4;
      *(float4*)&Ws[r][c4] = *(const float4*)&W[(long)(kt * 32 + r) * N + n0 + c4];
    }
    __syncthreads();
#pragma unroll
    for (int k = 0; k < 32; ++k) {
      float4 a4 = *(const float4*)&As[k][4 * tm];
      float4 b4 = *(const float4*)&Ws[k][4 * tn];
      float av[4] = {a4.x, a4.y, a4.z, a4.w};
      float bv[4] = {b4.x, b4.y, b4.z, b4.w};
#pragma unroll
      for (int i = 0; i < 4; ++i)
#pragma unroll
        for (int j = 0; j < 4; ++j) acc[i][j] = fmaf(av[i], bv[j], acc[i][j]);
    }
  }
  float bv4[4] = {0.f, 0.f, 0.f, 0.f};
  if (bias) {
#pragma unroll
    for (int j = 0; j < 4; ++j) bv4[j] = bias[n0 + 4 * tn + j];
  }
#pragma unroll
  for (int i = 0; i < 4; ++i) {
    int row = m0 + 4 * tm + i;
    float4 o;
    o.x = acc[i][0] + bv4[0]; o.y = acc[i][1] + bv4[1];
    o.z = acc[i][2] + bv4[2]; o.w = acc[i][3] + bv4[3];
    *(float4*)&Co[(long)row * N + n0 + 4 * tn] = o;
  }
}

// --- KV projection via MFMA, split-bf16 in, split-bf16 OUT ------------------
__global__ __launch_bounds__(256) void gemm_kv_mfma_kernel(
    const float* __restrict__ f0, const float* __restrict__ f1,
    const float* __restrict__ f2, const float* __restrict__ f3,
    const float* __restrict__ stats, int vbase,
    const unsigned short* __restrict__ Wh, const unsigned short* __restrict__ Wl,
    const float* __restrict__ bias,
    unsigned short* __restrict__ KVh, unsigned short* __restrict__ KVl) {
  __shared__ unsigned short Ah[64][72], Al[64][72];   // [m][k] bf16, pad 8
  __shared__ unsigned short Bh[64][72], Bl[64][72];   // [n][k] bf16
  __shared__ float sm[64], sr[64];
  int tid = threadIdx.x;
  int m0 = blockIdx.y * 64, n0 = blockIdx.x * 64;
  const float* fp; int HW, rel;
  if (m0 < 16384)      { fp = f0; HW = 4096; rel = m0; }
  else if (m0 < 20480) { fp = f1; HW = 1024; rel = m0 - 16384; }
  else if (m0 < 21504) { fp = f2; HW = 256;  rel = m0 - 20480; }
  else                 { fp = f3; HW = 64;   rel = m0 - 21504; }
  int b = rel / HW, t0 = rel % HW;
  const float* fb = fp + (long)b * 256 * HW + t0;
  if (tid < 64) {
    sm[tid] = stats[(vbase + m0 + tid) * 2 + 0];
    sr[tid] = stats[(vbase + m0 + tid) * 2 + 1];
  }
  int wv = tid >> 6, lane = tid & 63;
  int fr = lane & 15;
  int kq = lane >> 4;
  f32x4 acc[4];
#pragma unroll
  for (int c = 0; c < 4; ++c)
#pragma unroll
    for (int r = 0; r < 4; ++r) acc[c][r] = 0.f;
  __syncthreads();
  for (int kc = 0; kc < 4; ++kc) {
    {
      float mean = sm[lane], rstd = sr[lane];
#pragma unroll
      for (int pass = 0; pass < 4; ++pass) {
        int k = pass * 16 + wv * 4;
        float xs[4];
#pragma unroll
        for (int i = 0; i < 4; ++i)
          xs[i] = (fb[(long)(kc * 64 + k + i) * HW + lane] - mean) * rstd;
        ushort4 uh, ul;
        uh.x = bf_rne(xs[0]); ul.x = bf_rne(xs[0] - bf2f(uh.x));
        uh.y = bf_rne(xs[1]); ul.y = bf_rne(xs[1] - bf2f(uh.y));
        uh.z = bf_rne(xs[2]); ul.z = bf_rne(xs[2] - bf2f(uh.z));
        uh.w = bf_rne(xs[3]); ul.w = bf_rne(xs[3] - bf2f(uh.w));
        *(ushort4*)&Ah[lane][k] = uh;
        *(ushort4*)&Al[lane][k] = ul;
      }
    }
    {
      int ks = (tid & 15) * 4;
#pragma unroll
      for (int pass = 0; pass < 4; ++pass) {
        int n = pass * 16 + (tid >> 4);
        long g = (long)(n0 + n) * 256 + kc * 64 + ks;
        *(ushort4*)&Bh[n][ks] = *(const ushort4*)&Wh[g];
        *(ushort4*)&Bl[n][ks] = *(const ushort4*)&Wl[g];
      }
    }
    __syncthreads();
#pragma unroll
    for (int s = 0; s < 2; ++s) {
      int k0 = s * 32 + kq * 8;
      bf16x8 a_h = *(const bf16x8*)&Ah[wv * 16 + fr][k0];
      bf16x8 a_l = *(const bf16x8*)&Al[wv * 16 + fr][k0];
#pragma unroll
      for (int c = 0; c < 4; ++c) {
        bf16x8 b_h = *(const bf16x8*)&Bh[c * 16 + fr][k0];
        bf16x8 b_l = *(const bf16x8*)&Bl[c * 16 + fr][k0];
        acc[c] = __builtin_amdgcn_mfma_f32_16x16x32_bf16(a_h, b_h, acc[c], 0, 0, 0);
        acc[c] = __builtin_amdgcn_mfma_f32_16x16x32_bf16(a_l, b_h, acc[c], 0, 0, 0);
        acc[c] = __builtin_amdgcn_mfma_f32_16x16x32_bf16(a_h, b_l, acc[c], 0, 0, 0);
      }
    }
    __syncthreads();
  }
  int row0 = m0 + wv * 16 + kq * 4;
#pragma unroll
  for (int c = 0; c < 4; ++c) {
    float bv = bias[n0 + c * 16 + fr];
#pragma unroll
    for (int r = 0; r < 4; ++r) {
      float val = acc[c][r] + bv;
      long off = (long)(row0 + r) * 512 + n0 + c * 16 + fr;
      unsigned short hi = bf_rne(val);
      KVh[off] = hi;
      KVl[off] = bf_rne(val - bf2f(hi));
    }
  }
}

// --- row LayerNorm (no affine) ---------------------------------------------
__global__ __launch_bounds__(256) void row_ln_kernel(const float* __restrict__ in,
                                                     float* __restrict__ out) {
  __shared__ float s1[4], s2[4];
  long r = blockIdx.x;
  float x = in[r * 256 + threadIdx.x];
  float vs = x, vq = x * x;
  for (int o = 32; o; o >>= 1) { vs += __shfl_xor(vs, o); vq += __shfl_xor(vq, o); }
  int w = threadIdx.x >> 6;
  if ((threadIdx.x & 63) == 0) { s1[w] = vs; s2[w] = vq; }
  __syncthreads();
  float ts = s1[0] + s1[1] + s1[2] + s1[3];
  float tq = s2[0] + s2[1] + s2[2] + s2[3];
  float m = ts * (1.f / 256.f);
  float var = tq * (1.f / 256.f) - m * m;
  out[r * 256 + threadIdx.x] = (x - m) * rsqrtf(var + 1e-5f);
}

// --- SA flash (VALU path, unchanged) ---------------------------------------
__global__ __launch_bounds__(256) void flash_kernel(const float* __restrict__ qp, int qld,
                                                    const float* __restrict__ kb,
                                                    const float* __restrict__ vb, int kvld,
                                                    int4 startv, int4 nchv, int4 nkv,
                                                    int4 koffv, int4 kstrbv,
                                                    float* __restrict__ po,
                                                    float* __restrict__ pm,
                                                    float* __restrict__ pl) {
  __shared__ float Kt[32][36];
  __shared__ float Vt[32][36];
  int bid = blockIdx.x;
  int s1 = startv.y, s2 = startv.z, s3 = startv.w;
  int l = (bid < s1) ? 0 : (bid < s2) ? 1 : (bid < s3) ? 2 : 3;
  int r = bid - sel4(startv, l);
  int nc = sel4(nchv, l);
  int b = r / (8 * nc);
  int h = (r / nc) & 7;
  int ch = r % nc;
  int Nk = sel4(nkv, l);
  int qr0 = (l * 4 + b) * 100;
  int kr0 = sel4(koffv, l) + b * sel4(kstrbv, l);
  int j0 = ch * 128;
  int jn = min(128, Nk - j0);
  int tiles = (jn + 31) >> 5;
  int tid = threadIdx.x;
  int qi = tid >> 1, half = tid & 1, ho = half * 16, jb = half * 16;
  const float SC = 0.17677669529663689f;
  float4 q8[8];
  if (qi < 100) {
    const float* qrow = qp + (long)(qr0 + qi) * qld + h * 32;
#pragma unroll
    for (int k = 0; k < 8; ++k) {
      float4 f = *(const float4*)&qrow[4 * k];
      q8[k] = make_float4(f.x * SC, f.y * SC, f.z * SC, f.w * SC);
    }
  } else {
#pragma unroll
    for (int k = 0; k < 8; ++k) q8[k] = make_float4(0.f, 0.f, 0.f, 0.f);
  }
  float m = -1e30f, lsum = 0.f;
  float o[16];
#pragma unroll
  for (int i = 0; i < 16; ++i) o[i] = 0.f;

  for (int kt = 0; kt < tiles; ++kt) {
    __syncthreads();
    {
      int rr = tid >> 3, c4 = (tid & 7) * 4;
      int jr = kt * 32 + rr;
      float4 kf = make_float4(0.f, 0.f, 0.f, 0.f), vf = kf;
      if (jr < jn) {
        long g = (long)(kr0 + j0 + jr) * kvld + h * 32 + c4;
        kf = *(const float4*)&kb[g];
        vf = *(const float4*)&vb[g];
      }
      *(float4*)&Kt[rr][c4 ^ (rr & 16)] = kf;
      *(float4*)&Vt[rr][c4] = vf;
    }
    __syncthreads();
    float sv[16];
#pragma unroll
    for (int j = 0; j < 16; ++j) {
      float s = 0.f;
#pragma unroll
      for (int k4 = 0; k4 < 8; ++k4) {
        float4 kv = *(const float4*)&Kt[jb + j][(4 * k4) ^ jb];
        s = fmaf(q8[k4].x, kv.x, s); s = fmaf(q8[k4].y, kv.y, s);
        s = fmaf(q8[k4].z, kv.z, s); s = fmaf(q8[k4].w, kv.w, s);
      }
      int jglob = j0 + kt * 32 + jb + j;
      sv[j] = (jglob < Nk) ? s : -1e30f;
    }
    float tmax = sv[0];
#pragma unroll
    for (int j = 1; j < 16; ++j) tmax = fmaxf(tmax, sv[j]);
    tmax = fmaxf(tmax, __shfl_xor(tmax, 1));
    float mnew = fmaxf(m, tmax);
    float scale = __expf(m - mnew);
    float p[16]; float psum = 0.f;
#pragma unroll
    for (int j = 0; j < 16; ++j) {
      int jglob = j0 + kt * 32 + jb + j;
      float e = (jglob < Nk) ? __expf(sv[j] - mnew) : 0.f;
      p[j] = e; psum += e;
    }
    psum += __shfl_xor(psum, 1);
    lsum = lsum * scale + psum;
    m = mnew;
#pragma unroll
    for (int i = 0; i < 16; ++i) o[i] *= scale;
    float pO[16];
#pragma unroll
    for (int j = 0; j < 16; ++j) pO[j] = __shfl_xor(p[j], 1);
    int jbO = jb ^ 16;
#pragma unroll
    for (int j = 0; j < 16; ++j) {
      float pj = p[j];
      const float* vrow = &Vt[jb + j][ho];
#pragma unroll
      for (int k = 0; k < 4; ++k) {
        float4 v4 = *(const float4*)&vrow[4 * k];
        o[4 * k + 0] = fmaf(pj, v4.x, o[4 * k + 0]);
        o[4 * k + 1] = fmaf(pj, v4.y, o[4 * k + 1]);
        o[4 * k + 2] = fmaf(pj, v4.z, o[4 * k + 2]);
        o[4 * k + 3] = fmaf(pj, v4.w, o[4 * k + 3]);
      }
    }
#pragma unroll
    for (int j = 0; j < 16; ++j) {
      float pj = pO[j];
      const float* vrow = &Vt[jbO + j][ho];
#pragma unroll
      for (int k = 0; k < 4; ++k) {
        float4 v4 = *(const float4*)&vrow[4 * k];
        o[4 * k + 0] = fmaf(pj, v4.x, o[4 * k + 0]);
        o[4 * k + 1] = fmaf(pj, v4.y, o[4 * k + 1]);
        o[4 * k + 2] = fmaf(pj, v4.z, o[4 * k + 2]);
        o[4 * k + 3] = fmaf(pj, v4.w, o[4 * k + 3]);
      }
    }
  }
  if (qi < 100) {
    float* pod = po + (long)bid * 3200 + qi * 32 + ho;
#pragma unroll
    for (int k = 0; k < 4; ++k)
      *(float4*)&pod[4 * k] = make_float4(o[4 * k], o[4 * k + 1], o[4 * k + 2], o[4 * k + 3]);
    if (half == 0) { pm[bid * 128 + qi] = m; pl[bid * 128 + qi] = lsum; }
  }
}

// --- SA combine (unchanged) -------------------------------------------------
__global__ __launch_bounds__(256) void combine_kernel(const float* __restrict__ po,
                                                      const float* __restrict__ pm,
                                                      const float* __restrict__ pl,
                                                      int4 startv, int4 nchv,
                                                      float* __restrict__ outp, int outld) {
  int bid = blockIdx.x;
  int l = bid >> 5, rr = bid & 31, b = rr >> 3, h = rr & 7;
  int nc = sel4(nchv, l);
  int sb = sel4(startv, l) + (b * 8 + h) * nc;
  int qr0 = (l * 4 + b) * 100;
  int idx = blockIdx.y * 256 + threadIdx.x;
  if (idx >= 3200) return;
  int qi = idx >> 5, hd = idx & 31;
  float mstar = -1e30f;
  for (int c = 0; c < nc; ++c) mstar = fmaxf(mstar, pm[(sb + c) * 128 + qi]);
  float Lt = 0.f, val = 0.f;
  for (int c = 0; c < nc; ++c) {
    float w = __expf(pm[(sb + c) * 128 + qi] - mstar);
    Lt = fmaf(w, pl[(sb + c) * 128 + qi], Lt);
    val = fmaf(w, po[(long)(sb + c) * 3200 + qi * 32 + hd], val);
  }
  outp[(long)(qr0 + qi) * outld + h * 32 + hd] = val / Lt;
}

// --- CA flash: MFMA, swapped operands, split-bf16 ---------------------------
// block = (b,l,chunk512,hquad): 4 waves = 4 heads; wave owns one 16-q tile.
// grid 672 blocks/dispatch. S^T = mfma(K,Q): lane holds rows k=4g+reg, col q=fr.
__global__ __launch_bounds__(256) void flash_ca_kernel(
    const unsigned short* __restrict__ Qh, const unsigned short* __restrict__ Ql,
    const unsigned short* __restrict__ KVh, const unsigned short* __restrict__ KVl,
    float* __restrict__ po, float* __restrict__ pm, float* __restrict__ pl) {
  __shared__ __align__(16) unsigned short VTh[128 * 40];
  __shared__ __align__(16) unsigned short VTl[128 * 40];
  __shared__ __align__(16) unsigned short Pbuf[4][2][16 * 40];
  int bid = blockIdx.x;
  int start, nc, koff, kstr, jn, pub;
  if (bid < 448)      { start = 0;   nc = 8; koff = 0;     kstr = 4096; jn = 512; pub = 0; }
  else if (bid < 560) { start = 448; nc = 2; koff = 16384; kstr = 1024; jn = 512; pub = 1792; }
  else if (bid < 616) { start = 560; nc = 1; koff = 20480; kstr = 256;  jn = 256; pub = 2240; }
  else                { start = 616; nc = 1; koff = 21504; kstr = 64;   jn = 64;  pub = 2464; }
  int lvl4 = (bid < 448) ? 0 : (bid < 560) ? 4 : (bid < 616) ? 8 : 12;
  int r = bid - start;
  int ch = r % nc; int t = r / nc;
  int qt = t % 7; t /= 7;
  int hq = t & 1; int b = t >> 1;
  int tid = threadIdx.x;
  int wid = tid >> 6, lane = tid & 63;
  int h = hq * 4 + wid;
  int fr = lane & 15, g = lane >> 4;
  int kr0 = koff + b * kstr + ch * 512;
  int ntile = jn >> 5;
  int qrow = (lvl4 + b) * 100 + qt * 16 + fr;
  bf16x8 qhf = *(const bf16x8*)&Qh[(long)qrow * 256 + h * 32 + 8 * g];
  bf16x8 qlf = *(const bf16x8*)&Ql[(long)qrow * 256 + h * 32 + 8 * g];
  float mrun = -1e30f, lrun = 0.f;
  f32x4 o0 = {0.f, 0.f, 0.f, 0.f}, o1 = o0;
  unsigned short* Pw0 = &Pbuf[wid][0][0];
  unsigned short* Pw1 = &Pbuf[wid][1][0];

  for (int kt = 0; kt < ntile; ++kt) {
    if (kt) __syncthreads();
    {  // stage V^T for this 32-key tile (4 heads' slices)
      int vr = tid >> 3, vd0 = (tid & 7) * 16;
      long vg = (long)(kr0 + kt * 32 + vr) * 512 + 256 + hq * 128 + vd0;
      u16x8 a0 = *(const u16x8*)&KVh[vg];
      u16x8 a1 = *(const u16x8*)&KVh[vg + 8];
      u16x8 b0 = *(const u16x8*)&KVl[vg];
      u16x8 b1 = *(const u16x8*)&KVl[vg + 8];
#pragma unroll
      for (int i = 0; i < 8; ++i) {
        VTh[(vd0 + i) * 40 + vr] = a0[i];
        VTh[(vd0 + 8 + i) * 40 + vr] = a1[i];
        VTl[(vd0 + i) * 40 + vr] = b0[i];
        VTl[(vd0 + 8 + i) * 40 + vr] = b1[i];
      }
    }
    __syncthreads();
    // scores S^T[32k][16q]
    f32x4 s[2];
#pragma unroll
    for (int t16 = 0; t16 < 2; ++t16) {
      long krow = (long)(kr0 + kt * 32 + t16 * 16 + fr) * 512 + h * 32 + 8 * g;
      bf16x8 kh = *(const bf16x8*)&KVh[krow];
      bf16x8 kl = *(const bf16x8*)&KVl[krow];
      f32x4 z = {0.f, 0.f, 0.f, 0.f};
      z = __builtin_amdgcn_mfma_f32_16x16x32_bf16(kh, qhf, z, 0, 0, 0);
      z = __builtin_amdgcn_mfma_f32_16x16x32_bf16(kl, qhf, z, 0, 0, 0);
      z = __builtin_amdgcn_mfma_f32_16x16x32_bf16(kh, qlf, z, 0, 0, 0);
      s[t16] = z;
    }
    // online softmax over this tile's 32 keys (per q column = per fr)
    float tmax = s[0][0];
#pragma unroll
    for (int i = 1; i < 4; ++i) tmax = fmaxf(tmax, s[0][i]);
#pragma unroll
    for (int i = 0; i < 4; ++i) tmax = fmaxf(tmax, s[1][i]);
    tmax = fmaxf(tmax, __shfl_xor(tmax, 16));
    tmax = fmaxf(tmax, __shfl_xor(tmax, 32));
    float mnew = fmaxf(mrun, tmax);
    float scale = __expf(mrun - mnew);
    mrun = mnew;
    float psum = 0.f;
    float p[8];
#pragma unroll
    for (int t16 = 0; t16 < 2; ++t16)
#pragma unroll
      for (int i = 0; i < 4; ++i) {
        float e = __expf(s[t16][i] - mnew);
        p[t16 * 4 + i] = e;
        psum += e;
      }
    lrun = lrun * scale + psum;
    o0 *= scale; o1 *= scale;
    // write split P^T as [q][k]
#pragma unroll
    for (int t16 = 0; t16 < 2; ++t16)
#pragma unroll
      for (int i = 0; i < 4; ++i) {
        int k = t16 * 16 + 4 * g + i;
        float pv = p[t16 * 4 + i];
        unsigned short hi = bf_rne(pv);
        Pw0[fr * 40 + k] = hi;
        Pw1[fr * 40 + k] = bf_rne(pv - bf2f(hi));
      }
    __syncthreads();
    bf16x8 pbh = *(const bf16x8*)&Pw0[fr * 40 + 8 * g];
    bf16x8 pbl = *(const bf16x8*)&Pw1[fr * 40 + 8 * g];
    {
      const unsigned short* v0h = &VTh[(wid * 32 + fr) * 40 + 8 * g];
      const unsigned short* v0l = &VTl[(wid * 32 + fr) * 40 + 8 * g];
      bf16x8 vh = *(const bf16x8*)v0h;
      bf16x8 vl = *(const bf16x8*)v0l;
      o0 = __builtin_amdgcn_mfma_f32_16x16x32_bf16(vh, pbh, o0, 0, 0, 0);
      o0 = __builtin_amdgcn_mfma_f32_16x16x32_bf16(vl, pbh, o0, 0, 0, 0);
      o0 = __builtin_amdgcn_mfma_f32_16x16x32_bf16(vh, pbl, o0, 0, 0, 0);
    }
    {
      const unsigned short* v1h = &VTh[(wid * 32 + 16 + fr) * 40 + 8 * g];
      const unsigned short* v1l = &VTl[(wid * 32 + 16 + fr) * 40 + 8 * g];
      bf16x8 vh = *(const bf16x8*)v1h;
      bf16x8 vl = *(const bf16x8*)v1l;
      o1 = __builtin_amdgcn_mfma_f32_16x16x32_bf16(vh, pbh, o1, 0, 0, 0);
      o1 = __builtin_amdgcn_mfma_f32_16x16x32_bf16(vl, pbh, o1, 0, 0, 0);
      o1 = __builtin_amdgcn_mfma_f32_16x16x32_bf16(vh, pbl, o1, 0, 0, 0);
    }
  }
  lrun += __shfl_xor(lrun, 16);
  lrun += __shfl_xor(lrun, 32);
  int u_rel = (b * 8 + h) * 7 + qt;
  int pu = pub + u_rel * nc + ch;
  float* pod = po + (long)pu * 512 + fr * 32;
  *(f32x4*)&pod[4 * g] = o0;
  *(f32x4*)&pod[16 + 4 * g] = o1;
  if (g == 0) { pm[pu * 16 + fr] = mrun; pl[pu * 16 + fr] = lrun; }
}

// --- CA combine: u = (l,b,h,qt), 896 blocks --------------------------------
__global__ __launch_bounds__(256) void combine2_kernel(const float* __restrict__ po,
                                                       const float* __restrict__ pm,
                                                       const float* __restrict__ pl,
                                                       float* __restrict__ outp) {
  int u = blockIdx.x;
  int l = u / 224, ur = u % 224;
  int b = ur / 56, rem = ur % 56, h = rem / 7, qt = rem % 7;
  int nc, pub;
  if (l == 0)      { nc = 8; pub = 0; }
  else if (l == 1) { nc = 2; pub = 1792; }
  else if (l == 2) { nc = 1; pub = 2240; }
  else             { nc = 1; pub = 2464; }
  int pu0 = pub + ur * nc;
  int qr0 = (l * 4 + b) * 100 + qt * 16;
  int qn = min(16, 100 - qt * 16);
  for (int e = threadIdx.x; e < 512; e += 256) {
    int qi = e >> 5, d = e & 31;
    if (qi >= qn) continue;
    float mstar = -1e30f;
    for (int c = 0; c < nc; ++c) mstar = fmaxf(mstar, pm[(pu0 + c) * 16 + qi]);
    float Lt = 0.f, val = 0.f;
    for (int c = 0; c < nc; ++c) {
      float w = __expf(pm[(pu0 + c) * 16 + qi] - mstar);
      Lt = fmaf(w, pl[(pu0 + c) * 16 + qi], Lt);
      val = fmaf(w, po[(long)(pu0 + c) * 512 + qi * 32 + d], val);
    }
    outp[(long)(qr0 + qi) * 256 + h * 32 + d] = val / Lt;
  }
}

// --- ms = q1 @ q2^T ---------------------------------------------------------
__global__ __launch_bounds__(256) void fuse_ms_kernel(const float* __restrict__ q1,
                                                      const float* __restrict__ q2,
                                                      float* __restrict__ ms) {
  __shared__ float a[32][132];
  __shared__ float bsh[32][132];
  int lb = blockIdx.x;
  int it = blockIdx.y >> 2, jt = blockIdx.y & 3;
  int tid = threadIdx.x;
  int ti = tid & 15, tj = tid >> 4;
  float acc[2][2] = {};
  for (int chalf = 0; chalf < 2; ++chalf) {
    __syncthreads();
#pragma unroll
    for (int k = 0; k < 4; ++k) {
      int i = tid + k * 256;
      int rr = i >> 5, c4 = (i & 31) * 4;
      int row1 = it * 32 + rr, row2 = jt * 32 + rr;
      float4 fa = make_float4(0.f, 0.f, 0.f, 0.f), fb = fa;
      if (row1 < 100) fa = *(const float4*)&q1[(long)(lb * 100 + row1) * 256 + chalf * 128 + c4];
      if (row2 < 100) fb = *(const float4*)&q2[(long)(lb * 100 + row2) * 256 + chalf * 128 + c4];
      *(float4*)&a[rr][c4] = fa;
      *(float4*)&bsh[rr][c4] = fb;
    }
    __syncthreads();
#pragma unroll
    for (int k4 = 0; k4 < 32; ++k4) {
      float4 a0 = *(const float4*)&a[2 * ti][4 * k4];
      float4 a1 = *(const float4*)&a[2 * ti + 1][4 * k4];
      float4 b0 = *(const float4*)&bsh[2 * tj][4 * k4];
      float4 b1 = *(const float4*)&bsh[2 * tj + 1][4 * k4];
      acc[0][0] += dot4(a0, b0); acc[0][1] += dot4(a0, b1);
      acc[1][0] += dot4(a1, b0); acc[1][1] += dot4(a1, b1);
    }
  }
#pragma unroll
  for (int i = 0; i < 2; ++i)
#pragma unroll
    for (int j = 0; j < 2; ++j)
      ms[(long)(lb * 128 + it * 32 + 2 * ti + i) * 128 + jt * 32 + 2 * tj + j] = acc[i][j];
}

// --- row & column softmax stats of ms --------------------------------------
__global__ void fuse_stats_kernel(const float* __restrict__ ms, float* __restrict__ rst) {
  int lb = blockIdx.x, tid = threadIdx.x;
  if (tid < 100) {
    const float* row = ms + (long)(lb * 128 + tid) * 128;
    float mx = row[0];
    for (int j = 1; j < 100; ++j) mx = fmaxf(mx, row[j]);
    float s = 0.f;
    for (int j = 0; j < 100; ++j) s += __expf(row[j] - mx);
    rst[(0 * 16 + lb) * 128 + tid] = mx;
    rst[(1 * 16 + lb) * 128 + tid] = s;
  } else if (tid >= 128 && tid < 228) {
    int j = tid - 128;
    const float* colp = ms + (long)lb * 128 * 128 + j;
    float mx = colp[0];
    for (int i = 1; i < 100; ++i) mx = fmaxf(mx, colp[i * 128]);
    float s = 0.f;
    for (int i = 0; i < 100; ++i) s += __expf(colp[i * 128] - mx);
    rst[(2 * 16 + lb) * 128 + j] = mx;
    rst[(3 * 16 + lb) * 128 + j] = s;
  }
}

// --- r1/r2 mixing + final channel softmax -----------------------------------
__global__ __launch_bounds__(256) void fuse_apply_kernel(const float* __restrict__ ms,
                                                         const float* __restrict__ rst,
                                                         const float* __restrict__ q1,
                                                         const float* __restrict__ q2,
                                                         const float* __restrict__ qsa,
                                                         float* __restrict__ qout) {
  __shared__ float pr[100], pc[100];
  __shared__ float red1[4], red2[4];
  int lb = blockIdx.x, qc = blockIdx.y, tid = threadIdx.x;
  for (int ii = 0; ii < 10; ++ii) {
    int i = qc * 10 + ii;
    long r = lb * 100 + i;
    if (tid < 100) {
      float rm = rst[(0 * 16 + lb) * 128 + i], rs = rst[(1 * 16 + lb) * 128 + i];
      pr[tid] = __expf(ms[(long)(lb * 128 + i) * 128 + tid] - rm) / rs;
    } else if (tid >= 128 && tid < 228) {
      int i2 = tid - 128;
      float cm = rst[(2 * 16 + lb) * 128 + i], cs = rst[(3 * 16 + lb) * 128 + i];
      pc[i2] = __expf(ms[(long)(lb * 128 + i2) * 128 + i] - cm) / cs;
    }
    __syncthreads();
    float acc1 = 0.f, acc2 = 0.f;
    for (int j = 0; j < 100; ++j) acc1 = fmaf(pr[j], q2[(long)(lb * 100 + j) * 256 + tid], acc1);
    for (int j = 0; j < 100; ++j) acc2 = fmaf(pc[j], q1[(long)(lb * 100 + j) * 256 + tid], acc2);
    float z = qsa[r * 256 + tid] + q1[r * 256 + tid] + acc1 + q2[r * 256 + tid] + acc2;
    float v = z;
    for (int off = 32; off; off >>= 1) v = fmaxf(v, __shfl_xor(v, off));
    int w = tid >> 6;
    if ((tid & 63) == 0) red1[w] = v;
    __syncthreads();
    float zm = fmaxf(fmaxf(red1[0], red1[1]), fmaxf(red1[2], red1[3]));
    float e = __expf(z - zm);
    float sv = e;
    for (int off = 32; off; off >>= 1) sv += __shfl_xor(sv, off);
    if ((tid & 63) == 0) red2[w] = sv;
    __syncthreads();
    float es = red2[0] + red2[1] + red2[2] + red2[3];
    qout[r * 256 + tid] = e / es;
    __syncthreads();
  }
}

// ---------------------------------------------------------------------------
extern "C" void kernel_launch(void* const* d_in, const int* in_sizes, int n_in,
                              void* d_out, int out_size, void* d_ws, size_t ws_size,
                              hipStream_t stream) {
  (void)in_sizes; (void)n_in; (void)out_size; (void)ws_size;
  const float* feats[2][4] = {
      {(const float*)d_in[0], (const float*)d_in[1], (const float*)d_in[2], (const float*)d_in[3]},
      {(const float*)d_in[4], (const float*)d_in[5], (const float*)d_in[6], (const float*)d_in[7]}};
  const float* qe   = (const float*)d_in[8];
  const float* ng   = (const float*)d_in[9];
  const float* nb   = (const float*)d_in[10];
  const float* wq   = (const float*)d_in[11];
  const float* wk   = (const float*)d_in[12];
  const float* wv   = (const float*)d_in[13];
  const float* wp   = (const float*)d_in[14];
  const float* bp   = (const float*)d_in[15];
  const float* swqkv= (const float*)d_in[16];
  const float* swp  = (const float*)d_in[17];
  const float* sbp  = (const float*)d_in[18];

  float* ws = (float*)d_ws;
  unsigned short* KVHp = (unsigned short*)(ws + O_KVH);
  unsigned short* KVLp = (unsigned short*)(ws + O_KVL);
  float* QBUFp = ws + O_QBUF;
  float* QKVp  = ws + O_QKV;
  float* QSAp  = ws + O_QSA;
  float* QHATp = ws + O_QHAT;
  float* QNp   = ws + O_QN;
  float* SAOp  = ws + O_SAO;
  float* OCAp  = ws + O_OCA;
  float* Q12p  = ws + O_Q12;
  unsigned short* QHp  = (unsigned short*)(ws + O_QH);
  unsigned short* QLp  = (unsigned short*)(ws + O_QL);
  unsigned short* WTHp = (unsigned short*)(ws + O_WTH);
  unsigned short* WTLp = (unsigned short*)(ws + O_WTL);
  float* WQp   = ws + O_WQ;
  float* BKVp  = ws + O_BKV;
  float* BQp   = ws + O_BQ;
  float* POp   = ws + O_PO;
  float* PMp   = ws + O_PM;
  float* PLp   = ws + O_PL;
  float* PO2p  = ws + O_PO2;
  float* PM2p  = ws + O_PM2;
  float* PL2p  = ws + O_PL2;
  float* MSp   = ws + O_MS;
  float* RSTp  = ws + O_RST;
  float* STATSp= ws + O_STATS;

  const int HWs[4] = {4096, 1024, 256, 64};
  const int VOs[4] = {0, 16384, 20480, 21504};

  fold_w2_kernel<<<4608, 256, 0, stream>>>(ng, wk, wv, wq, WTHp, WTLp, WQp);
  fold_b_kernel<<<18, 256, 0, stream>>>(nb, wk, wv, wq, BKVp, BQp);
  for (int v = 0; v < 2; ++v)
    for (int l = 0; l < 4; ++l)
      ln_stats_kernel<<<dim3(HWs[l] / 64, 4), 256, 0, stream>>>(
          feats[v][l], STATSp, v * 21760 + VOs[l], HWs[l]);
  init_q_kernel<<<1600, 256, 0, stream>>>(qe, QBUFp);

  const int4 saStart = make_int4(0, 32, 64, 96);
  const int4 saNch   = make_int4(1, 1, 1, 1);
  const int4 saNk    = make_int4(100, 100, 100, 100);
  const int4 saKoff  = make_int4(0, 400, 800, 1200);
  const int4 saKstrb = make_int4(100, 100, 100, 100);

  for (int d = 0; d < 6; ++d) {
    // --- self attention ---
    gemm256_kernel<<<dim3(12, 25), 256, 0, stream>>>(QBUFp, swqkv + (long)d * 196608, nullptr,
                                                     QKVp, 1600, 768);
    flash_kernel<<<128, 256, 0, stream>>>(QKVp, 768, QKVp + 256, QKVp + 512, 768,
                                          saStart, saNch, saNk, saKoff, saKstrb, POp, PMp, PLp);
    combine_kernel<<<dim3(128, 13), 256, 0, stream>>>(POp, PMp, PLp, saStart, saNch, SAOp, 256);
    gemm256_kernel<<<dim3(4, 25), 256, 0, stream>>>(SAOp, swp + (long)d * 65536, sbp + d * 256,
                                                    QSAp, 1600, 256);
    // --- cross-attention query projection + split ---
    row_ln_kernel<<<1600, 256, 0, stream>>>(QSAp, QHATp);
    gemm256_kernel<<<dim3(4, 25), 256, 0, stream>>>(QHATp, WQp + (long)d * 65536, BQp + d * 256,
                                                    QNp, 1600, 256);
    split_q_kernel<<<1616, 256, 0, stream>>>(QNp, QHp, QLp);
    // --- cross attention per view ---
    for (int v = 0; v < 2; ++v) {
      gemm_kv_mfma_kernel<<<dim3(8, 340), 256, 0, stream>>>(
          feats[v][0], feats[v][1], feats[v][2], feats[v][3], STATSp, v * 21760,
          WTHp + (long)d * 131072, WTLp + (long)d * 131072, BKVp + d * 512, KVHp, KVLp);
      flash_ca_kernel<<<672, 256, 0, stream>>>(QHp, QLp, KVHp, KVLp, PO2p, PM2p, PL2p);
      combine2_kernel<<<896, 256, 0, stream>>>(PO2p, PM2p, PL2p, OCAp + (long)v * 409600);
    }
    gemm256_kernel<<<dim3(4, 50), 256, 0, stream>>>(OCAp, wp + (long)d * 65536, bp + d * 256,
                                                    Q12p, 3200, 256);
    // --- matching fusion + channel softmax ---
    fuse_ms_kernel<<<dim3(16, 16), 256, 0, stream>>>(Q12p, Q12p + 409600, MSp);
    fuse_stats_kernel<<<16, 256, 0, stream>>>(MSp, RSTp);
    fuse_apply_kernel<<<dim3(16, 10), 256, 0, stream>>>(MSp, RSTp, Q12p, Q12p + 409600,
                                                        QSAp, QBUFp);
  }
  hipMemcpyAsync(d_out, QBUFp, 409600 * sizeof(float), hipMemcpyDeviceToDevice, stream);
}

// Round 5
// 2436.878 us; speedup vs baseline: 1.1442x; 1.1442x over previous
//
#include <hip/hip_runtime.h>

// ---------------------------------------------------------------------------
// VolumeAttention: 4 feature levels x 6 decoder depths, B=4, NQ=100, C=256, H=8
// Round 5:
//  - CA flash v2: barrier-free, LDS-free. V^T produced by KV projection
//    (write-side transpose); key-permutation makes score-D layout == PV-B
//    layout so P never leaves registers. 1536 independent waves.
//  - K stored row-major [tok][256] hi/lo; V stored [d][tok] hi/lo.
// ---------------------------------------------------------------------------

#define DI __device__ __forceinline__
#define MFMA16(a, b, c) __builtin_amdgcn_mfma_f32_16x16x32_bf16(a, b, c, 0, 0, 0)

typedef __attribute__((ext_vector_type(8))) short bf16x8;
typedef __attribute__((ext_vector_type(4))) float f32x4;

// ws offsets in floats
constexpr long O_KH    = 0;                        // [21760][256] ushort hi
constexpr long O_KL    = O_KH   + 2785280;         // [21760][256] ushort lo
constexpr long O_VTH   = O_KL   + 2785280;         // [256][21760] ushort hi
constexpr long O_VTL   = O_VTH  + 2785280;         // [256][21760] ushort lo
constexpr long O_QBUF  = O_VTL  + 2785280;         // [1600][256]
constexpr long O_QKV   = O_QBUF + 409600;          // [1600][768]
constexpr long O_QSA   = O_QKV  + 1228800;         // [1600][256]
constexpr long O_QHAT  = O_QSA  + 409600;          // [1600][256]
constexpr long O_QN    = O_QHAT + 409600;          // [1600][256]
constexpr long O_SAO   = O_QN   + 409600;          // [1600][256]
constexpr long O_OCA   = O_SAO  + 409600;          // [2][1600][256]
constexpr long O_Q12   = O_OCA  + 819200;          // [2][1600][256]
constexpr long O_QH    = O_Q12  + 819200;          // [1632][256] ushort hi
constexpr long O_QL    = O_QH   + 208896;          // [1632][256] ushort lo
constexpr long O_WTH   = O_QL   + 208896;          // [6][512][256] ushort hi
constexpr long O_WTL   = O_WTH  + 393216;          // [6][512][256] ushort lo
constexpr long O_WQ    = O_WTL  + 393216;          // [6][256][256] fp32
constexpr long O_BKV   = O_WQ   + 393216;          // [6][512]
constexpr long O_BQ    = O_BKV  + 3072;            // [6][256]
constexpr long O_PO    = O_BQ   + 1536;            // [128][3200] SA partials
constexpr long O_PM    = O_PO   + 409600;          // [128][128]
constexpr long O_PL    = O_PM   + 16384;           // [128][128]
constexpr long O_PO2   = O_PL   + 16384;           // [1536][1024] CA partials
constexpr long O_PM2   = O_PO2  + 1572864;         // [1536][32]
constexpr long O_PL2   = O_PM2  + 49152;           // [1536][32]
constexpr long O_MS    = O_PL2  + 49152;           // [16][128][128]
constexpr long O_RST   = O_MS   + 262144;          // [4][16][128]
constexpr long O_STATS = O_RST  + 8192;            // [43520][2]
constexpr long WS_FLOATS = O_STATS + 87040;        // ~80.5 MB

DI int sel4(int4 v, int i) { return i == 0 ? v.x : (i == 1 ? v.y : (i == 2 ? v.z : v.w)); }
DI float dot4(float4 a, float4 b) {
  float s = a.x * b.x;
  s = fmaf(a.y, b.y, s); s = fmaf(a.z, b.z, s); s = fmaf(a.w, b.w, s);
  return s;
}
DI unsigned short bf_rne(float x) {
  unsigned u = __float_as_uint(x);
  u += 0x7fffu + ((u >> 16) & 1u);
  return (unsigned short)(u >> 16);
}
DI float bf2f(unsigned short h) { return __uint_as_float(((unsigned)h) << 16); }

// --- fold LN affine into projections; KV weights -> transposed split-bf16 --
__global__ void fold_w2_kernel(const float* __restrict__ ng, const float* __restrict__ wk,
                               const float* __restrict__ wv, const float* __restrict__ wq,
                               unsigned short* __restrict__ WTh, unsigned short* __restrict__ WTl,
                               float* __restrict__ wqo) {
  long idx = (long)blockIdx.x * 256 + threadIdx.x;
  const long T1 = 6L * 512 * 256;
  if (idx < T1) {
    int d = idx / (512 * 256); int r = idx % (512 * 256); int n = r / 256; int k = r % 256;
    float g = ng[d * 256 + k];
    float w = (n < 256) ? wk[((long)(d * 256 + k)) * 256 + n]
                        : wv[((long)(d * 256 + k)) * 256 + (n - 256)];
    w *= g;
    unsigned short h = bf_rne(w);
    WTh[idx] = h;
    WTl[idx] = bf_rne(w - bf2f(h));
  } else {
    long j = idx - T1;
    if (j < 6L * 256 * 256) {
      int d = j / 65536; int r = j % 65536; int c = r / 256; int n = r % 256;
      wqo[j] = ng[d * 256 + c] * wq[((long)(d * 256 + c)) * 256 + n];
    }
  }
}

__global__ void fold_b_kernel(const float* __restrict__ nb, const float* __restrict__ wk,
                              const float* __restrict__ wv, const float* __restrict__ wq,
                              float* __restrict__ bkvo, float* __restrict__ bqo) {
  int idx = blockIdx.x * 256 + threadIdx.x;
  if (idx >= 6 * 768) return;
  int d = idx / 768, j = idx % 768;
  float s = 0.f;
  if (j < 256) {
    for (int c = 0; c < 256; ++c) s = fmaf(nb[d * 256 + c], wk[(d * 256 + c) * 256 + j], s);
    bkvo[d * 512 + j] = s;
  } else if (j < 512) {
    int n = j - 256;
    for (int c = 0; c < 256; ++c) s = fmaf(nb[d * 256 + c], wv[(d * 256 + c) * 256 + n], s);
    bkvo[d * 512 + j] = s;
  } else {
    int n = j - 512;
    for (int c = 0; c < 256; ++c) s = fmaf(nb[d * 256 + c], wq[(d * 256 + c) * 256 + n], s);
    bqo[d * 256 + n] = s;
  }
}

// --- per-token LN statistics of feature maps ------------------------------
__global__ __launch_bounds__(256) void ln_stats_kernel(const float* __restrict__ feat,
                                                       float* __restrict__ stats,
                                                       int rowBase, int HW) {
  __shared__ float sred[4][64];
  __shared__ float qred[4][64];
  int b = blockIdx.y, t0 = blockIdx.x * 64;
  int tx = threadIdx.x & 63, ty = threadIdx.x >> 6;
  const float* fb = feat + (long)b * 256 * HW;
  float s = 0.f, q = 0.f;
  for (int k = 0; k < 64; ++k) {
    int c = ty * 64 + k;
    float v = fb[(long)c * HW + t0 + tx];
    s += v; q += v * v;
  }
  sred[ty][tx] = s; qred[ty][tx] = q;
  __syncthreads();
  if (ty == 0) {
    float ts = sred[0][tx] + sred[1][tx] + sred[2][tx] + sred[3][tx];
    float tq = qred[0][tx] + qred[1][tx] + qred[2][tx] + qred[3][tx];
    float m = ts * (1.f / 256.f);
    float var = tq * (1.f / 256.f) - m * m;
    int row = rowBase + b * HW + t0 + tx;
    stats[row * 2 + 0] = m;
    stats[row * 2 + 1] = rsqrtf(var + 1e-5f);
  }
}

__global__ void init_q_kernel(const float* __restrict__ qe, float* __restrict__ qb) {
  int idx = blockIdx.x * 256 + threadIdx.x;
  if (idx < 1600 * 256) {
    int row = idx >> 8, c = idx & 255;
    qb[idx] = qe[(row % 100) * 256 + c];
  }
}

// --- split/scale Q for CA flash: Qh/Ql [1632][256], pad rows zeroed --------
__global__ void split_q_kernel(const float* __restrict__ qn,
                               unsigned short* __restrict__ Qh,
                               unsigned short* __restrict__ Ql) {
  int idx = blockIdx.x * 256 + threadIdx.x;
  if (idx >= 1632 * 256) return;
  float v = (idx < 1600 * 256) ? qn[idx] * 0.17677669529663689f : 0.f;
  unsigned short hi = bf_rne(v);
  Qh[idx] = hi;
  Ql[idx] = bf_rne(v - bf2f(hi));
}

// --- generic fp32 GEMM: C[M,N] = A[M,256] @ W[256,N] (+bias) --------------
__global__ __launch_bounds__(256) void gemm256_kernel(const float* __restrict__ A,
                                                      const float* __restrict__ W,
                                                      const float* __restrict__ bias,
                                                      float* __restrict__ Co, int M, int N) {
  __shared__ float As[32][68];
  __shared__ float Ws[32][68];
  int tid = threadIdx.x;
  int tm = tid & 15, tn = tid >> 4;
  int m0 = blockIdx.y * 64, n0 = blockIdx.x * 64;
  float acc[4][4] = {};
  for (int kt = 0; kt < 8; ++kt) {
    __syncthreads();
#pragma unroll
    for (int it = 0; it < 2; ++it) {
      int i = tid + it * 256;
      int r = i >> 3, c4 = (i & 7) * 4;
      float4 f = *(const float4*)&A[(long)(m0 + r) * 256 + kt * 32 + c4];
      As[c4 + 0][r] = f.x; As[c4 + 1][r] = f.y; As[c4 + 2][r] = f.z; As[c4 + 3][r] = f.w;
    }
#pragma unroll
    for (int it = 0; it < 2; ++it) {
      int i = tid + it * 256;
      int r = i >> 4, c4 = (i & 15) * 4;
      *(float4*)&Ws[r][c4] = *(const float4*)&W[(long)(kt * 32 + r) * N + n0 + c4];
    }
    __syncthreads();
#pragma unroll
    for (int k = 0; k < 32; ++k) {
      float4 a4 = *(const float4*)&As[k][4 * tm];
      float4 b4 = *(const float4*)&Ws[k][4 * tn];
      float av[4] = {a4.x, a4.y, a4.z, a4.w};
      float bv[4] = {b4.x, b4.y, b4.z, b4.w};
#pragma unroll
      for (int i = 0; i < 4; ++i)
#pragma unroll
        for (int j = 0; j < 4; ++j) acc[i][j] = fmaf(av[i], bv[j], acc[i][j]);
    }
  }
  float bv4[4] = {0.f, 0.f, 0.f, 0.f};
  if (bias) {
#pragma unroll
    for (int j = 0; j < 4; ++j) bv4[j] = bias[n0 + 4 * tn + j];
  }
#pragma unroll
  for (int i = 0; i < 4; ++i) {
    int row = m0 + 4 * tm + i;
    float4 o;
    o.x = acc[i][0] + bv4[0]; o.y = acc[i][1] + bv4[1];
    o.z = acc[i][2] + bv4[2]; o.w = acc[i][3] + bv4[3];
    *(float4*)&Co[(long)row * N + n0 + 4 * tn] = o;
  }
}

// --- KV projection via MFMA; K row-major split, V transposed split ---------
__global__ __launch_bounds__(256) void gemm_kv_mfma_kernel(
    const float* __restrict__ f0, const float* __restrict__ f1,
    const float* __restrict__ f2, const float* __restrict__ f3,
    const float* __restrict__ stats, int vbase,
    const unsigned short* __restrict__ Wh, const unsigned short* __restrict__ Wl,
    const float* __restrict__ bias,
    unsigned short* __restrict__ Kh, unsigned short* __restrict__ Kl,
    unsigned short* __restrict__ VTh, unsigned short* __restrict__ VTl) {
  __shared__ unsigned short Ah[64][72], Al[64][72];   // [m][k] bf16, pad 8
  __shared__ unsigned short Bh[64][72], Bl[64][72];   // [n][k] bf16
  __shared__ float sm[64], sr[64];
  int tid = threadIdx.x;
  int m0 = blockIdx.y * 64, n0 = blockIdx.x * 64;
  const float* fp; int HW, rel;
  if (m0 < 16384)      { fp = f0; HW = 4096; rel = m0; }
  else if (m0 < 20480) { fp = f1; HW = 1024; rel = m0 - 16384; }
  else if (m0 < 21504) { fp = f2; HW = 256;  rel = m0 - 20480; }
  else                 { fp = f3; HW = 64;   rel = m0 - 21504; }
  int b = rel / HW, t0 = rel % HW;
  const float* fb = fp + (long)b * 256 * HW + t0;
  if (tid < 64) {
    sm[tid] = stats[(vbase + m0 + tid) * 2 + 0];
    sr[tid] = stats[(vbase + m0 + tid) * 2 + 1];
  }
  int wv = tid >> 6, lane = tid & 63;
  int fr = lane & 15;
  int kq = lane >> 4;
  f32x4 acc[4];
#pragma unroll
  for (int c = 0; c < 4; ++c)
#pragma unroll
    for (int r = 0; r < 4; ++r) acc[c][r] = 0.f;
  __syncthreads();
  for (int kc = 0; kc < 4; ++kc) {
    {
      float mean = sm[lane], rstd = sr[lane];
#pragma unroll
      for (int pass = 0; pass < 4; ++pass) {
        int k = pass * 16 + wv * 4;
        float xs[4];
#pragma unroll
        for (int i = 0; i < 4; ++i)
          xs[i] = (fb[(long)(kc * 64 + k + i) * HW + lane] - mean) * rstd;
        ushort4 uh, ul;
        uh.x = bf_rne(xs[0]); ul.x = bf_rne(xs[0] - bf2f(uh.x));
        uh.y = bf_rne(xs[1]); ul.y = bf_rne(xs[1] - bf2f(uh.y));
        uh.z = bf_rne(xs[2]); ul.z = bf_rne(xs[2] - bf2f(uh.z));
        uh.w = bf_rne(xs[3]); ul.w = bf_rne(xs[3] - bf2f(uh.w));
        *(ushort4*)&Ah[lane][k] = uh;
        *(ushort4*)&Al[lane][k] = ul;
      }
    }
    {
      int ks = (tid & 15) * 4;
#pragma unroll
      for (int pass = 0; pass < 4; ++pass) {
        int n = pass * 16 + (tid >> 4);
        long g = (long)(n0 + n) * 256 + kc * 64 + ks;
        *(ushort4*)&Bh[n][ks] = *(const ushort4*)&Wh[g];
        *(ushort4*)&Bl[n][ks] = *(const ushort4*)&Wl[g];
      }
    }
    __syncthreads();
#pragma unroll
    for (int s = 0; s < 2; ++s) {
      int k0 = s * 32 + kq * 8;
      bf16x8 a_h = *(const bf16x8*)&Ah[wv * 16 + fr][k0];
      bf16x8 a_l = *(const bf16x8*)&Al[wv * 16 + fr][k0];
#pragma unroll
      for (int c = 0; c < 4; ++c) {
        bf16x8 b_h = *(const bf16x8*)&Bh[c * 16 + fr][k0];
        bf16x8 b_l = *(const bf16x8*)&Bl[c * 16 + fr][k0];
        acc[c] = MFMA16(a_h, b_h, acc[c]);
        acc[c] = MFMA16(a_l, b_h, acc[c]);
        acc[c] = MFMA16(a_h, b_l, acc[c]);
      }
    }
    __syncthreads();
  }
  int row0 = m0 + wv * 16 + kq * 4;
  if (n0 < 256) {
    // K half: row-major [tok][256] split stores
#pragma unroll
    for (int c = 0; c < 4; ++c) {
      float bv = bias[n0 + c * 16 + fr];
#pragma unroll
      for (int r = 0; r < 4; ++r) {
        float val = acc[c][r] + bv;
        long off = (long)(row0 + r) * 256 + n0 + c * 16 + fr;
        unsigned short hi = bf_rne(val);
        Kh[off] = hi;
        Kl[off] = bf_rne(val - bf2f(hi));
      }
    }
  } else {
    // V half: transpose via LDS (reuse Ah/Al), write V^T [d][tok] coalesced
#pragma unroll
    for (int c = 0; c < 4; ++c) {
      float bv = bias[n0 + c * 16 + fr];
      int nl = c * 16 + fr;
      int ml = wv * 16 + kq * 4;
#pragma unroll
      for (int r = 0; r < 4; ++r) {
        float val = acc[c][r] + bv;
        unsigned short hi = bf_rne(val);
        Ah[nl][ml + r] = hi;
        Al[nl][ml + r] = bf_rne(val - bf2f(hi));
      }
    }
    __syncthreads();
    int rw = tid >> 2, seg = (tid & 3) * 16;
    long dst = (long)(n0 - 256 + rw) * 21760 + m0 + seg;
#pragma unroll
    for (int q4 = 0; q4 < 4; ++q4) {
      *(ushort4*)&VTh[dst + q4 * 4] = *(ushort4*)&Ah[rw][seg + q4 * 4];
      *(ushort4*)&VTl[dst + q4 * 4] = *(ushort4*)&Al[rw][seg + q4 * 4];
    }
  }
}

// --- row LayerNorm (no affine) ---------------------------------------------
__global__ __launch_bounds__(256) void row_ln_kernel(const float* __restrict__ in,
                                                     float* __restrict__ out) {
  __shared__ float s1[4], s2[4];
  long r = blockIdx.x;
  float x = in[r * 256 + threadIdx.x];
  float vs = x, vq = x * x;
  for (int o = 32; o; o >>= 1) { vs += __shfl_xor(vs, o); vq += __shfl_xor(vq, o); }
  int w = threadIdx.x >> 6;
  if ((threadIdx.x & 63) == 0) { s1[w] = vs; s2[w] = vq; }
  __syncthreads();
  float ts = s1[0] + s1[1] + s1[2] + s1[3];
  float tq = s2[0] + s2[1] + s2[2] + s2[3];
  float m = ts * (1.f / 256.f);
  float var = tq * (1.f / 256.f) - m * m;
  out[r * 256 + threadIdx.x] = (x - m) * rsqrtf(var + 1e-5f);
}

// --- SA flash (VALU path, unchanged) ---------------------------------------
__global__ __launch_bounds__(256) void flash_kernel(const float* __restrict__ qp, int qld,
                                                    const float* __restrict__ kb,
                                                    const float* __restrict__ vb, int kvld,
                                                    int4 startv, int4 nchv, int4 nkv,
                                                    int4 koffv, int4 kstrbv,
                                                    float* __restrict__ po,
                                                    float* __restrict__ pm,
                                                    float* __restrict__ pl) {
  __shared__ float Kt[32][36];
  __shared__ float Vt[32][36];
  int bid = blockIdx.x;
  int s1 = startv.y, s2 = startv.z, s3 = startv.w;
  int l = (bid < s1) ? 0 : (bid < s2) ? 1 : (bid < s3) ? 2 : 3;
  int r = bid - sel4(startv, l);
  int nc = sel4(nchv, l);
  int b = r / (8 * nc);
  int h = (r / nc) & 7;
  int ch = r % nc;
  int Nk = sel4(nkv, l);
  int qr0 = (l * 4 + b) * 100;
  int kr0 = sel4(koffv, l) + b * sel4(kstrbv, l);
  int j0 = ch * 128;
  int jn = min(128, Nk - j0);
  int tiles = (jn + 31) >> 5;
  int tid = threadIdx.x;
  int qi = tid >> 1, half = tid & 1, ho = half * 16, jb = half * 16;
  const float SC = 0.17677669529663689f;
  float4 q8[8];
  if (qi < 100) {
    const float* qrow = qp + (long)(qr0 + qi) * qld + h * 32;
#pragma unroll
    for (int k = 0; k < 8; ++k) {
      float4 f = *(const float4*)&qrow[4 * k];
      q8[k] = make_float4(f.x * SC, f.y * SC, f.z * SC, f.w * SC);
    }
  } else {
#pragma unroll
    for (int k = 0; k < 8; ++k) q8[k] = make_float4(0.f, 0.f, 0.f, 0.f);
  }
  float m = -1e30f, lsum = 0.f;
  float o[16];
#pragma unroll
  for (int i = 0; i < 16; ++i) o[i] = 0.f;

  for (int kt = 0; kt < tiles; ++kt) {
    __syncthreads();
    {
      int rr = tid >> 3, c4 = (tid & 7) * 4;
      int jr = kt * 32 + rr;
      float4 kf = make_float4(0.f, 0.f, 0.f, 0.f), vf = kf;
      if (jr < jn) {
        long g = (long)(kr0 + j0 + jr) * kvld + h * 32 + c4;
        kf = *(const float4*)&kb[g];
        vf = *(const float4*)&vb[g];
      }
      *(float4*)&Kt[rr][c4 ^ (rr & 16)] = kf;
      *(float4*)&Vt[rr][c4] = vf;
    }
    __syncthreads();
    float sv[16];
#pragma unroll
    for (int j = 0; j < 16; ++j) {
      float s = 0.f;
#pragma unroll
      for (int k4 = 0; k4 < 8; ++k4) {
        float4 kv = *(const float4*)&Kt[jb + j][(4 * k4) ^ jb];
        s = fmaf(q8[k4].x, kv.x, s); s = fmaf(q8[k4].y, kv.y, s);
        s = fmaf(q8[k4].z, kv.z, s); s = fmaf(q8[k4].w, kv.w, s);
      }
      int jglob = j0 + kt * 32 + jb + j;
      sv[j] = (jglob < Nk) ? s : -1e30f;
    }
    float tmax = sv[0];
#pragma unroll
    for (int j = 1; j < 16; ++j) tmax = fmaxf(tmax, sv[j]);
    tmax = fmaxf(tmax, __shfl_xor(tmax, 1));
    float mnew = fmaxf(m, tmax);
    float scale = __expf(m - mnew);
    float p[16]; float psum = 0.f;
#pragma unroll
    for (int j = 0; j < 16; ++j) {
      int jglob = j0 + kt * 32 + jb + j;
      float e = (jglob < Nk) ? __expf(sv[j] - mnew) : 0.f;
      p[j] = e; psum += e;
    }
    psum += __shfl_xor(psum, 1);
    lsum = lsum * scale + psum;
    m = mnew;
#pragma unroll
    for (int i = 0; i < 16; ++i) o[i] *= scale;
    float pO[16];
#pragma unroll
    for (int j = 0; j < 16; ++j) pO[j] = __shfl_xor(p[j], 1);
    int jbO = jb ^ 16;
#pragma unroll
    for (int j = 0; j < 16; ++j) {
      float pj = p[j];
      const float* vrow = &Vt[jb + j][ho];
#pragma unroll
      for (int k = 0; k < 4; ++k) {
        float4 v4 = *(const float4*)&vrow[4 * k];
        o[4 * k + 0] = fmaf(pj, v4.x, o[4 * k + 0]);
        o[4 * k + 1] = fmaf(pj, v4.y, o[4 * k + 1]);
        o[4 * k + 2] = fmaf(pj, v4.z, o[4 * k + 2]);
        o[4 * k + 3] = fmaf(pj, v4.w, o[4 * k + 3]);
      }
    }
#pragma unroll
    for (int j = 0; j < 16; ++j) {
      float pj = pO[j];
      const float* vrow = &Vt[jbO + j][ho];
#pragma unroll
      for (int k = 0; k < 4; ++k) {
        float4 v4 = *(const float4*)&vrow[4 * k];
        o[4 * k + 0] = fmaf(pj, v4.x, o[4 * k + 0]);
        o[4 * k + 1] = fmaf(pj, v4.y, o[4 * k + 1]);
        o[4 * k + 2] = fmaf(pj, v4.z, o[4 * k + 2]);
        o[4 * k + 3] = fmaf(pj, v4.w, o[4 * k + 3]);
      }
    }
  }
  if (qi < 100) {
    float* pod = po + (long)bid * 3200 + qi * 32 + ho;
#pragma unroll
    for (int k = 0; k < 4; ++k)
      *(float4*)&pod[4 * k] = make_float4(o[4 * k], o[4 * k + 1], o[4 * k + 2], o[4 * k + 3]);
    if (half == 0) { pm[bid * 128 + qi] = m; pl[bid * 128 + qi] = lsum; }
  }
}

// --- SA combine (unchanged) -------------------------------------------------
__global__ __launch_bounds__(256) void combine_kernel(const float* __restrict__ po,
                                                      const float* __restrict__ pm,
                                                      const float* __restrict__ pl,
                                                      int4 startv, int4 nchv,
                                                      float* __restrict__ outp, int outld) {
  int bid = blockIdx.x;
  int l = bid >> 5, rr = bid & 31, b = rr >> 3, h = rr & 7;
  int nc = sel4(nchv, l);
  int sb = sel4(startv, l) + (b * 8 + h) * nc;
  int qr0 = (l * 4 + b) * 100;
  int idx = blockIdx.y * 256 + threadIdx.x;
  if (idx >= 3200) return;
  int qi = idx >> 5, hd = idx & 31;
  float mstar = -1e30f;
  for (int c = 0; c < nc; ++c) mstar = fmaxf(mstar, pm[(sb + c) * 128 + qi]);
  float Lt = 0.f, val = 0.f;
  for (int c = 0; c < nc; ++c) {
    float w = __expf(pm[(sb + c) * 128 + qi] - mstar);
    Lt = fmaf(w, pl[(sb + c) * 128 + qi], Lt);
    val = fmaf(w, po[(long)(sb + c) * 3200 + qi * 32 + hd], val);
  }
  outp[(long)(qr0 + qi) * outld + h * 32 + hd] = val / Lt;
}

// --- CA flash v2: barrier-free, LDS-free, register-resident P ---------------
// wave u = (level, b, h, ch, qg): u_rel = ((b*8+h)*nc + ch)*4 + qg.
// Scores use key-permuted A rows so lane g's score regs ARE the PV B-frag.
__global__ __launch_bounds__(256) void flash_ca2_kernel(
    const unsigned short* __restrict__ Qh, const unsigned short* __restrict__ Ql,
    const unsigned short* __restrict__ Kh, const unsigned short* __restrict__ Kl,
    const unsigned short* __restrict__ VTh, const unsigned short* __restrict__ VTl,
    float* __restrict__ po, float* __restrict__ pm, float* __restrict__ pl) {
  int tid = threadIdx.x;
  int u = blockIdx.x * 4 + (tid >> 6);
  int lane = tid & 63;
  int fr = lane & 15, g = lane >> 4;
  int base, lognc, koff, kstr, ntile, l;
  if (u < 1024)      { base = 0;    lognc = 3; koff = 0;     kstr = 4096; ntile = 16; l = 0; }
  else if (u < 1280) { base = 1024; lognc = 1; koff = 16384; kstr = 1024; ntile = 16; l = 1; }
  else if (u < 1408) { base = 1280; lognc = 0; koff = 20480; kstr = 256;  ntile = 8;  l = 2; }
  else               { base = 1408; lognc = 0; koff = 21504; kstr = 64;   ntile = 2;  l = 3; }
  int r = u - base;
  int qg = r & 3; r >>= 2;
  int ch = r & ((1 << lognc) - 1); r >>= lognc;
  int h = r & 7, b = r >> 3;
  long qoff = ((long)((l * 4 + b) * 100 + qg * 32)) * 256 + h * 32 + 8 * g;
  bf16x8 qh0 = *(const bf16x8*)&Qh[qoff + fr * 256];
  bf16x8 qh1 = *(const bf16x8*)&Qh[qoff + (16 + fr) * 256];
  bf16x8 ql0 = *(const bf16x8*)&Ql[qoff + fr * 256];
  bf16x8 ql1 = *(const bf16x8*)&Ql[qoff + (16 + fr) * 256];
  int kbase = koff + b * kstr + ch * 512;
  int kperm = 8 * (fr >> 2) + (fr & 3);   // score-row key permutation
  long vr0 = (long)(h * 32 + fr) * 21760;
  long vr1 = (long)(h * 32 + 16 + fr) * 21760;
  f32x4 o00 = {0.f, 0.f, 0.f, 0.f}, o01 = o00, o10 = o00, o11 = o00;
  float m0r = -1e30f, m1r = -1e30f, l0r = 0.f, l1r = 0.f;

  for (int kt = 0; kt < ntile; ++kt) {
    int tok0 = kbase + kt * 32;
    long ka = (long)(tok0 + kperm) * 256 + h * 32 + 8 * g;
    bf16x8 kh0 = *(const bf16x8*)&Kh[ka];
    bf16x8 kl0 = *(const bf16x8*)&Kl[ka];
    bf16x8 kh1 = *(const bf16x8*)&Kh[ka + 1024];   // key + 4 (t16=1)
    bf16x8 kl1 = *(const bf16x8*)&Kl[ka + 1024];
    bf16x8 vh0 = *(const bf16x8*)&VTh[vr0 + tok0 + 8 * g];
    bf16x8 vl0 = *(const bf16x8*)&VTl[vr0 + tok0 + 8 * g];
    bf16x8 vh1 = *(const bf16x8*)&VTh[vr1 + tok0 + 8 * g];
    bf16x8 vl1 = *(const bf16x8*)&VTl[vr1 + tok0 + 8 * g];
    f32x4 zz = {0.f, 0.f, 0.f, 0.f};
    f32x4 s00 = zz, s01 = zz, s10 = zz, s11 = zz;
    s00 = MFMA16(kh0, qh0, s00); s00 = MFMA16(kl0, qh0, s00); s00 = MFMA16(kh0, ql0, s00);
    s01 = MFMA16(kh1, qh0, s01); s01 = MFMA16(kl1, qh0, s01); s01 = MFMA16(kh1, ql0, s01);
    s10 = MFMA16(kh0, qh1, s10); s10 = MFMA16(kl0, qh1, s10); s10 = MFMA16(kh0, ql1, s10);
    s11 = MFMA16(kh1, qh1, s11); s11 = MFMA16(kl1, qh1, s11); s11 = MFMA16(kh1, ql1, s11);
    // --- softmax + PV, q-sub 0 ---
    {
      float t0 = fmaxf(fmaxf(s00[0], s00[1]), fmaxf(s00[2], s00[3]));
      float t1 = fmaxf(fmaxf(s01[0], s01[1]), fmaxf(s01[2], s01[3]));
      float tm = fmaxf(t0, t1);
      tm = fmaxf(tm, __shfl_xor(tm, 16));
      tm = fmaxf(tm, __shfl_xor(tm, 32));
      float mn = fmaxf(m0r, tm);
      float sc = __expf(m0r - mn); m0r = mn;
      float p[8]; float ps = 0.f;
#pragma unroll
      for (int i = 0; i < 4; ++i) { p[i] = __expf(s00[i] - mn); ps += p[i]; }
#pragma unroll
      for (int i = 0; i < 4; ++i) { p[4 + i] = __expf(s01[i] - mn); ps += p[4 + i]; }
      l0r = l0r * sc + ps;
      union { bf16x8 v; unsigned short us[8]; } ph, plo;
#pragma unroll
      for (int e = 0; e < 8; ++e) {
        unsigned short hi = bf_rne(p[e]);
        ph.us[e] = hi;
        plo.us[e] = bf_rne(p[e] - bf2f(hi));
      }
#pragma unroll
      for (int i = 0; i < 4; ++i) { o00[i] *= sc; o01[i] *= sc; }
      o00 = MFMA16(vh0, ph.v, o00); o00 = MFMA16(vl0, ph.v, o00); o00 = MFMA16(vh0, plo.v, o00);
      o01 = MFMA16(vh1, ph.v, o01); o01 = MFMA16(vl1, ph.v, o01); o01 = MFMA16(vh1, plo.v, o01);
    }
    // --- softmax + PV, q-sub 1 ---
    {
      float t0 = fmaxf(fmaxf(s10[0], s10[1]), fmaxf(s10[2], s10[3]));
      float t1 = fmaxf(fmaxf(s11[0], s11[1]), fmaxf(s11[2], s11[3]));
      float tm = fmaxf(t0, t1);
      tm = fmaxf(tm, __shfl_xor(tm, 16));
      tm = fmaxf(tm, __shfl_xor(tm, 32));
      float mn = fmaxf(m1r, tm);
      float sc = __expf(m1r - mn); m1r = mn;
      float p[8]; float ps = 0.f;
#pragma unroll
      for (int i = 0; i < 4; ++i) { p[i] = __expf(s10[i] - mn); ps += p[i]; }
#pragma unroll
      for (int i = 0; i < 4; ++i) { p[4 + i] = __expf(s11[i] - mn); ps += p[4 + i]; }
      l1r = l1r * sc + ps;
      union { bf16x8 v; unsigned short us[8]; } ph, plo;
#pragma unroll
      for (int e = 0; e < 8; ++e) {
        unsigned short hi = bf_rne(p[e]);
        ph.us[e] = hi;
        plo.us[e] = bf_rne(p[e] - bf2f(hi));
      }
#pragma unroll
      for (int i = 0; i < 4; ++i) { o10[i] *= sc; o11[i] *= sc; }
      o10 = MFMA16(vh0, ph.v, o10); o10 = MFMA16(vl0, ph.v, o10); o10 = MFMA16(vh0, plo.v, o10);
      o11 = MFMA16(vh1, ph.v, o11); o11 = MFMA16(vl1, ph.v, o11); o11 = MFMA16(vh1, plo.v, o11);
    }
  }
  l0r += __shfl_xor(l0r, 16); l0r += __shfl_xor(l0r, 32);
  l1r += __shfl_xor(l1r, 16); l1r += __shfl_xor(l1r, 32);
  long pob = (long)u * 1024;
  *(f32x4*)&po[pob + fr * 32 + 4 * g] = o00;
  *(f32x4*)&po[pob + fr * 32 + 16 + 4 * g] = o01;
  *(f32x4*)&po[pob + (16 + fr) * 32 + 4 * g] = o10;
  *(f32x4*)&po[pob + (16 + fr) * 32 + 16 + 4 * g] = o11;
  if (g == 0) {
    pm[u * 32 + fr] = m0r;       pl[u * 32 + fr] = l0r;
    pm[u * 32 + 16 + fr] = m1r;  pl[u * 32 + 16 + fr] = l1r;
  }
}

// --- CA combine v2: unit = (l,b,h,qg), 512 blocks ---------------------------
__global__ __launch_bounds__(256) void combine2_kernel(const float* __restrict__ po,
                                                       const float* __restrict__ pm,
                                                       const float* __restrict__ pl,
                                                       float* __restrict__ outp) {
  int u = blockIdx.x;
  int l = u >> 7, ur = u & 127;
  int b = ur >> 5, h = (ur >> 2) & 7, qg = ur & 3;
  int nc, base;
  if (l == 0)      { nc = 8; base = 0; }
  else if (l == 1) { nc = 2; base = 1024; }
  else if (l == 2) { nc = 1; base = 1280; }
  else             { nc = 1; base = 1408; }
  int pu0 = base + ((b * 8 + h) * nc) * 4 + qg;  // chunk c lives at pu0 + 4c
  int qr0 = (l * 4 + b) * 100 + qg * 32;
  int qn = min(32, 100 - qg * 32);
  for (int e = threadIdx.x; e < 1024; e += 256) {
    int qi = e >> 5, d = e & 31;
    if (qi >= qn) continue;
    float mstar = -1e30f;
    for (int c = 0; c < nc; ++c) mstar = fmaxf(mstar, pm[(pu0 + 4 * c) * 32 + qi]);
    float Lt = 0.f, val = 0.f;
    for (int c = 0; c < nc; ++c) {
      float w = __expf(pm[(pu0 + 4 * c) * 32 + qi] - mstar);
      Lt = fmaf(w, pl[(pu0 + 4 * c) * 32 + qi], Lt);
      val = fmaf(w, po[(long)(pu0 + 4 * c) * 1024 + qi * 32 + d], val);
    }
    outp[(long)(qr0 + qi) * 256 + h * 32 + d] = val / Lt;
  }
}

// --- ms = q1 @ q2^T ---------------------------------------------------------
__global__ __launch_bounds__(256) void fuse_ms_kernel(const float* __restrict__ q1,
                                                      const float* __restrict__ q2,
                                                      float* __restrict__ ms) {
  __shared__ float a[32][132];
  __shared__ float bsh[32][132];
  int lb = blockIdx.x;
  int it = blockIdx.y >> 2, jt = blockIdx.y & 3;
  int tid = threadIdx.x;
  int ti = tid & 15, tj = tid >> 4;
  float acc[2][2] = {};
  for (int chalf = 0; chalf < 2; ++chalf) {
    __syncthreads();
#pragma unroll
    for (int k = 0; k < 4; ++k) {
      int i = tid + k * 256;
      int rr = i >> 5, c4 = (i & 31) * 4;
      int row1 = it * 32 + rr, row2 = jt * 32 + rr;
      float4 fa = make_float4(0.f, 0.f, 0.f, 0.f), fb = fa;
      if (row1 < 100) fa = *(const float4*)&q1[(long)(lb * 100 + row1) * 256 + chalf * 128 + c4];
      if (row2 < 100) fb = *(const float4*)&q2[(long)(lb * 100 + row2) * 256 + chalf * 128 + c4];
      *(float4*)&a[rr][c4] = fa;
      *(float4*)&bsh[rr][c4] = fb;
    }
    __syncthreads();
#pragma unroll
    for (int k4 = 0; k4 < 32; ++k4) {
      float4 a0 = *(const float4*)&a[2 * ti][4 * k4];
      float4 a1 = *(const float4*)&a[2 * ti + 1][4 * k4];
      float4 b0 = *(const float4*)&bsh[2 * tj][4 * k4];
      float4 b1 = *(const float4*)&bsh[2 * tj + 1][4 * k4];
      acc[0][0] += dot4(a0, b0); acc[0][1] += dot4(a0, b1);
      acc[1][0] += dot4(a1, b0); acc[1][1] += dot4(a1, b1);
    }
  }
#pragma unroll
  for (int i = 0; i < 2; ++i)
#pragma unroll
    for (int j = 0; j < 2; ++j)
      ms[(long)(lb * 128 + it * 32 + 2 * ti + i) * 128 + jt * 32 + 2 * tj + j] = acc[i][j];
}

// --- row & column softmax stats of ms --------------------------------------
__global__ void fuse_stats_kernel(const float* __restrict__ ms, float* __restrict__ rst) {
  int lb = blockIdx.x, tid = threadIdx.x;
  if (tid < 100) {
    const float* row = ms + (long)(lb * 128 + tid) * 128;
    float mx = row[0];
    for (int j = 1; j < 100; ++j) mx = fmaxf(mx, row[j]);
    float s = 0.f;
    for (int j = 0; j < 100; ++j) s += __expf(row[j] - mx);
    rst[(0 * 16 + lb) * 128 + tid] = mx;
    rst[(1 * 16 + lb) * 128 + tid] = s;
  } else if (tid >= 128 && tid < 228) {
    int j = tid - 128;
    const float* colp = ms + (long)lb * 128 * 128 + j;
    float mx = colp[0];
    for (int i = 1; i < 100; ++i) mx = fmaxf(mx, colp[i * 128]);
    float s = 0.f;
    for (int i = 0; i < 100; ++i) s += __expf(colp[i * 128] - mx);
    rst[(2 * 16 + lb) * 128 + j] = mx;
    rst[(3 * 16 + lb) * 128 + j] = s;
  }
}

// --- r1/r2 mixing + final channel softmax -----------------------------------
__global__ __launch_bounds__(256) void fuse_apply_kernel(const float* __restrict__ ms,
                                                         const float* __restrict__ rst,
                                                         const float* __restrict__ q1,
                                                         const float* __restrict__ q2,
                                                         const float* __restrict__ qsa,
                                                         float* __restrict__ qout) {
  __shared__ float pr[100], pc[100];
  __shared__ float red1[4], red2[4];
  int lb = blockIdx.x, qc = blockIdx.y, tid = threadIdx.x;
  for (int ii = 0; ii < 10; ++ii) {
    int i = qc * 10 + ii;
    long r = lb * 100 + i;
    if (tid < 100) {
      float rm = rst[(0 * 16 + lb) * 128 + i], rs = rst[(1 * 16 + lb) * 128 + i];
      pr[tid] = __expf(ms[(long)(lb * 128 + i) * 128 + tid] - rm) / rs;
    } else if (tid >= 128 && tid < 228) {
      int i2 = tid - 128;
      float cm = rst[(2 * 16 + lb) * 128 + i], cs = rst[(3 * 16 + lb) * 128 + i];
      pc[i2] = __expf(ms[(long)(lb * 128 + i2) * 128 + i] - cm) / cs;
    }
    __syncthreads();
    float acc1 = 0.f, acc2 = 0.f;
    for (int j = 0; j < 100; ++j) acc1 = fmaf(pr[j], q2[(long)(lb * 100 + j) * 256 + tid], acc1);
    for (int j = 0; j < 100; ++j) acc2 = fmaf(pc[j], q1[(long)(lb * 100 + j) * 256 + tid], acc2);
    float z = qsa[r * 256 + tid] + q1[r * 256 + tid] + acc1 + q2[r * 256 + tid] + acc2;
    float v = z;
    for (int off = 32; off; off >>= 1) v = fmaxf(v, __shfl_xor(v, off));
    int w = tid >> 6;
    if ((tid & 63) == 0) red1[w] = v;
    __syncthreads();
    float zm = fmaxf(fmaxf(red1[0], red1[1]), fmaxf(red1[2], red1[3]));
    float e = __expf(z - zm);
    float sv = e;
    for (int off = 32; off; off >>= 1) sv += __shfl_xor(sv, off);
    if ((tid & 63) == 0) red2[w] = sv;
    __syncthreads();
    float es = red2[0] + red2[1] + red2[2] + red2[3];
    qout[r * 256 + tid] = e / es;
    __syncthreads();
  }
}

// ---------------------------------------------------------------------------
extern "C" void kernel_launch(void* const* d_in, const int* in_sizes, int n_in,
                              void* d_out, int out_size, void* d_ws, size_t ws_size,
                              hipStream_t stream) {
  (void)in_sizes; (void)n_in; (void)out_size; (void)ws_size;
  const float* feats[2][4] = {
      {(const float*)d_in[0], (const float*)d_in[1], (const float*)d_in[2], (const float*)d_in[3]},
      {(const float*)d_in[4], (const float*)d_in[5], (const float*)d_in[6], (const float*)d_in[7]}};
  const float* qe   = (const float*)d_in[8];
  const float* ng   = (const float*)d_in[9];
  const float* nb   = (const float*)d_in[10];
  const float* wq   = (const float*)d_in[11];
  const float* wk   = (const float*)d_in[12];
  const float* wv   = (const float*)d_in[13];
  const float* wp   = (const float*)d_in[14];
  const float* bp   = (const float*)d_in[15];
  const float* swqkv= (const float*)d_in[16];
  const float* swp  = (const float*)d_in[17];
  const float* sbp  = (const float*)d_in[18];

  float* ws = (float*)d_ws;
  unsigned short* KHp  = (unsigned short*)(ws + O_KH);
  unsigned short* KLp  = (unsigned short*)(ws + O_KL);
  unsigned short* VTHp = (unsigned short*)(ws + O_VTH);
  unsigned short* VTLp = (unsigned short*)(ws + O_VTL);
  float* QBUFp = ws + O_QBUF;
  float* QKVp  = ws + O_QKV;
  float* QSAp  = ws + O_QSA;
  float* QHATp = ws + O_QHAT;
  float* QNp   = ws + O_QN;
  float* SAOp  = ws + O_SAO;
  float* OCAp  = ws + O_OCA;
  float* Q12p  = ws + O_Q12;
  unsigned short* QHp  = (unsigned short*)(ws + O_QH);
  unsigned short* QLp  = (unsigned short*)(ws + O_QL);
  unsigned short* WTHp = (unsigned short*)(ws + O_WTH);
  unsigned short* WTLp = (unsigned short*)(ws + O_WTL);
  float* WQp   = ws + O_WQ;
  float* BKVp  = ws + O_BKV;
  float* BQp   = ws + O_BQ;
  float* POp   = ws + O_PO;
  float* PMp   = ws + O_PM;
  float* PLp   = ws + O_PL;
  float* PO2p  = ws + O_PO2;
  float* PM2p  = ws + O_PM2;
  float* PL2p  = ws + O_PL2;
  float* MSp   = ws + O_MS;
  float* RSTp  = ws + O_RST;
  float* STATSp= ws + O_STATS;

  const int HWs[4] = {4096, 1024, 256, 64};
  const int VOs[4] = {0, 16384, 20480, 21504};

  fold_w2_kernel<<<4608, 256, 0, stream>>>(ng, wk, wv, wq, WTHp, WTLp, WQp);
  fold_b_kernel<<<18, 256, 0, stream>>>(nb, wk, wv, wq, BKVp, BQp);
  for (int v = 0; v < 2; ++v)
    for (int l = 0; l < 4; ++l)
      ln_stats_kernel<<<dim3(HWs[l] / 64, 4), 256, 0, stream>>>(
          feats[v][l], STATSp, v * 21760 + VOs[l], HWs[l]);
  init_q_kernel<<<1600, 256, 0, stream>>>(qe, QBUFp);

  const int4 saStart = make_int4(0, 32, 64, 96);
  const int4 saNch   = make_int4(1, 1, 1, 1);
  const int4 saNk    = make_int4(100, 100, 100, 100);
  const int4 saKoff  = make_int4(0, 400, 800, 1200);
  const int4 saKstrb = make_int4(100, 100, 100, 100);

  for (int d = 0; d < 6; ++d) {
    // --- self attention ---
    gemm256_kernel<<<dim3(12, 25), 256, 0, stream>>>(QBUFp, swqkv + (long)d * 196608, nullptr,
                                                     QKVp, 1600, 768);
    flash_kernel<<<128, 256, 0, stream>>>(QKVp, 768, QKVp + 256, QKVp + 512, 768,
                                          saStart, saNch, saNk, saKoff, saKstrb, POp, PMp, PLp);
    combine_kernel<<<dim3(128, 13), 256, 0, stream>>>(POp, PMp, PLp, saStart, saNch, SAOp, 256);
    gemm256_kernel<<<dim3(4, 25), 256, 0, stream>>>(SAOp, swp + (long)d * 65536, sbp + d * 256,
                                                    QSAp, 1600, 256);
    // --- cross-attention query projection + split ---
    row_ln_kernel<<<1600, 256, 0, stream>>>(QSAp, QHATp);
    gemm256_kernel<<<dim3(4, 25), 256, 0, stream>>>(QHATp, WQp + (long)d * 65536, BQp + d * 256,
                                                    QNp, 1600, 256);
    split_q_kernel<<<1632, 256, 0, stream>>>(QNp, QHp, QLp);
    // --- cross attention per view ---
    for (int v = 0; v < 2; ++v) {
      gemm_kv_mfma_kernel<<<dim3(8, 340), 256, 0, stream>>>(
          feats[v][0], feats[v][1], feats[v][2], feats[v][3], STATSp, v * 21760,
          WTHp + (long)d * 131072, WTLp + (long)d * 131072, BKVp + d * 512,
          KHp, KLp, VTHp, VTLp);
      flash_ca2_kernel<<<384, 256, 0, stream>>>(QHp, QLp, KHp, KLp, VTHp, VTLp,
                                                PO2p, PM2p, PL2p);
      combine2_kernel<<<512, 256, 0, stream>>>(PO2p, PM2p, PL2p, OCAp + (long)v * 409600);
    }
    gemm256_kernel<<<dim3(4, 50), 256, 0, stream>>>(OCAp, wp + (long)d * 65536, bp + d * 256,
                                                    Q12p, 3200, 256);
    // --- matching fusion + channel softmax ---
    fuse_ms_kernel<<<dim3(16, 16), 256, 0, stream>>>(Q12p, Q12p + 409600, MSp);
    fuse_stats_kernel<<<16, 256, 0, stream>>>(MSp, RSTp);
    fuse_apply_kernel<<<dim3(16, 10), 256, 0, stream>>>(MSp, RSTp, Q12p, Q12p + 409600,
                                                        QSAp, QBUFp);
  }
  hipMemcpyAsync(d_out, QBUFp, 409600 * sizeof(float), hipMemcpyDeviceToDevice, stream);
}

// Round 6
// 2412.117 us; speedup vs baseline: 1.1560x; 1.0103x over previous
//
#include <hip/hip_runtime.h>

// ---------------------------------------------------------------------------
// VolumeAttention: 4 feature levels x 6 decoder depths, B=4, NQ=100, C=256, H=8
// Round 6:
//  - ln_split_x: LN-normalized split-bf16 token matrix Xh/Xl [43520][256]
//    built ONCE per call (was re-staged 8 n-blocks x 12 dispatches).
//  - gemm_kv v3: grid (2 n-halves, 340 m-tiles), LDS-free, barrier-free;
//    MFMA frags read directly from global (X/W are L2-resident), K row-major
//    out, V^T via ushort4 register stores.
//  - CA flash v2 / SA path unchanged from round 5.
// ws: ~125 MB.
// ---------------------------------------------------------------------------

#define DI __device__ __forceinline__
#define MFMA16(a, b, c) __builtin_amdgcn_mfma_f32_16x16x32_bf16(a, b, c, 0, 0, 0)

typedef __attribute__((ext_vector_type(8))) short bf16x8;
typedef __attribute__((ext_vector_type(8))) unsigned short u16x8;
typedef __attribute__((ext_vector_type(4))) float f32x4;

// ws offsets in floats
constexpr long O_KH    = 0;                        // [21760][256] ushort hi
constexpr long O_KL    = O_KH   + 2785280;         // [21760][256] ushort lo
constexpr long O_VTH   = O_KL   + 2785280;         // [256][21760] ushort hi
constexpr long O_VTL   = O_VTH  + 2785280;         // [256][21760] ushort lo
constexpr long O_QBUF  = O_VTL  + 2785280;         // [1600][256]
constexpr long O_QKV   = O_QBUF + 409600;          // [1600][768]
constexpr long O_QSA   = O_QKV  + 1228800;         // [1600][256]
constexpr long O_QHAT  = O_QSA  + 409600;          // [1600][256]
constexpr long O_QN    = O_QHAT + 409600;          // [1600][256]
constexpr long O_SAO   = O_QN   + 409600;          // [1600][256]
constexpr long O_OCA   = O_SAO  + 409600;          // [2][1600][256]
constexpr long O_Q12   = O_OCA  + 819200;          // [2][1600][256]
constexpr long O_QH    = O_Q12  + 819200;          // [1632][256] ushort hi
constexpr long O_QL    = O_QH   + 208896;          // [1632][256] ushort lo
constexpr long O_WTH   = O_QL   + 208896;          // [6][512][256] ushort hi
constexpr long O_WTL   = O_WTH  + 393216;          // [6][512][256] ushort lo
constexpr long O_WQ    = O_WTL  + 393216;          // [6][256][256] fp32
constexpr long O_BKV   = O_WQ   + 393216;          // [6][512]
constexpr long O_BQ    = O_BKV  + 3072;            // [6][256]
constexpr long O_PO    = O_BQ   + 1536;            // [128][3200] SA partials
constexpr long O_PM    = O_PO   + 409600;          // [128][128]
constexpr long O_PL    = O_PM   + 16384;           // [128][128]
constexpr long O_PO2   = O_PL   + 16384;           // [1536][1024] CA partials
constexpr long O_PM2   = O_PO2  + 1572864;         // [1536][32]
constexpr long O_PL2   = O_PM2  + 49152;           // [1536][32]
constexpr long O_MS    = O_PL2  + 49152;           // [16][128][128]
constexpr long O_RST   = O_MS   + 262144;          // [4][16][128]
constexpr long O_STATS = O_RST  + 8192;            // [43520][2]
constexpr long O_XH    = O_STATS + 87040;          // [43520][256] ushort hi
constexpr long O_XL    = O_XH   + 5570560;         // [43520][256] ushort lo
constexpr long WS_FLOATS = O_XL + 5570560;         // ~125 MB

DI int sel4(int4 v, int i) { return i == 0 ? v.x : (i == 1 ? v.y : (i == 2 ? v.z : v.w)); }
DI float dot4(float4 a, float4 b) {
  float s = a.x * b.x;
  s = fmaf(a.y, b.y, s); s = fmaf(a.z, b.z, s); s = fmaf(a.w, b.w, s);
  return s;
}
DI unsigned short bf_rne(float x) {
  unsigned u = __float_as_uint(x);
  u += 0x7fffu + ((u >> 16) & 1u);
  return (unsigned short)(u >> 16);
}
DI float bf2f(unsigned short h) { return __uint_as_float(((unsigned)h) << 16); }

// --- fold LN affine into projections; KV weights -> transposed split-bf16 --
__global__ void fold_w2_kernel(const float* __restrict__ ng, const float* __restrict__ wk,
                               const float* __restrict__ wv, const float* __restrict__ wq,
                               unsigned short* __restrict__ WTh, unsigned short* __restrict__ WTl,
                               float* __restrict__ wqo) {
  long idx = (long)blockIdx.x * 256 + threadIdx.x;
  const long T1 = 6L * 512 * 256;
  if (idx < T1) {
    int d = idx / (512 * 256); int r = idx % (512 * 256); int n = r / 256; int k = r % 256;
    float g = ng[d * 256 + k];
    float w = (n < 256) ? wk[((long)(d * 256 + k)) * 256 + n]
                        : wv[((long)(d * 256 + k)) * 256 + (n - 256)];
    w *= g;
    unsigned short h = bf_rne(w);
    WTh[idx] = h;
    WTl[idx] = bf_rne(w - bf2f(h));
  } else {
    long j = idx - T1;
    if (j < 6L * 256 * 256) {
      int d = j / 65536; int r = j % 65536; int c = r / 256; int n = r % 256;
      wqo[j] = ng[d * 256 + c] * wq[((long)(d * 256 + c)) * 256 + n];
    }
  }
}

__global__ void fold_b_kernel(const float* __restrict__ nb, const float* __restrict__ wk,
                              const float* __restrict__ wv, const float* __restrict__ wq,
                              float* __restrict__ bkvo, float* __restrict__ bqo) {
  int idx = blockIdx.x * 256 + threadIdx.x;
  if (idx >= 6 * 768) return;
  int d = idx / 768, j = idx % 768;
  float s = 0.f;
  if (j < 256) {
    for (int c = 0; c < 256; ++c) s = fmaf(nb[d * 256 + c], wk[(d * 256 + c) * 256 + j], s);
    bkvo[d * 512 + j] = s;
  } else if (j < 512) {
    int n = j - 256;
    for (int c = 0; c < 256; ++c) s = fmaf(nb[d * 256 + c], wv[(d * 256 + c) * 256 + n], s);
    bkvo[d * 512 + j] = s;
  } else {
    int n = j - 512;
    for (int c = 0; c < 256; ++c) s = fmaf(nb[d * 256 + c], wq[(d * 256 + c) * 256 + n], s);
    bqo[d * 256 + n] = s;
  }
}

// --- per-token LN statistics of feature maps ------------------------------
__global__ __launch_bounds__(256) void ln_stats_kernel(const float* __restrict__ feat,
                                                       float* __restrict__ stats,
                                                       int rowBase, int HW) {
  __shared__ float sred[4][64];
  __shared__ float qred[4][64];
  int b = blockIdx.y, t0 = blockIdx.x * 64;
  int tx = threadIdx.x & 63, ty = threadIdx.x >> 6;
  const float* fb = feat + (long)b * 256 * HW;
  float s = 0.f, q = 0.f;
  for (int k = 0; k < 64; ++k) {
    int c = ty * 64 + k;
    float v = fb[(long)c * HW + t0 + tx];
    s += v; q += v * v;
  }
  sred[ty][tx] = s; qred[ty][tx] = q;
  __syncthreads();
  if (ty == 0) {
    float ts = sred[0][tx] + sred[1][tx] + sred[2][tx] + sred[3][tx];
    float tq = qred[0][tx] + qred[1][tx] + qred[2][tx] + qred[3][tx];
    float m = ts * (1.f / 256.f);
    float var = tq * (1.f / 256.f) - m * m;
    int row = rowBase + b * HW + t0 + tx;
    stats[row * 2 + 0] = m;
    stats[row * 2 + 1] = rsqrtf(var + 1e-5f);
  }
}

// --- build LN-normalized split-bf16 X [tok][256] once per call -------------
// block = 64 tokens of one view; LDS transpose for coalesced writes.
__global__ __launch_bounds__(256) void ln_split_x_kernel(
    const float* __restrict__ f0, const float* __restrict__ f1,
    const float* __restrict__ f2, const float* __restrict__ f3,
    const float* __restrict__ stats, int vbase,
    unsigned short* __restrict__ Xh, unsigned short* __restrict__ Xl) {
  __shared__ unsigned short Th[64][66], Tl[64][66];
  int m0 = blockIdx.x * 64;
  const float* fp; int HW, rel;
  if (m0 < 16384)      { fp = f0; HW = 4096; rel = m0; }
  else if (m0 < 20480) { fp = f1; HW = 1024; rel = m0 - 16384; }
  else if (m0 < 21504) { fp = f2; HW = 256;  rel = m0 - 20480; }
  else                 { fp = f3; HW = 64;   rel = m0 - 21504; }
  int b = rel / HW, t0 = rel % HW;
  const float* fb = fp + (long)b * 256 * HW + t0;
  int t = threadIdx.x & 63, cg4 = threadIdx.x >> 6;
  float mean = stats[(vbase + m0 + t) * 2 + 0];
  float rstd = stats[(vbase + m0 + t) * 2 + 1];
  int r = threadIdx.x >> 2, s = (threadIdx.x & 3) * 16;
  for (int cgo = 0; cgo < 4; ++cgo) {
    if (cgo) __syncthreads();
#pragma unroll
    for (int i = 0; i < 16; ++i) {
      int c = cgo * 64 + cg4 * 16 + i;
      float x = (fb[(long)c * HW + t] - mean) * rstd;
      unsigned short hi = bf_rne(x);
      Th[t][cg4 * 16 + i] = hi;
      Tl[t][cg4 * 16 + i] = bf_rne(x - bf2f(hi));
    }
    __syncthreads();
    union { ushort2 u2[8]; u16x8 v8[2]; } th, tl;
#pragma unroll
    for (int k = 0; k < 8; ++k) {
      th.u2[k] = *(const ushort2*)&Th[r][s + 2 * k];
      tl.u2[k] = *(const ushort2*)&Tl[r][s + 2 * k];
    }
    long dst = (long)(vbase + m0 + r) * 256 + cgo * 64 + s;
    *(u16x8*)&Xh[dst] = th.v8[0];
    *(u16x8*)&Xh[dst + 8] = th.v8[1];
    *(u16x8*)&Xl[dst] = tl.v8[0];
    *(u16x8*)&Xl[dst + 8] = tl.v8[1];
  }
}

__global__ void init_q_kernel(const float* __restrict__ qe, float* __restrict__ qb) {
  int idx = blockIdx.x * 256 + threadIdx.x;
  if (idx < 1600 * 256) {
    int row = idx >> 8, c = idx & 255;
    qb[idx] = qe[(row % 100) * 256 + c];
  }
}

// --- split/scale Q for CA flash: Qh/Ql [1632][256], pad rows zeroed --------
__global__ void split_q_kernel(const float* __restrict__ qn,
                               unsigned short* __restrict__ Qh,
                               unsigned short* __restrict__ Ql) {
  int idx = blockIdx.x * 256 + threadIdx.x;
  if (idx >= 1632 * 256) return;
  float v = (idx < 1600 * 256) ? qn[idx] * 0.17677669529663689f : 0.f;
  unsigned short hi = bf_rne(v);
  Qh[idx] = hi;
  Ql[idx] = bf_rne(v - bf2f(hi));
}

// --- generic fp32 GEMM: C[M,N] = A[M,256] @ W[256,N] (+bias) --------------
__global__ __launch_bounds__(256) void gemm256_kernel(const float* __restrict__ A,
                                                      const float* __restrict__ W,
                                                      const float* __restrict__ bias,
                                                      float* __restrict__ Co, int M, int N) {
  __shared__ float As[32][68];
  __shared__ float Ws[32][68];
  int tid = threadIdx.x;
  int tm = tid & 15, tn = tid >> 4;
  int m0 = blockIdx.y * 64, n0 = blockIdx.x * 64;
  float acc[4][4] = {};
  for (int kt = 0; kt < 8; ++kt) {
    __syncthreads();
#pragma unroll
    for (int it = 0; it < 2; ++it) {
      int i = tid + it * 256;
      int r = i >> 3, c4 = (i & 7) * 4;
      float4 f = *(const float4*)&A[(long)(m0 + r) * 256 + kt * 32 + c4];
      As[c4 + 0][r] = f.x; As[c4 + 1][r] = f.y; As[c4 + 2][r] = f.z; As[c4 + 3][r] = f.w;
    }
#pragma unroll
    for (int it = 0; it < 2; ++it) {
      int i = tid + it * 256;
      int r = i >> 4, c4 = (i & 15) * 4;
      *(float4*)&Ws[r][c4] = *(const float4*)&W[(long)(kt * 32 + r) * N + n0 + c4];
    }
    __syncthreads();
#pragma unroll
    for (int k = 0; k < 32; ++k) {
      float4 a4 = *(const float4*)&As[k][4 * tm];
      float4 b4 = *(const float4*)&Ws[k][4 * tn];
      float av[4] = {a4.x, a4.y, a4.z, a4.w};
      float bv[4] = {b4.x, b4.y, b4.z, b4.w};
#pragma unroll
      for (int i = 0; i < 4; ++i)
#pragma unroll
        for (int j = 0; j < 4; ++j) acc[i][j] = fmaf(av[i], bv[j], acc[i][j]);
    }
  }
  float bv4[4] = {0.f, 0.f, 0.f, 0.f};
  if (bias) {
#pragma unroll
    for (int j = 0; j < 4; ++j) bv4[j] = bias[n0 + 4 * tn + j];
  }
#pragma unroll
  for (int i = 0; i < 4; ++i) {
    int row = m0 + 4 * tm + i;
    float4 o;
    o.x = acc[i][0] + bv4[0]; o.y = acc[i][1] + bv4[1];
    o.z = acc[i][2] + bv4[2]; o.w = acc[i][3] + bv4[3];
    *(float4*)&Co[(long)row * N + n0 + 4 * tn] = o;
  }
}

// --- KV projection v3: LDS-free, barrier-free, full-N-half per block --------
// grid (2, 340): x=0 -> K (n 0..255), x=1 -> V (n 256..511). 4 waves; wave w
// owns n-sub w*16 of each 64-n chunk; 4 m-tiles of 16 tokens each.
__global__ __launch_bounds__(256) void gemm_kv3_kernel(
    const unsigned short* __restrict__ Xh, const unsigned short* __restrict__ Xl,
    const unsigned short* __restrict__ Wh, const unsigned short* __restrict__ Wl,
    const float* __restrict__ bias,
    unsigned short* __restrict__ Kh, unsigned short* __restrict__ Kl,
    unsigned short* __restrict__ VTh, unsigned short* __restrict__ VTl) {
  int nh = blockIdx.x;
  int m0 = blockIdx.y * 64;
  int tid = threadIdx.x;
  int w = tid >> 6, lane = tid & 63;
  int fr = lane & 15, g = lane >> 4;
  int nb0 = nh * 256 + w * 16 + fr;   // + c4*64
  f32x4 acc[4][4];
#pragma unroll
  for (int c4 = 0; c4 < 4; ++c4)
#pragma unroll
    for (int mt = 0; mt < 4; ++mt)
#pragma unroll
      for (int r = 0; r < 4; ++r) acc[c4][mt][r] = 0.f;
  for (int ks = 0; ks < 8; ++ks) {
    int k0 = ks * 32 + 8 * g;
    bf16x8 ah[4], al[4];
#pragma unroll
    for (int mt = 0; mt < 4; ++mt) {
      long ar = (long)(m0 + mt * 16 + fr) * 256 + k0;
      ah[mt] = *(const bf16x8*)&Xh[ar];
      al[mt] = *(const bf16x8*)&Xl[ar];
    }
#pragma unroll
    for (int c4 = 0; c4 < 4; ++c4) {
      long br = (long)(nb0 + c4 * 64) * 256 + k0;
      bf16x8 bh = *(const bf16x8*)&Wh[br];
      bf16x8 bl = *(const bf16x8*)&Wl[br];
#pragma unroll
      for (int mt = 0; mt < 4; ++mt) {
        acc[c4][mt] = MFMA16(ah[mt], bh, acc[c4][mt]);
        acc[c4][mt] = MFMA16(al[mt], bh, acc[c4][mt]);
        acc[c4][mt] = MFMA16(ah[mt], bl, acc[c4][mt]);
      }
    }
  }
  if (nh == 0) {
#pragma unroll
    for (int c4 = 0; c4 < 4; ++c4) {
      int n = c4 * 64 + w * 16 + fr;
      float bv = bias[n];
#pragma unroll
      for (int mt = 0; mt < 4; ++mt)
#pragma unroll
        for (int r = 0; r < 4; ++r) {
          float val = acc[c4][mt][r] + bv;
          long off = (long)(m0 + mt * 16 + 4 * g + r) * 256 + n;
          unsigned short hi = bf_rne(val);
          Kh[off] = hi;
          Kl[off] = bf_rne(val - bf2f(hi));
        }
    }
  } else {
#pragma unroll
    for (int c4 = 0; c4 < 4; ++c4) {
      int nv = c4 * 64 + w * 16 + fr;
      float bv = bias[256 + nv];
#pragma unroll
      for (int mt = 0; mt < 4; ++mt) {
        float v0 = acc[c4][mt][0] + bv;
        float v1 = acc[c4][mt][1] + bv;
        float v2 = acc[c4][mt][2] + bv;
        float v3 = acc[c4][mt][3] + bv;
        ushort4 uh, ul;
        uh.x = bf_rne(v0); ul.x = bf_rne(v0 - bf2f(uh.x));
        uh.y = bf_rne(v1); ul.y = bf_rne(v1 - bf2f(uh.y));
        uh.z = bf_rne(v2); ul.z = bf_rne(v2 - bf2f(uh.z));
        uh.w = bf_rne(v3); ul.w = bf_rne(v3 - bf2f(uh.w));
        long off = (long)nv * 21760 + m0 + mt * 16 + 4 * g;
        *(ushort4*)&VTh[off] = uh;
        *(ushort4*)&VTl[off] = ul;
      }
    }
  }
}

// --- row LayerNorm (no affine) ---------------------------------------------
__global__ __launch_bounds__(256) void row_ln_kernel(const float* __restrict__ in,
                                                     float* __restrict__ out) {
  __shared__ float s1[4], s2[4];
  long r = blockIdx.x;
  float x = in[r * 256 + threadIdx.x];
  float vs = x, vq = x * x;
  for (int o = 32; o; o >>= 1) { vs += __shfl_xor(vs, o); vq += __shfl_xor(vq, o); }
  int w = threadIdx.x >> 6;
  if ((threadIdx.x & 63) == 0) { s1[w] = vs; s2[w] = vq; }
  __syncthreads();
  float ts = s1[0] + s1[1] + s1[2] + s1[3];
  float tq = s2[0] + s2[1] + s2[2] + s2[3];
  float m = ts * (1.f / 256.f);
  float var = tq * (1.f / 256.f) - m * m;
  out[r * 256 + threadIdx.x] = (x - m) * rsqrtf(var + 1e-5f);
}

// --- SA flash (VALU path, unchanged) ---------------------------------------
__global__ __launch_bounds__(256) void flash_kernel(const float* __restrict__ qp, int qld,
                                                    const float* __restrict__ kb,
                                                    const float* __restrict__ vb, int kvld,
                                                    int4 startv, int4 nchv, int4 nkv,
                                                    int4 koffv, int4 kstrbv,
                                                    float* __restrict__ po,
                                                    float* __restrict__ pm,
                                                    float* __restrict__ pl) {
  __shared__ float Kt[32][36];
  __shared__ float Vt[32][36];
  int bid = blockIdx.x;
  int s1 = startv.y, s2 = startv.z, s3 = startv.w;
  int l = (bid < s1) ? 0 : (bid < s2) ? 1 : (bid < s3) ? 2 : 3;
  int r = bid - sel4(startv, l);
  int nc = sel4(nchv, l);
  int b = r / (8 * nc);
  int h = (r / nc) & 7;
  int ch = r % nc;
  int Nk = sel4(nkv, l);
  int qr0 = (l * 4 + b) * 100;
  int kr0 = sel4(koffv, l) + b * sel4(kstrbv, l);
  int j0 = ch * 128;
  int jn = min(128, Nk - j0);
  int tiles = (jn + 31) >> 5;
  int tid = threadIdx.x;
  int qi = tid >> 1, half = tid & 1, ho = half * 16, jb = half * 16;
  const float SC = 0.17677669529663689f;
  float4 q8[8];
  if (qi < 100) {
    const float* qrow = qp + (long)(qr0 + qi) * qld + h * 32;
#pragma unroll
    for (int k = 0; k < 8; ++k) {
      float4 f = *(const float4*)&qrow[4 * k];
      q8[k] = make_float4(f.x * SC, f.y * SC, f.z * SC, f.w * SC);
    }
  } else {
#pragma unroll
    for (int k = 0; k < 8; ++k) q8[k] = make_float4(0.f, 0.f, 0.f, 0.f);
  }
  float m = -1e30f, lsum = 0.f;
  float o[16];
#pragma unroll
  for (int i = 0; i < 16; ++i) o[i] = 0.f;

  for (int kt = 0; kt < tiles; ++kt) {
    __syncthreads();
    {
      int rr = tid >> 3, c4 = (tid & 7) * 4;
      int jr = kt * 32 + rr;
      float4 kf = make_float4(0.f, 0.f, 0.f, 0.f), vf = kf;
      if (jr < jn) {
        long g = (long)(kr0 + j0 + jr) * kvld + h * 32 + c4;
        kf = *(const float4*)&kb[g];
        vf = *(const float4*)&vb[g];
      }
      *(float4*)&Kt[rr][c4 ^ (rr & 16)] = kf;
      *(float4*)&Vt[rr][c4] = vf;
    }
    __syncthreads();
    float sv[16];
#pragma unroll
    for (int j = 0; j < 16; ++j) {
      float s = 0.f;
#pragma unroll
      for (int k4 = 0; k4 < 8; ++k4) {
        float4 kv = *(const float4*)&Kt[jb + j][(4 * k4) ^ jb];
        s = fmaf(q8[k4].x, kv.x, s); s = fmaf(q8[k4].y, kv.y, s);
        s = fmaf(q8[k4].z, kv.z, s); s = fmaf(q8[k4].w, kv.w, s);
      }
      int jglob = j0 + kt * 32 + jb + j;
      sv[j] = (jglob < Nk) ? s : -1e30f;
    }
    float tmax = sv[0];
#pragma unroll
    for (int j = 1; j < 16; ++j) tmax = fmaxf(tmax, sv[j]);
    tmax = fmaxf(tmax, __shfl_xor(tmax, 1));
    float mnew = fmaxf(m, tmax);
    float scale = __expf(m - mnew);
    float p[16]; float psum = 0.f;
#pragma unroll
    for (int j = 0; j < 16; ++j) {
      int jglob = j0 + kt * 32 + jb + j;
      float e = (jglob < Nk) ? __expf(sv[j] - mnew) : 0.f;
      p[j] = e; psum += e;
    }
    psum += __shfl_xor(psum, 1);
    lsum = lsum * scale + psum;
    m = mnew;
#pragma unroll
    for (int i = 0; i < 16; ++i) o[i] *= scale;
    float pO[16];
#pragma unroll
    for (int j = 0; j < 16; ++j) pO[j] = __shfl_xor(p[j], 1);
    int jbO = jb ^ 16;
#pragma unroll
    for (int j = 0; j < 16; ++j) {
      float pj = p[j];
      const float* vrow = &Vt[jb + j][ho];
#pragma unroll
      for (int k = 0; k < 4; ++k) {
        float4 v4 = *(const float4*)&vrow[4 * k];
        o[4 * k + 0] = fmaf(pj, v4.x, o[4 * k + 0]);
        o[4 * k + 1] = fmaf(pj, v4.y, o[4 * k + 1]);
        o[4 * k + 2] = fmaf(pj, v4.z, o[4 * k + 2]);
        o[4 * k + 3] = fmaf(pj, v4.w, o[4 * k + 3]);
      }
    }
#pragma unroll
    for (int j = 0; j < 16; ++j) {
      float pj = pO[j];
      const float* vrow = &Vt[jbO + j][ho];
#pragma unroll
      for (int k = 0; k < 4; ++k) {
        float4 v4 = *(const float4*)&vrow[4 * k];
        o[4 * k + 0] = fmaf(pj, v4.x, o[4 * k + 0]);
        o[4 * k + 1] = fmaf(pj, v4.y, o[4 * k + 1]);
        o[4 * k + 2] = fmaf(pj, v4.z, o[4 * k + 2]);
        o[4 * k + 3] = fmaf(pj, v4.w, o[4 * k + 3]);
      }
    }
  }
  if (qi < 100) {
    float* pod = po + (long)bid * 3200 + qi * 32 + ho;
#pragma unroll
    for (int k = 0; k < 4; ++k)
      *(float4*)&pod[4 * k] = make_float4(o[4 * k], o[4 * k + 1], o[4 * k + 2], o[4 * k + 3]);
    if (half == 0) { pm[bid * 128 + qi] = m; pl[bid * 128 + qi] = lsum; }
  }
}

// --- SA combine (unchanged) -------------------------------------------------
__global__ __launch_bounds__(256) void combine_kernel(const float* __restrict__ po,
                                                      const float* __restrict__ pm,
                                                      const float* __restrict__ pl,
                                                      int4 startv, int4 nchv,
                                                      float* __restrict__ outp, int outld) {
  int bid = blockIdx.x;
  int l = bid >> 5, rr = bid & 31, b = rr >> 3, h = rr & 7;
  int nc = sel4(nchv, l);
  int sb = sel4(startv, l) + (b * 8 + h) * nc;
  int qr0 = (l * 4 + b) * 100;
  int idx = blockIdx.y * 256 + threadIdx.x;
  if (idx >= 3200) return;
  int qi = idx >> 5, hd = idx & 31;
  float mstar = -1e30f;
  for (int c = 0; c < nc; ++c) mstar = fmaxf(mstar, pm[(sb + c) * 128 + qi]);
  float Lt = 0.f, val = 0.f;
  for (int c = 0; c < nc; ++c) {
    float w = __expf(pm[(sb + c) * 128 + qi] - mstar);
    Lt = fmaf(w, pl[(sb + c) * 128 + qi], Lt);
    val = fmaf(w, po[(long)(sb + c) * 3200 + qi * 32 + hd], val);
  }
  outp[(long)(qr0 + qi) * outld + h * 32 + hd] = val / Lt;
}

// --- CA flash v2: barrier-free, LDS-free, register-resident P ---------------
__global__ __launch_bounds__(256) void flash_ca2_kernel(
    const unsigned short* __restrict__ Qh, const unsigned short* __restrict__ Ql,
    const unsigned short* __restrict__ Kh, const unsigned short* __restrict__ Kl,
    const unsigned short* __restrict__ VTh, const unsigned short* __restrict__ VTl,
    float* __restrict__ po, float* __restrict__ pm, float* __restrict__ pl) {
  int tid = threadIdx.x;
  int u = blockIdx.x * 4 + (tid >> 6);
  int lane = tid & 63;
  int fr = lane & 15, g = lane >> 4;
  int base, lognc, koff, kstr, ntile, l;
  if (u < 1024)      { base = 0;    lognc = 3; koff = 0;     kstr = 4096; ntile = 16; l = 0; }
  else if (u < 1280) { base = 1024; lognc = 1; koff = 16384; kstr = 1024; ntile = 16; l = 1; }
  else if (u < 1408) { base = 1280; lognc = 0; koff = 20480; kstr = 256;  ntile = 8;  l = 2; }
  else               { base = 1408; lognc = 0; koff = 21504; kstr = 64;   ntile = 2;  l = 3; }
  int r = u - base;
  int qg = r & 3; r >>= 2;
  int ch = r & ((1 << lognc) - 1); r >>= lognc;
  int h = r & 7, b = r >> 3;
  long qoff = ((long)((l * 4 + b) * 100 + qg * 32)) * 256 + h * 32 + 8 * g;
  bf16x8 qh0 = *(const bf16x8*)&Qh[qoff + fr * 256];
  bf16x8 qh1 = *(const bf16x8*)&Qh[qoff + (16 + fr) * 256];
  bf16x8 ql0 = *(const bf16x8*)&Ql[qoff + fr * 256];
  bf16x8 ql1 = *(const bf16x8*)&Ql[qoff + (16 + fr) * 256];
  int kbase = koff + b * kstr + ch * 512;
  int kperm = 8 * (fr >> 2) + (fr & 3);
  long vr0 = (long)(h * 32 + fr) * 21760;
  long vr1 = (long)(h * 32 + 16 + fr) * 21760;
  f32x4 o00 = {0.f, 0.f, 0.f, 0.f}, o01 = o00, o10 = o00, o11 = o00;
  float m0r = -1e30f, m1r = -1e30f, l0r = 0.f, l1r = 0.f;

  for (int kt = 0; kt < ntile; ++kt) {
    int tok0 = kbase + kt * 32;
    long ka = (long)(tok0 + kperm) * 256 + h * 32 + 8 * g;
    bf16x8 kh0 = *(const bf16x8*)&Kh[ka];
    bf16x8 kl0 = *(const bf16x8*)&Kl[ka];
    bf16x8 kh1 = *(const bf16x8*)&Kh[ka + 1024];
    bf16x8 kl1 = *(const bf16x8*)&Kl[ka + 1024];
    bf16x8 vh0 = *(const bf16x8*)&VTh[vr0 + tok0 + 8 * g];
    bf16x8 vl0 = *(const bf16x8*)&VTl[vr0 + tok0 + 8 * g];
    bf16x8 vh1 = *(const bf16x8*)&VTh[vr1 + tok0 + 8 * g];
    bf16x8 vl1 = *(const bf16x8*)&VTl[vr1 + tok0 + 8 * g];
    f32x4 zz = {0.f, 0.f, 0.f, 0.f};
    f32x4 s00 = zz, s01 = zz, s10 = zz, s11 = zz;
    s00 = MFMA16(kh0, qh0, s00); s00 = MFMA16(kl0, qh0, s00); s00 = MFMA16(kh0, ql0, s00);
    s01 = MFMA16(kh1, qh0, s01); s01 = MFMA16(kl1, qh0, s01); s01 = MFMA16(kh1, ql0, s01);
    s10 = MFMA16(kh0, qh1, s10); s10 = MFMA16(kl0, qh1, s10); s10 = MFMA16(kh0, ql1, s10);
    s11 = MFMA16(kh1, qh1, s11); s11 = MFMA16(kl1, qh1, s11); s11 = MFMA16(kh1, ql1, s11);
    {
      float t0 = fmaxf(fmaxf(s00[0], s00[1]), fmaxf(s00[2], s00[3]));
      float t1 = fmaxf(fmaxf(s01[0], s01[1]), fmaxf(s01[2], s01[3]));
      float tm = fmaxf(t0, t1);
      tm = fmaxf(tm, __shfl_xor(tm, 16));
      tm = fmaxf(tm, __shfl_xor(tm, 32));
      float mn = fmaxf(m0r, tm);
      float sc = __expf(m0r - mn); m0r = mn;
      float p[8]; float ps = 0.f;
#pragma unroll
      for (int i = 0; i < 4; ++i) { p[i] = __expf(s00[i] - mn); ps += p[i]; }
#pragma unroll
      for (int i = 0; i < 4; ++i) { p[4 + i] = __expf(s01[i] - mn); ps += p[4 + i]; }
      l0r = l0r * sc + ps;
      union { bf16x8 v; unsigned short us[8]; } ph, plo;
#pragma unroll
      for (int e = 0; e < 8; ++e) {
        unsigned short hi = bf_rne(p[e]);
        ph.us[e] = hi;
        plo.us[e] = bf_rne(p[e] - bf2f(hi));
      }
#pragma unroll
      for (int i = 0; i < 4; ++i) { o00[i] *= sc; o01[i] *= sc; }
      o00 = MFMA16(vh0, ph.v, o00); o00 = MFMA16(vl0, ph.v, o00); o00 = MFMA16(vh0, plo.v, o00);
      o01 = MFMA16(vh1, ph.v, o01); o01 = MFMA16(vl1, ph.v, o01); o01 = MFMA16(vh1, plo.v, o01);
    }
    {
      float t0 = fmaxf(fmaxf(s10[0], s10[1]), fmaxf(s10[2], s10[3]));
      float t1 = fmaxf(fmaxf(s11[0], s11[1]), fmaxf(s11[2], s11[3]));
      float tm = fmaxf(t0, t1);
      tm = fmaxf(tm, __shfl_xor(tm, 16));
      tm = fmaxf(tm, __shfl_xor(tm, 32));
      float mn = fmaxf(m1r, tm);
      float sc = __expf(m1r - mn); m1r = mn;
      float p[8]; float ps = 0.f;
#pragma unroll
      for (int i = 0; i < 4; ++i) { p[i] = __expf(s10[i] - mn); ps += p[i]; }
#pragma unroll
      for (int i = 0; i < 4; ++i) { p[4 + i] = __expf(s11[i] - mn); ps += p[4 + i]; }
      l1r = l1r * sc + ps;
      union { bf16x8 v; unsigned short us[8]; } ph, plo;
#pragma unroll
      for (int e = 0; e < 8; ++e) {
        unsigned short hi = bf_rne(p[e]);
        ph.us[e] = hi;
        plo.us[e] = bf_rne(p[e] - bf2f(hi));
      }
#pragma unroll
      for (int i = 0; i < 4; ++i) { o10[i] *= sc; o11[i] *= sc; }
      o10 = MFMA16(vh0, ph.v, o10); o10 = MFMA16(vl0, ph.v, o10); o10 = MFMA16(vh0, plo.v, o10);
      o11 = MFMA16(vh1, ph.v, o11); o11 = MFMA16(vl1, ph.v, o11); o11 = MFMA16(vh1, plo.v, o11);
    }
  }
  l0r += __shfl_xor(l0r, 16); l0r += __shfl_xor(l0r, 32);
  l1r += __shfl_xor(l1r, 16); l1r += __shfl_xor(l1r, 32);
  long pob = (long)u * 1024;
  *(f32x4*)&po[pob + fr * 32 + 4 * g] = o00;
  *(f32x4*)&po[pob + fr * 32 + 16 + 4 * g] = o01;
  *(f32x4*)&po[pob + (16 + fr) * 32 + 4 * g] = o10;
  *(f32x4*)&po[pob + (16 + fr) * 32 + 16 + 4 * g] = o11;
  if (g == 0) {
    pm[u * 32 + fr] = m0r;       pl[u * 32 + fr] = l0r;
    pm[u * 32 + 16 + fr] = m1r;  pl[u * 32 + 16 + fr] = l1r;
  }
}

// --- CA combine v2: unit = (l,b,h,qg), 512 blocks ---------------------------
__global__ __launch_bounds__(256) void combine2_kernel(const float* __restrict__ po,
                                                       const float* __restrict__ pm,
                                                       const float* __restrict__ pl,
                                                       float* __restrict__ outp) {
  int u = blockIdx.x;
  int l = u >> 7, ur = u & 127;
  int b = ur >> 5, h = (ur >> 2) & 7, qg = ur & 3;
  int nc, base;
  if (l == 0)      { nc = 8; base = 0; }
  else if (l == 1) { nc = 2; base = 1024; }
  else if (l == 2) { nc = 1; base = 1280; }
  else             { nc = 1; base = 1408; }
  int pu0 = base + ((b * 8 + h) * nc) * 4 + qg;
  int qr0 = (l * 4 + b) * 100 + qg * 32;
  int qn = min(32, 100 - qg * 32);
  for (int e = threadIdx.x; e < 1024; e += 256) {
    int qi = e >> 5, d = e & 31;
    if (qi >= qn) continue;
    float mstar = -1e30f;
    for (int c = 0; c < nc; ++c) mstar = fmaxf(mstar, pm[(pu0 + 4 * c) * 32 + qi]);
    float Lt = 0.f, val = 0.f;
    for (int c = 0; c < nc; ++c) {
      float w = __expf(pm[(pu0 + 4 * c) * 32 + qi] - mstar);
      Lt = fmaf(w, pl[(pu0 + 4 * c) * 32 + qi], Lt);
      val = fmaf(w, po[(long)(pu0 + 4 * c) * 1024 + qi * 32 + d], val);
    }
    outp[(long)(qr0 + qi) * 256 + h * 32 + d] = val / Lt;
  }
}

// --- ms = q1 @ q2^T ---------------------------------------------------------
__global__ __launch_bounds__(256) void fuse_ms_kernel(const float* __restrict__ q1,
                                                      const float* __restrict__ q2,
                                                      float* __restrict__ ms) {
  __shared__ float a[32][132];
  __shared__ float bsh[32][132];
  int lb = blockIdx.x;
  int it = blockIdx.y >> 2, jt = blockIdx.y & 3;
  int tid = threadIdx.x;
  int ti = tid & 15, tj = tid >> 4;
  float acc[2][2] = {};
  for (int chalf = 0; chalf < 2; ++chalf) {
    __syncthreads();
#pragma unroll
    for (int k = 0; k < 4; ++k) {
      int i = tid + k * 256;
      int rr = i >> 5, c4 = (i & 31) * 4;
      int row1 = it * 32 + rr, row2 = jt * 32 + rr;
      float4 fa = make_float4(0.f, 0.f, 0.f, 0.f), fb = fa;
      if (row1 < 100) fa = *(const float4*)&q1[(long)(lb * 100 + row1) * 256 + chalf * 128 + c4];
      if (row2 < 100) fb = *(const float4*)&q2[(long)(lb * 100 + row2) * 256 + chalf * 128 + c4];
      *(float4*)&a[rr][c4] = fa;
      *(float4*)&bsh[rr][c4] = fb;
    }
    __syncthreads();
#pragma unroll
    for (int k4 = 0; k4 < 32; ++k4) {
      float4 a0 = *(const float4*)&a[2 * ti][4 * k4];
      float4 a1 = *(const float4*)&a[2 * ti + 1][4 * k4];
      float4 b0 = *(const float4*)&bsh[2 * tj][4 * k4];
      float4 b1 = *(const float4*)&bsh[2 * tj + 1][4 * k4];
      acc[0][0] += dot4(a0, b0); acc[0][1] += dot4(a0, b1);
      acc[1][0] += dot4(a1, b0); acc[1][1] += dot4(a1, b1);
    }
  }
#pragma unroll
  for (int i = 0; i < 2; ++i)
#pragma unroll
    for (int j = 0; j < 2; ++j)
      ms[(long)(lb * 128 + it * 32 + 2 * ti + i) * 128 + jt * 32 + 2 * tj + j] = acc[i][j];
}

// --- row & column softmax stats of ms --------------------------------------
__global__ void fuse_stats_kernel(const float* __restrict__ ms, float* __restrict__ rst) {
  int lb = blockIdx.x, tid = threadIdx.x;
  if (tid < 100) {
    const float* row = ms + (long)(lb * 128 + tid) * 128;
    float mx = row[0];
    for (int j = 1; j < 100; ++j) mx = fmaxf(mx, row[j]);
    float s = 0.f;
    for (int j = 0; j < 100; ++j) s += __expf(row[j] - mx);
    rst[(0 * 16 + lb) * 128 + tid] = mx;
    rst[(1 * 16 + lb) * 128 + tid] = s;
  } else if (tid >= 128 && tid < 228) {
    int j = tid - 128;
    const float* colp = ms + (long)lb * 128 * 128 + j;
    float mx = colp[0];
    for (int i = 1; i < 100; ++i) mx = fmaxf(mx, colp[i * 128]);
    float s = 0.f;
    for (int i = 0; i < 100; ++i) s += __expf(colp[i * 128] - mx);
    rst[(2 * 16 + lb) * 128 + j] = mx;
    rst[(3 * 16 + lb) * 128 + j] = s;
  }
}

// --- r1/r2 mixing + final channel softmax -----------------------------------
__global__ __launch_bounds__(256) void fuse_apply_kernel(const float* __restrict__ ms,
                                                         const float* __restrict__ rst,
                                                         const float* __restrict__ q1,
                                                         const float* __restrict__ q2,
                                                         const float* __restrict__ qsa,
                                                         float* __restrict__ qout) {
  __shared__ float pr[100], pc[100];
  __shared__ float red1[4], red2[4];
  int lb = blockIdx.x, qc = blockIdx.y, tid = threadIdx.x;
  for (int ii = 0; ii < 10; ++ii) {
    int i = qc * 10 + ii;
    long r = lb * 100 + i;
    if (tid < 100) {
      float rm = rst[(0 * 16 + lb) * 128 + i], rs = rst[(1 * 16 + lb) * 128 + i];
      pr[tid] = __expf(ms[(long)(lb * 128 + i) * 128 + tid] - rm) / rs;
    } else if (tid >= 128 && tid < 228) {
      int i2 = tid - 128;
      float cm = rst[(2 * 16 + lb) * 128 + i], cs = rst[(3 * 16 + lb) * 128 + i];
      pc[i2] = __expf(ms[(long)(lb * 128 + i2) * 128 + i] - cm) / cs;
    }
    __syncthreads();
    float acc1 = 0.f, acc2 = 0.f;
    for (int j = 0; j < 100; ++j) acc1 = fmaf(pr[j], q2[(long)(lb * 100 + j) * 256 + tid], acc1);
    for (int j = 0; j < 100; ++j) acc2 = fmaf(pc[j], q1[(long)(lb * 100 + j) * 256 + tid], acc2);
    float z = qsa[r * 256 + tid] + q1[r * 256 + tid] + acc1 + q2[r * 256 + tid] + acc2;
    float v = z;
    for (int off = 32; off; off >>= 1) v = fmaxf(v, __shfl_xor(v, off));
    int w = tid >> 6;
    if ((tid & 63) == 0) red1[w] = v;
    __syncthreads();
    float zm = fmaxf(fmaxf(red1[0], red1[1]), fmaxf(red1[2], red1[3]));
    float e = __expf(z - zm);
    float sv = e;
    for (int off = 32; off; off >>= 1) sv += __shfl_xor(sv, off);
    if ((tid & 63) == 0) red2[w] = sv;
    __syncthreads();
    float es = red2[0] + red2[1] + red2[2] + red2[3];
    qout[r * 256 + tid] = e / es;
    __syncthreads();
  }
}

// ---------------------------------------------------------------------------
extern "C" void kernel_launch(void* const* d_in, const int* in_sizes, int n_in,
                              void* d_out, int out_size, void* d_ws, size_t ws_size,
                              hipStream_t stream) {
  (void)in_sizes; (void)n_in; (void)out_size; (void)ws_size;
  const float* feats[2][4] = {
      {(const float*)d_in[0], (const float*)d_in[1], (const float*)d_in[2], (const float*)d_in[3]},
      {(const float*)d_in[4], (const float*)d_in[5], (const float*)d_in[6], (const float*)d_in[7]}};
  const float* qe   = (const float*)d_in[8];
  const float* ng   = (const float*)d_in[9];
  const float* nb   = (const float*)d_in[10];
  const float* wq   = (const float*)d_in[11];
  const float* wk   = (const float*)d_in[12];
  const float* wv   = (const float*)d_in[13];
  const float* wp   = (const float*)d_in[14];
  const float* bp   = (const float*)d_in[15];
  const float* swqkv= (const float*)d_in[16];
  const float* swp  = (const float*)d_in[17];
  const float* sbp  = (const float*)d_in[18];

  float* ws = (float*)d_ws;
  unsigned short* KHp  = (unsigned short*)(ws + O_KH);
  unsigned short* KLp  = (unsigned short*)(ws + O_KL);
  unsigned short* VTHp = (unsigned short*)(ws + O_VTH);
  unsigned short* VTLp = (unsigned short*)(ws + O_VTL);
  float* QBUFp = ws + O_QBUF;
  float* QKVp  = ws + O_QKV;
  float* QSAp  = ws + O_QSA;
  float* QHATp = ws + O_QHAT;
  float* QNp   = ws + O_QN;
  float* SAOp  = ws + O_SAO;
  float* OCAp  = ws + O_OCA;
  float* Q12p  = ws + O_Q12;
  unsigned short* QHp  = (unsigned short*)(ws + O_QH);
  unsigned short* QLp  = (unsigned short*)(ws + O_QL);
  unsigned short* WTHp = (unsigned short*)(ws + O_WTH);
  unsigned short* WTLp = (unsigned short*)(ws + O_WTL);
  float* WQp   = ws + O_WQ;
  float* BKVp  = ws + O_BKV;
  float* BQp   = ws + O_BQ;
  float* POp   = ws + O_PO;
  float* PMp   = ws + O_PM;
  float* PLp   = ws + O_PL;
  float* PO2p  = ws + O_PO2;
  float* PM2p  = ws + O_PM2;
  float* PL2p  = ws + O_PL2;
  float* MSp   = ws + O_MS;
  float* RSTp  = ws + O_RST;
  float* STATSp= ws + O_STATS;
  unsigned short* XHp  = (unsigned short*)(ws + O_XH);
  unsigned short* XLp  = (unsigned short*)(ws + O_XL);

  const int HWs[4] = {4096, 1024, 256, 64};
  const int VOs[4] = {0, 16384, 20480, 21504};

  fold_w2_kernel<<<4608, 256, 0, stream>>>(ng, wk, wv, wq, WTHp, WTLp, WQp);
  fold_b_kernel<<<18, 256, 0, stream>>>(nb, wk, wv, wq, BKVp, BQp);
  for (int v = 0; v < 2; ++v)
    for (int l = 0; l < 4; ++l)
      ln_stats_kernel<<<dim3(HWs[l] / 64, 4), 256, 0, stream>>>(
          feats[v][l], STATSp, v * 21760 + VOs[l], HWs[l]);
  for (int v = 0; v < 2; ++v)
    ln_split_x_kernel<<<340, 256, 0, stream>>>(
        feats[v][0], feats[v][1], feats[v][2], feats[v][3], STATSp, v * 21760, XHp, XLp);
  init_q_kernel<<<1600, 256, 0, stream>>>(qe, QBUFp);

  const int4 saStart = make_int4(0, 32, 64, 96);
  const int4 saNch   = make_int4(1, 1, 1, 1);
  const int4 saNk    = make_int4(100, 100, 100, 100);
  const int4 saKoff  = make_int4(0, 400, 800, 1200);
  const int4 saKstrb = make_int4(100, 100, 100, 100);

  for (int d = 0; d < 6; ++d) {
    // --- self attention ---
    gemm256_kernel<<<dim3(12, 25), 256, 0, stream>>>(QBUFp, swqkv + (long)d * 196608, nullptr,
                                                     QKVp, 1600, 768);
    flash_kernel<<<128, 256, 0, stream>>>(QKVp, 768, QKVp + 256, QKVp + 512, 768,
                                          saStart, saNch, saNk, saKoff, saKstrb, POp, PMp, PLp);
    combine_kernel<<<dim3(128, 13), 256, 0, stream>>>(POp, PMp, PLp, saStart, saNch, SAOp, 256);
    gemm256_kernel<<<dim3(4, 25), 256, 0, stream>>>(SAOp, swp + (long)d * 65536, sbp + d * 256,
                                                    QSAp, 1600, 256);
    // --- cross-attention query projection + split ---
    row_ln_kernel<<<1600, 256, 0, stream>>>(QSAp, QHATp);
    gemm256_kernel<<<dim3(4, 25), 256, 0, stream>>>(QHATp, WQp + (long)d * 65536, BQp + d * 256,
                                                    QNp, 1600, 256);
    split_q_kernel<<<1632, 256, 0, stream>>>(QNp, QHp, QLp);
    // --- cross attention per view ---
    for (int v = 0; v < 2; ++v) {
      gemm_kv3_kernel<<<dim3(2, 340), 256, 0, stream>>>(
          XHp + (long)v * 5570560, XLp + (long)v * 5570560,
          WTHp + (long)d * 131072, WTLp + (long)d * 131072, BKVp + d * 512,
          KHp, KLp, VTHp, VTLp);
      flash_ca2_kernel<<<384, 256, 0, stream>>>(QHp, QLp, KHp, KLp, VTHp, VTLp,
                                                PO2p, PM2p, PL2p);
      combine2_kernel<<<512, 256, 0, stream>>>(PO2p, PM2p, PL2p, OCAp + (long)v * 409600);
    }
    gemm256_kernel<<<dim3(4, 50), 256, 0, stream>>>(OCAp, wp + (long)d * 65536, bp + d * 256,
                                                    Q12p, 3200, 256);
    // --- matching fusion + channel softmax ---
    fuse_ms_kernel<<<dim3(16, 16), 256, 0, stream>>>(Q12p, Q12p + 409600, MSp);
    fuse_stats_kernel<<<16, 256, 0, stream>>>(MSp, RSTp);
    fuse_apply_kernel<<<dim3(16, 10), 256, 0, stream>>>(MSp, RSTp, Q12p, Q12p + 409600,
                                                        QSAp, QBUFp);
  }
  hipMemcpyAsync(d_out, QBUFp, 409600 * sizeof(float), hipMemcpyDeviceToDevice, stream);
}

// Round 8
// 2305.633 us; speedup vs baseline: 1.2094x; 1.0462x over previous
//
#include <hip/hip_runtime.h>

// ---------------------------------------------------------------------------
// VolumeAttention: 4 feature levels x 6 decoder depths, B=4, NQ=100, C=256, H=8
// Round 8 (= round 7 + fix):
//  - FIX: ln_split_x was called with BOTH a pre-offset X pointer AND vbase,
//    double-offsetting view 1's writes (view-1 X was poison). Pass un-offset
//    pointers; vbase places the view (round-6 convention).
//  - gemm_kv4: BM=64 x BN=128, hoisted frags, both views in one dispatch.
//  - flash_ca2 / combine2 merged across views.
// ---------------------------------------------------------------------------

#define DI __device__ __forceinline__
#define MFMA16(a, b, c) __builtin_amdgcn_mfma_f32_16x16x32_bf16(a, b, c, 0, 0, 0)

typedef __attribute__((ext_vector_type(8))) short bf16x8;
typedef __attribute__((ext_vector_type(8))) unsigned short u16x8;
typedef __attribute__((ext_vector_type(4))) float f32x4;

constexpr long KVV = 5570560;   // ushorts per view (21760*256)

// ws offsets in floats
constexpr long O_KH    = 0;                        // [2][21760][256] ushort hi
constexpr long O_KL    = O_KH   + 5570560;         // [2][21760][256] ushort lo
constexpr long O_VTH   = O_KL   + 5570560;         // [2][256][21760] ushort hi
constexpr long O_VTL   = O_VTH  + 5570560;         // [2][256][21760] ushort lo
constexpr long O_QBUF  = O_VTL  + 5570560;         // [1600][256]
constexpr long O_QKV   = O_QBUF + 409600;          // [1600][768]
constexpr long O_QSA   = O_QKV  + 1228800;         // [1600][256]
constexpr long O_QHAT  = O_QSA  + 409600;          // [1600][256]
constexpr long O_QN    = O_QHAT + 409600;          // [1600][256]
constexpr long O_SAO   = O_QN   + 409600;          // [1600][256]
constexpr long O_OCA   = O_SAO  + 409600;          // [2][1600][256]
constexpr long O_Q12   = O_OCA  + 819200;          // [2][1600][256]
constexpr long O_QH    = O_Q12  + 819200;          // [1632][256] ushort hi
constexpr long O_QL    = O_QH   + 208896;          // [1632][256] ushort lo
constexpr long O_WTH   = O_QL   + 208896;          // [6][512][256] ushort hi
constexpr long O_WTL   = O_WTH  + 393216;          // [6][512][256] ushort lo
constexpr long O_WQ    = O_WTL  + 393216;          // [6][256][256] fp32
constexpr long O_BKV   = O_WQ   + 393216;          // [6][512]
constexpr long O_BQ    = O_BKV  + 3072;            // [6][256]
constexpr long O_PO    = O_BQ   + 1536;            // [128][3200] SA partials
constexpr long O_PM    = O_PO   + 409600;          // [128][128]
constexpr long O_PL    = O_PM   + 16384;           // [128][128]
constexpr long O_PO2   = O_PL   + 16384;           // [3072][1024] CA partials
constexpr long O_PM2   = O_PO2  + 3145728;         // [3072][32]
constexpr long O_PL2   = O_PM2  + 98304;           // [3072][32]
constexpr long O_MS    = O_PL2  + 98304;           // [16][128][128]
constexpr long O_RST   = O_MS   + 262144;          // [4][16][128]
constexpr long O_STATS = O_RST  + 8192;            // [43520][2]
constexpr long O_XH    = O_STATS + 87040;          // [2][21760][256] ushort hi
constexpr long O_XL    = O_XH   + 5570560;         // [2][21760][256] ushort lo
constexpr long WS_FLOATS = O_XL + 5570560;         // ~176 MB

DI int sel4(int4 v, int i) { return i == 0 ? v.x : (i == 1 ? v.y : (i == 2 ? v.z : v.w)); }
DI float dot4(float4 a, float4 b) {
  float s = a.x * b.x;
  s = fmaf(a.y, b.y, s); s = fmaf(a.z, b.z, s); s = fmaf(a.w, b.w, s);
  return s;
}
DI unsigned short bf_rne(float x) {
  unsigned u = __float_as_uint(x);
  u += 0x7fffu + ((u >> 16) & 1u);
  return (unsigned short)(u >> 16);
}
DI float bf2f(unsigned short h) { return __uint_as_float(((unsigned)h) << 16); }

// --- fold LN affine into projections; KV weights -> transposed split-bf16 --
__global__ void fold_w2_kernel(const float* __restrict__ ng, const float* __restrict__ wk,
                               const float* __restrict__ wv, const float* __restrict__ wq,
                               unsigned short* __restrict__ WTh, unsigned short* __restrict__ WTl,
                               float* __restrict__ wqo) {
  long idx = (long)blockIdx.x * 256 + threadIdx.x;
  const long T1 = 6L * 512 * 256;
  if (idx < T1) {
    int d = idx / (512 * 256); int r = idx % (512 * 256); int n = r / 256; int k = r % 256;
    float g = ng[d * 256 + k];
    float w = (n < 256) ? wk[((long)(d * 256 + k)) * 256 + n]
                        : wv[((long)(d * 256 + k)) * 256 + (n - 256)];
    w *= g;
    unsigned short h = bf_rne(w);
    WTh[idx] = h;
    WTl[idx] = bf_rne(w - bf2f(h));
  } else {
    long j = idx - T1;
    if (j < 6L * 256 * 256) {
      int d = j / 65536; int r = j % 65536; int c = r / 256; int n = r % 256;
      wqo[j] = ng[d * 256 + c] * wq[((long)(d * 256 + c)) * 256 + n];
    }
  }
}

__global__ void fold_b_kernel(const float* __restrict__ nb, const float* __restrict__ wk,
                              const float* __restrict__ wv, const float* __restrict__ wq,
                              float* __restrict__ bkvo, float* __restrict__ bqo) {
  int idx = blockIdx.x * 256 + threadIdx.x;
  if (idx >= 6 * 768) return;
  int d = idx / 768, j = idx % 768;
  float s = 0.f;
  if (j < 256) {
    for (int c = 0; c < 256; ++c) s = fmaf(nb[d * 256 + c], wk[(d * 256 + c) * 256 + j], s);
    bkvo[d * 512 + j] = s;
  } else if (j < 512) {
    int n = j - 256;
    for (int c = 0; c < 256; ++c) s = fmaf(nb[d * 256 + c], wv[(d * 256 + c) * 256 + n], s);
    bkvo[d * 512 + j] = s;
  } else {
    int n = j - 512;
    for (int c = 0; c < 256; ++c) s = fmaf(nb[d * 256 + c], wq[(d * 256 + c) * 256 + n], s);
    bqo[d * 256 + n] = s;
  }
}

// --- per-token LN statistics of feature maps ------------------------------
__global__ __launch_bounds__(256) void ln_stats_kernel(const float* __restrict__ feat,
                                                       float* __restrict__ stats,
                                                       int rowBase, int HW) {
  __shared__ float sred[4][64];
  __shared__ float qred[4][64];
  int b = blockIdx.y, t0 = blockIdx.x * 64;
  int tx = threadIdx.x & 63, ty = threadIdx.x >> 6;
  const float* fb = feat + (long)b * 256 * HW;
  float s = 0.f, q = 0.f;
  for (int k = 0; k < 64; ++k) {
    int c = ty * 64 + k;
    float v = fb[(long)c * HW + t0 + tx];
    s += v; q += v * v;
  }
  sred[ty][tx] = s; qred[ty][tx] = q;
  __syncthreads();
  if (ty == 0) {
    float ts = sred[0][tx] + sred[1][tx] + sred[2][tx] + sred[3][tx];
    float tq = qred[0][tx] + qred[1][tx] + qred[2][tx] + qred[3][tx];
    float m = ts * (1.f / 256.f);
    float var = tq * (1.f / 256.f) - m * m;
    int row = rowBase + b * HW + t0 + tx;
    stats[row * 2 + 0] = m;
    stats[row * 2 + 1] = rsqrtf(var + 1e-5f);
  }
}

// --- build LN-normalized split-bf16 X [tok][256] once per call -------------
// NOTE: dst uses vbase; callers must pass UN-offset Xh/Xl (round-7 bug fix).
__global__ __launch_bounds__(256) void ln_split_x_kernel(
    const float* __restrict__ f0, const float* __restrict__ f1,
    const float* __restrict__ f2, const float* __restrict__ f3,
    const float* __restrict__ stats, int vbase,
    unsigned short* __restrict__ Xh, unsigned short* __restrict__ Xl) {
  __shared__ unsigned short Th[64][66], Tl[64][66];
  int m0 = blockIdx.x * 64;
  const float* fp; int HW, rel;
  if (m0 < 16384)      { fp = f0; HW = 4096; rel = m0; }
  else if (m0 < 20480) { fp = f1; HW = 1024; rel = m0 - 16384; }
  else if (m0 < 21504) { fp = f2; HW = 256;  rel = m0 - 20480; }
  else                 { fp = f3; HW = 64;   rel = m0 - 21504; }
  int b = rel / HW, t0 = rel % HW;
  const float* fb = fp + (long)b * 256 * HW + t0;
  int t = threadIdx.x & 63, cg4 = threadIdx.x >> 6;
  float mean = stats[(vbase + m0 + t) * 2 + 0];
  float rstd = stats[(vbase + m0 + t) * 2 + 1];
  int r = threadIdx.x >> 2, s = (threadIdx.x & 3) * 16;
  for (int cgo = 0; cgo < 4; ++cgo) {
    if (cgo) __syncthreads();
#pragma unroll
    for (int i = 0; i < 16; ++i) {
      int c = cgo * 64 + cg4 * 16 + i;
      float x = (fb[(long)c * HW + t] - mean) * rstd;
      unsigned short hi = bf_rne(x);
      Th[t][cg4 * 16 + i] = hi;
      Tl[t][cg4 * 16 + i] = bf_rne(x - bf2f(hi));
    }
    __syncthreads();
    union { ushort2 u2[8]; u16x8 v8[2]; } th, tl;
#pragma unroll
    for (int k = 0; k < 8; ++k) {
      th.u2[k] = *(const ushort2*)&Th[r][s + 2 * k];
      tl.u2[k] = *(const ushort2*)&Tl[r][s + 2 * k];
    }
    long dst = (long)(vbase + m0 + r) * 256 + cgo * 64 + s;
    *(u16x8*)&Xh[dst] = th.v8[0];
    *(u16x8*)&Xh[dst + 8] = th.v8[1];
    *(u16x8*)&Xl[dst] = tl.v8[0];
    *(u16x8*)&Xl[dst + 8] = tl.v8[1];
  }
}

__global__ void init_q_kernel(const float* __restrict__ qe, float* __restrict__ qb) {
  int idx = blockIdx.x * 256 + threadIdx.x;
  if (idx < 1600 * 256) {
    int row = idx >> 8, c = idx & 255;
    qb[idx] = qe[(row % 100) * 256 + c];
  }
}

// --- split/scale Q for CA flash: Qh/Ql [1632][256], pad rows zeroed --------
__global__ void split_q_kernel(const float* __restrict__ qn,
                               unsigned short* __restrict__ Qh,
                               unsigned short* __restrict__ Ql) {
  int idx = blockIdx.x * 256 + threadIdx.x;
  if (idx >= 1632 * 256) return;
  float v = (idx < 1600 * 256) ? qn[idx] * 0.17677669529663689f : 0.f;
  unsigned short hi = bf_rne(v);
  Qh[idx] = hi;
  Ql[idx] = bf_rne(v - bf2f(hi));
}

// --- generic fp32 GEMM: C[M,N] = A[M,256] @ W[256,N] (+bias) --------------
__global__ __launch_bounds__(256) void gemm256_kernel(const float* __restrict__ A,
                                                      const float* __restrict__ W,
                                                      const float* __restrict__ bias,
                                                      float* __restrict__ Co, int M, int N) {
  __shared__ float As[32][68];
  __shared__ float Ws[32][68];
  int tid = threadIdx.x;
  int tm = tid & 15, tn = tid >> 4;
  int m0 = blockIdx.y * 64, n0 = blockIdx.x * 64;
  float acc[4][4] = {};
  for (int kt = 0; kt < 8; ++kt) {
    __syncthreads();
#pragma unroll
    for (int it = 0; it < 2; ++it) {
      int i = tid + it * 256;
      int r = i >> 3, c4 = (i & 7) * 4;
      float4 f = *(const float4*)&A[(long)(m0 + r) * 256 + kt * 32 + c4];
      As[c4 + 0][r] = f.x; As[c4 + 1][r] = f.y; As[c4 + 2][r] = f.z; As[c4 + 3][r] = f.w;
    }
#pragma unroll
    for (int it = 0; it < 2; ++it) {
      int i = tid + it * 256;
      int r = i >> 4, c4 = (i & 15) * 4;
      *(float4*)&Ws[r][c4] = *(const float4*)&W[(long)(kt * 32 + r) * N + n0 + c4];
    }
    __syncthreads();
#pragma unroll
    for (int k = 0; k < 32; ++k) {
      float4 a4 = *(const float4*)&As[k][4 * tm];
      float4 b4 = *(const float4*)&Ws[k][4 * tn];
      float av[4] = {a4.x, a4.y, a4.z, a4.w};
      float bv[4] = {b4.x, b4.y, b4.z, b4.w};
#pragma unroll
      for (int i = 0; i < 4; ++i)
#pragma unroll
        for (int j = 0; j < 4; ++j) acc[i][j] = fmaf(av[i], bv[j], acc[i][j]);
    }
  }
  float bv4[4] = {0.f, 0.f, 0.f, 0.f};
  if (bias) {
#pragma unroll
    for (int j = 0; j < 4; ++j) bv4[j] = bias[n0 + 4 * tn + j];
  }
#pragma unroll
  for (int i = 0; i < 4; ++i) {
    int row = m0 + 4 * tm + i;
    float4 o;
    o.x = acc[i][0] + bv4[0]; o.y = acc[i][1] + bv4[1];
    o.z = acc[i][2] + bv4[2]; o.w = acc[i][3] + bv4[3];
    *(float4*)&Co[(long)row * N + n0 + 4 * tn] = o;
  }
}

// --- KV projection v4: BM=64 x BN=128, both views, hoisted frags ------------
__global__ __launch_bounds__(256) void gemm_kv4_kernel(
    const unsigned short* __restrict__ Xh, const unsigned short* __restrict__ Xl,
    const unsigned short* __restrict__ Wh, const unsigned short* __restrict__ Wl,
    const float* __restrict__ bias,
    unsigned short* __restrict__ Kh, unsigned short* __restrict__ Kl,
    unsigned short* __restrict__ VTh, unsigned short* __restrict__ VTl) {
  int nq = blockIdx.x;
  int m0 = blockIdx.y * 64;
  int v = blockIdx.z;
  int tid = threadIdx.x;
  int w = tid >> 6, lane = tid & 63;
  int fr = lane & 15, g = lane >> 4;
  int n0 = nq * 128;
  int nb0 = n0 + w * 16 + fr;
  const unsigned short* Xhb = Xh + (long)v * KVV;
  const unsigned short* Xlb = Xl + (long)v * KVV;
  f32x4 acc[2][4];
#pragma unroll
  for (int c4 = 0; c4 < 2; ++c4)
#pragma unroll
    for (int mt = 0; mt < 4; ++mt)
#pragma unroll
      for (int r = 0; r < 4; ++r) acc[c4][mt][r] = 0.f;
  for (int ks = 0; ks < 8; ++ks) {
    int k0 = ks * 32 + 8 * g;
    bf16x8 ah[4], al[4], bh[2], bl[2];
#pragma unroll
    for (int mt = 0; mt < 4; ++mt) {
      long ar = (long)(m0 + mt * 16 + fr) * 256 + k0;
      ah[mt] = *(const bf16x8*)&Xhb[ar];
      al[mt] = *(const bf16x8*)&Xlb[ar];
    }
#pragma unroll
    for (int c4 = 0; c4 < 2; ++c4) {
      long br = (long)(nb0 + c4 * 64) * 256 + k0;
      bh[c4] = *(const bf16x8*)&Wh[br];
      bl[c4] = *(const bf16x8*)&Wl[br];
    }
#pragma unroll
    for (int c4 = 0; c4 < 2; ++c4)
#pragma unroll
      for (int mt = 0; mt < 4; ++mt) {
        acc[c4][mt] = MFMA16(ah[mt], bh[c4], acc[c4][mt]);
        acc[c4][mt] = MFMA16(al[mt], bh[c4], acc[c4][mt]);
        acc[c4][mt] = MFMA16(ah[mt], bl[c4], acc[c4][mt]);
      }
  }
  long kvoff = (long)v * KVV;
  if (n0 < 256) {
#pragma unroll
    for (int c4 = 0; c4 < 2; ++c4) {
      int n = n0 + c4 * 64 + w * 16 + fr;
      float bv = bias[n];
#pragma unroll
      for (int mt = 0; mt < 4; ++mt)
#pragma unroll
        for (int r = 0; r < 4; ++r) {
          float val = acc[c4][mt][r] + bv;
          long off = kvoff + (long)(m0 + mt * 16 + 4 * g + r) * 256 + n;
          unsigned short hi = bf_rne(val);
          Kh[off] = hi;
          Kl[off] = bf_rne(val - bf2f(hi));
        }
    }
  } else {
#pragma unroll
    for (int c4 = 0; c4 < 2; ++c4) {
      int nv = n0 - 256 + c4 * 64 + w * 16 + fr;
      float bv = bias[256 + nv];
#pragma unroll
      for (int mt = 0; mt < 4; ++mt) {
        float v0 = acc[c4][mt][0] + bv;
        float v1 = acc[c4][mt][1] + bv;
        float v2 = acc[c4][mt][2] + bv;
        float v3 = acc[c4][mt][3] + bv;
        ushort4 uh, ul;
        uh.x = bf_rne(v0); ul.x = bf_rne(v0 - bf2f(uh.x));
        uh.y = bf_rne(v1); ul.y = bf_rne(v1 - bf2f(uh.y));
        uh.z = bf_rne(v2); ul.z = bf_rne(v2 - bf2f(uh.z));
        uh.w = bf_rne(v3); ul.w = bf_rne(v3 - bf2f(uh.w));
        long off = kvoff + (long)nv * 21760 + m0 + mt * 16 + 4 * g;
        *(ushort4*)&VTh[off] = uh;
        *(ushort4*)&VTl[off] = ul;
      }
    }
  }
}

// --- row LayerNorm (no affine) ---------------------------------------------
__global__ __launch_bounds__(256) void row_ln_kernel(const float* __restrict__ in,
                                                     float* __restrict__ out) {
  __shared__ float s1[4], s2[4];
  long r = blockIdx.x;
  float x = in[r * 256 + threadIdx.x];
  float vs = x, vq = x * x;
  for (int o = 32; o; o >>= 1) { vs += __shfl_xor(vs, o); vq += __shfl_xor(vq, o); }
  int w = threadIdx.x >> 6;
  if ((threadIdx.x & 63) == 0) { s1[w] = vs; s2[w] = vq; }
  __syncthreads();
  float ts = s1[0] + s1[1] + s1[2] + s1[3];
  float tq = s2[0] + s2[1] + s2[2] + s2[3];
  float m = ts * (1.f / 256.f);
  float var = tq * (1.f / 256.f) - m * m;
  out[r * 256 + threadIdx.x] = (x - m) * rsqrtf(var + 1e-5f);
}

// --- SA flash (VALU path) ---------------------------------------------------
__global__ __launch_bounds__(256) void flash_kernel(const float* __restrict__ qp, int qld,
                                                    const float* __restrict__ kb,
                                                    const float* __restrict__ vb, int kvld,
                                                    int4 startv, int4 nchv, int4 nkv,
                                                    int4 koffv, int4 kstrbv,
                                                    float* __restrict__ po,
                                                    float* __restrict__ pm,
                                                    float* __restrict__ pl) {
  __shared__ float Kt[32][36];
  __shared__ float Vt[32][36];
  int bid = blockIdx.x;
  int s1 = startv.y, s2 = startv.z, s3 = startv.w;
  int l = (bid < s1) ? 0 : (bid < s2) ? 1 : (bid < s3) ? 2 : 3;
  int r = bid - sel4(startv, l);
  int nc = sel4(nchv, l);
  int b = r / (8 * nc);
  int h = (r / nc) & 7;
  int ch = r % nc;
  int Nk = sel4(nkv, l);
  int qr0 = (l * 4 + b) * 100;
  int kr0 = sel4(koffv, l) + b * sel4(kstrbv, l);
  int j0 = ch * 128;
  int jn = min(128, Nk - j0);
  int tiles = (jn + 31) >> 5;
  int tid = threadIdx.x;
  int qi = tid >> 1, half = tid & 1, ho = half * 16, jb = half * 16;
  const float SC = 0.17677669529663689f;
  float4 q8[8];
  if (qi < 100) {
    const float* qrow = qp + (long)(qr0 + qi) * qld + h * 32;
#pragma unroll
    for (int k = 0; k < 8; ++k) {
      float4 f = *(const float4*)&qrow[4 * k];
      q8[k] = make_float4(f.x * SC, f.y * SC, f.z * SC, f.w * SC);
    }
  } else {
#pragma unroll
    for (int k = 0; k < 8; ++k) q8[k] = make_float4(0.f, 0.f, 0.f, 0.f);
  }
  float m = -1e30f, lsum = 0.f;
  float o[16];
#pragma unroll
  for (int i = 0; i < 16; ++i) o[i] = 0.f;

  for (int kt = 0; kt < tiles; ++kt) {
    __syncthreads();
    {
      int rr = tid >> 3, c4 = (tid & 7) * 4;
      int jr = kt * 32 + rr;
      float4 kf = make_float4(0.f, 0.f, 0.f, 0.f), vf = kf;
      if (jr < jn) {
        long g = (long)(kr0 + j0 + jr) * kvld + h * 32 + c4;
        kf = *(const float4*)&kb[g];
        vf = *(const float4*)&vb[g];
      }
      *(float4*)&Kt[rr][c4 ^ (rr & 16)] = kf;
      *(float4*)&Vt[rr][c4] = vf;
    }
    __syncthreads();
    float sv[16];
#pragma unroll
    for (int j = 0; j < 16; ++j) {
      float s = 0.f;
#pragma unroll
      for (int k4 = 0; k4 < 8; ++k4) {
        float4 kv = *(const float4*)&Kt[jb + j][(4 * k4) ^ jb];
        s = fmaf(q8[k4].x, kv.x, s); s = fmaf(q8[k4].y, kv.y, s);
        s = fmaf(q8[k4].z, kv.z, s); s = fmaf(q8[k4].w, kv.w, s);
      }
      int jglob = j0 + kt * 32 + jb + j;
      sv[j] = (jglob < Nk) ? s : -1e30f;
    }
    float tmax = sv[0];
#pragma unroll
    for (int j = 1; j < 16; ++j) tmax = fmaxf(tmax, sv[j]);
    tmax = fmaxf(tmax, __shfl_xor(tmax, 1));
    float mnew = fmaxf(m, tmax);
    float scale = __expf(m - mnew);
    float p[16]; float psum = 0.f;
#pragma unroll
    for (int j = 0; j < 16; ++j) {
      int jglob = j0 + kt * 32 + jb + j;
      float e = (jglob < Nk) ? __expf(sv[j] - mnew) : 0.f;
      p[j] = e; psum += e;
    }
    psum += __shfl_xor(psum, 1);
    lsum = lsum * scale + psum;
    m = mnew;
#pragma unroll
    for (int i = 0; i < 16; ++i) o[i] *= scale;
    float pO[16];
#pragma unroll
    for (int j = 0; j < 16; ++j) pO[j] = __shfl_xor(p[j], 1);
    int jbO = jb ^ 16;
#pragma unroll
    for (int j = 0; j < 16; ++j) {
      float pj = p[j];
      const float* vrow = &Vt[jb + j][ho];
#pragma unroll
      for (int k = 0; k < 4; ++k) {
        float4 v4 = *(const float4*)&vrow[4 * k];
        o[4 * k + 0] = fmaf(pj, v4.x, o[4 * k + 0]);
        o[4 * k + 1] = fmaf(pj, v4.y, o[4 * k + 1]);
        o[4 * k + 2] = fmaf(pj, v4.z, o[4 * k + 2]);
        o[4 * k + 3] = fmaf(pj, v4.w, o[4 * k + 3]);
      }
    }
#pragma unroll
    for (int j = 0; j < 16; ++j) {
      float pj = pO[j];
      const float* vrow = &Vt[jbO + j][ho];
#pragma unroll
      for (int k = 0; k < 4; ++k) {
        float4 v4 = *(const float4*)&vrow[4 * k];
        o[4 * k + 0] = fmaf(pj, v4.x, o[4 * k + 0]);
        o[4 * k + 1] = fmaf(pj, v4.y, o[4 * k + 1]);
        o[4 * k + 2] = fmaf(pj, v4.z, o[4 * k + 2]);
        o[4 * k + 3] = fmaf(pj, v4.w, o[4 * k + 3]);
      }
    }
  }
  if (qi < 100) {
    float* pod = po + (long)bid * 3200 + qi * 32 + ho;
#pragma unroll
    for (int k = 0; k < 4; ++k)
      *(float4*)&pod[4 * k] = make_float4(o[4 * k], o[4 * k + 1], o[4 * k + 2], o[4 * k + 3]);
    if (half == 0) { pm[bid * 128 + qi] = m; pl[bid * 128 + qi] = lsum; }
  }
}

// --- SA combine -------------------------------------------------------------
__global__ __launch_bounds__(256) void combine_kernel(const float* __restrict__ po,
                                                      const float* __restrict__ pm,
                                                      const float* __restrict__ pl,
                                                      int4 startv, int4 nchv,
                                                      float* __restrict__ outp, int outld) {
  int bid = blockIdx.x;
  int l = bid >> 5, rr = bid & 31, b = rr >> 3, h = rr & 7;
  int nc = sel4(nchv, l);
  int sb = sel4(startv, l) + (b * 8 + h) * nc;
  int qr0 = (l * 4 + b) * 100;
  int idx = blockIdx.y * 256 + threadIdx.x;
  if (idx >= 3200) return;
  int qi = idx >> 5, hd = idx & 31;
  float mstar = -1e30f;
  for (int c = 0; c < nc; ++c) mstar = fmaxf(mstar, pm[(sb + c) * 128 + qi]);
  float Lt = 0.f, val = 0.f;
  for (int c = 0; c < nc; ++c) {
    float w = __expf(pm[(sb + c) * 128 + qi] - mstar);
    Lt = fmaf(w, pl[(sb + c) * 128 + qi], Lt);
    val = fmaf(w, po[(long)(sb + c) * 3200 + qi * 32 + hd], val);
  }
  outp[(long)(qr0 + qi) * outld + h * 32 + hd] = val / Lt;
}

// --- CA flash v2 (both views): barrier-free, LDS-free, register P -----------
__global__ __launch_bounds__(256) void flash_ca2_kernel(
    const unsigned short* __restrict__ Qh, const unsigned short* __restrict__ Ql,
    const unsigned short* __restrict__ Kh, const unsigned short* __restrict__ Kl,
    const unsigned short* __restrict__ VTh, const unsigned short* __restrict__ VTl,
    float* __restrict__ po, float* __restrict__ pm, float* __restrict__ pl) {
  int tid = threadIdx.x;
  int uu = blockIdx.x * 4 + (tid >> 6);
  int v = uu / 1536;
  int u = uu - v * 1536;
  int lane = tid & 63;
  int fr = lane & 15, g = lane >> 4;
  int base, lognc, koff, kstr, ntile, l;
  if (u < 1024)      { base = 0;    lognc = 3; koff = 0;     kstr = 4096; ntile = 16; l = 0; }
  else if (u < 1280) { base = 1024; lognc = 1; koff = 16384; kstr = 1024; ntile = 16; l = 1; }
  else if (u < 1408) { base = 1280; lognc = 0; koff = 20480; kstr = 256;  ntile = 8;  l = 2; }
  else               { base = 1408; lognc = 0; koff = 21504; kstr = 64;   ntile = 2;  l = 3; }
  int r = u - base;
  int qg = r & 3; r >>= 2;
  int ch = r & ((1 << lognc) - 1); r >>= lognc;
  int h = r & 7, b = r >> 3;
  long kvoff = (long)v * KVV;
  long qoff = ((long)((l * 4 + b) * 100 + qg * 32)) * 256 + h * 32 + 8 * g;
  bf16x8 qh0 = *(const bf16x8*)&Qh[qoff + fr * 256];
  bf16x8 qh1 = *(const bf16x8*)&Qh[qoff + (16 + fr) * 256];
  bf16x8 ql0 = *(const bf16x8*)&Ql[qoff + fr * 256];
  bf16x8 ql1 = *(const bf16x8*)&Ql[qoff + (16 + fr) * 256];
  int kbase = koff + b * kstr + ch * 512;
  int kperm = 8 * (fr >> 2) + (fr & 3);
  long vr0 = kvoff + (long)(h * 32 + fr) * 21760;
  long vr1 = kvoff + (long)(h * 32 + 16 + fr) * 21760;
  f32x4 o00 = {0.f, 0.f, 0.f, 0.f}, o01 = o00, o10 = o00, o11 = o00;
  float m0r = -1e30f, m1r = -1e30f, l0r = 0.f, l1r = 0.f;

  for (int kt = 0; kt < ntile; ++kt) {
    int tok0 = kbase + kt * 32;
    long ka = kvoff + (long)(tok0 + kperm) * 256 + h * 32 + 8 * g;
    bf16x8 kh0 = *(const bf16x8*)&Kh[ka];
    bf16x8 kl0 = *(const bf16x8*)&Kl[ka];
    bf16x8 kh1 = *(const bf16x8*)&Kh[ka + 1024];
    bf16x8 kl1 = *(const bf16x8*)&Kl[ka + 1024];
    bf16x8 vh0 = *(const bf16x8*)&VTh[vr0 + tok0 + 8 * g];
    bf16x8 vl0 = *(const bf16x8*)&VTl[vr0 + tok0 + 8 * g];
    bf16x8 vh1 = *(const bf16x8*)&VTh[vr1 + tok0 + 8 * g];
    bf16x8 vl1 = *(const bf16x8*)&VTl[vr1 + tok0 + 8 * g];
    f32x4 zz = {0.f, 0.f, 0.f, 0.f};
    f32x4 s00 = zz, s01 = zz, s10 = zz, s11 = zz;
    s00 = MFMA16(kh0, qh0, s00); s00 = MFMA16(kl0, qh0, s00); s00 = MFMA16(kh0, ql0, s00);
    s01 = MFMA16(kh1, qh0, s01); s01 = MFMA16(kl1, qh0, s01); s01 = MFMA16(kh1, ql0, s01);
    s10 = MFMA16(kh0, qh1, s10); s10 = MFMA16(kl0, qh1, s10); s10 = MFMA16(kh0, ql1, s10);
    s11 = MFMA16(kh1, qh1, s11); s11 = MFMA16(kl1, qh1, s11); s11 = MFMA16(kh1, ql1, s11);
    {
      float t0 = fmaxf(fmaxf(s00[0], s00[1]), fmaxf(s00[2], s00[3]));
      float t1 = fmaxf(fmaxf(s01[0], s01[1]), fmaxf(s01[2], s01[3]));
      float tm = fmaxf(t0, t1);
      tm = fmaxf(tm, __shfl_xor(tm, 16));
      tm = fmaxf(tm, __shfl_xor(tm, 32));
      float mn = fmaxf(m0r, tm);
      float sc = __expf(m0r - mn); m0r = mn;
      float p[8]; float ps = 0.f;
#pragma unroll
      for (int i = 0; i < 4; ++i) { p[i] = __expf(s00[i] - mn); ps += p[i]; }
#pragma unroll
      for (int i = 0; i < 4; ++i) { p[4 + i] = __expf(s01[i] - mn); ps += p[4 + i]; }
      l0r = l0r * sc + ps;
      union { bf16x8 v; unsigned short us[8]; } ph, plo;
#pragma unroll
      for (int e = 0; e < 8; ++e) {
        unsigned short hi = bf_rne(p[e]);
        ph.us[e] = hi;
        plo.us[e] = bf_rne(p[e] - bf2f(hi));
      }
#pragma unroll
      for (int i = 0; i < 4; ++i) { o00[i] *= sc; o01[i] *= sc; }
      o00 = MFMA16(vh0, ph.v, o00); o00 = MFMA16(vl0, ph.v, o00); o00 = MFMA16(vh0, plo.v, o00);
      o01 = MFMA16(vh1, ph.v, o01); o01 = MFMA16(vl1, ph.v, o01); o01 = MFMA16(vh1, plo.v, o01);
    }
    {
      float t0 = fmaxf(fmaxf(s10[0], s10[1]), fmaxf(s10[2], s10[3]));
      float t1 = fmaxf(fmaxf(s11[0], s11[1]), fmaxf(s11[2], s11[3]));
      float tm = fmaxf(t0, t1);
      tm = fmaxf(tm, __shfl_xor(tm, 16));
      tm = fmaxf(tm, __shfl_xor(tm, 32));
      float mn = fmaxf(m1r, tm);
      float sc = __expf(m1r - mn); m1r = mn;
      float p[8]; float ps = 0.f;
#pragma unroll
      for (int i = 0; i < 4; ++i) { p[i] = __expf(s10[i] - mn); ps += p[i]; }
#pragma unroll
      for (int i = 0; i < 4; ++i) { p[4 + i] = __expf(s11[i] - mn); ps += p[4 + i]; }
      l1r = l1r * sc + ps;
      union { bf16x8 v; unsigned short us[8]; } ph, plo;
#pragma unroll
      for (int e = 0; e < 8; ++e) {
        unsigned short hi = bf_rne(p[e]);
        ph.us[e] = hi;
        plo.us[e] = bf_rne(p[e] - bf2f(hi));
      }
#pragma unroll
      for (int i = 0; i < 4; ++i) { o10[i] *= sc; o11[i] *= sc; }
      o10 = MFMA16(vh0, ph.v, o10); o10 = MFMA16(vl0, ph.v, o10); o10 = MFMA16(vh0, plo.v, o10);
      o11 = MFMA16(vh1, ph.v, o11); o11 = MFMA16(vl1, ph.v, o11); o11 = MFMA16(vh1, plo.v, o11);
    }
  }
  l0r += __shfl_xor(l0r, 16); l0r += __shfl_xor(l0r, 32);
  l1r += __shfl_xor(l1r, 16); l1r += __shfl_xor(l1r, 32);
  long pob = (long)uu * 1024;
  *(f32x4*)&po[pob + fr * 32 + 4 * g] = o00;
  *(f32x4*)&po[pob + fr * 32 + 16 + 4 * g] = o01;
  *(f32x4*)&po[pob + (16 + fr) * 32 + 4 * g] = o10;
  *(f32x4*)&po[pob + (16 + fr) * 32 + 16 + 4 * g] = o11;
  if (g == 0) {
    pm[uu * 32 + fr] = m0r;       pl[uu * 32 + fr] = l0r;
    pm[uu * 32 + 16 + fr] = m1r;  pl[uu * 32 + 16 + fr] = l1r;
  }
}

// --- CA combine v2 (both views): unit = (v,l,b,h,qg), 1024 blocks -----------
__global__ __launch_bounds__(256) void combine2_kernel(const float* __restrict__ po,
                                                       const float* __restrict__ pm,
                                                       const float* __restrict__ pl,
                                                       float* __restrict__ oca) {
  int gu = blockIdx.x;
  int v = gu >> 9;
  int u = gu & 511;
  int l = u >> 7, ur = u & 127;
  int b = ur >> 5, h = (ur >> 2) & 7, qg = ur & 3;
  int nc, base;
  if (l == 0)      { nc = 8; base = 0; }
  else if (l == 1) { nc = 2; base = 1024; }
  else if (l == 2) { nc = 1; base = 1280; }
  else             { nc = 1; base = 1408; }
  int pu0 = v * 1536 + base + ((b * 8 + h) * nc) * 4 + qg;
  int qr0 = (l * 4 + b) * 100 + qg * 32;
  int qn = min(32, 100 - qg * 32);
  float* outp = oca + (long)v * 409600;
  for (int e = threadIdx.x; e < 1024; e += 256) {
    int qi = e >> 5, d = e & 31;
    if (qi >= qn) continue;
    float mstar = -1e30f;
    for (int c = 0; c < nc; ++c) mstar = fmaxf(mstar, pm[(pu0 + 4 * c) * 32 + qi]);
    float Lt = 0.f, val = 0.f;
    for (int c = 0; c < nc; ++c) {
      float w = __expf(pm[(pu0 + 4 * c) * 32 + qi] - mstar);
      Lt = fmaf(w, pl[(pu0 + 4 * c) * 32 + qi], Lt);
      val = fmaf(w, po[(long)(pu0 + 4 * c) * 1024 + qi * 32 + d], val);
    }
    outp[(long)(qr0 + qi) * 256 + h * 32 + d] = val / Lt;
  }
}

// --- ms = q1 @ q2^T ---------------------------------------------------------
__global__ __launch_bounds__(256) void fuse_ms_kernel(const float* __restrict__ q1,
                                                      const float* __restrict__ q2,
                                                      float* __restrict__ ms) {
  __shared__ float a[32][132];
  __shared__ float bsh[32][132];
  int lb = blockIdx.x;
  int it = blockIdx.y >> 2, jt = blockIdx.y & 3;
  int tid = threadIdx.x;
  int ti = tid & 15, tj = tid >> 4;
  float acc[2][2] = {};
  for (int chalf = 0; chalf < 2; ++chalf) {
    __syncthreads();
#pragma unroll
    for (int k = 0; k < 4; ++k) {
      int i = tid + k * 256;
      int rr = i >> 5, c4 = (i & 31) * 4;
      int row1 = it * 32 + rr, row2 = jt * 32 + rr;
      float4 fa = make_float4(0.f, 0.f, 0.f, 0.f), fb = fa;
      if (row1 < 100) fa = *(const float4*)&q1[(long)(lb * 100 + row1) * 256 + chalf * 128 + c4];
      if (row2 < 100) fb = *(const float4*)&q2[(long)(lb * 100 + row2) * 256 + chalf * 128 + c4];
      *(float4*)&a[rr][c4] = fa;
      *(float4*)&bsh[rr][c4] = fb;
    }
    __syncthreads();
#pragma unroll
    for (int k4 = 0; k4 < 32; ++k4) {
      float4 a0 = *(const float4*)&a[2 * ti][4 * k4];
      float4 a1 = *(const float4*)&a[2 * ti + 1][4 * k4];
      float4 b0 = *(const float4*)&bsh[2 * tj][4 * k4];
      float4 b1 = *(const float4*)&bsh[2 * tj + 1][4 * k4];
      acc[0][0] += dot4(a0, b0); acc[0][1] += dot4(a0, b1);
      acc[1][0] += dot4(a1, b0); acc[1][1] += dot4(a1, b1);
    }
  }
#pragma unroll
  for (int i = 0; i < 2; ++i)
#pragma unroll
    for (int j = 0; j < 2; ++j)
      ms[(long)(lb * 128 + it * 32 + 2 * ti + i) * 128 + jt * 32 + 2 * tj + j] = acc[i][j];
}

// --- row & column softmax stats of ms --------------------------------------
__global__ void fuse_stats_kernel(const float* __restrict__ ms, float* __restrict__ rst) {
  int lb = blockIdx.x, tid = threadIdx.x;
  if (tid < 100) {
    const float* row = ms + (long)(lb * 128 + tid) * 128;
    float mx = row[0];
    for (int j = 1; j < 100; ++j) mx = fmaxf(mx, row[j]);
    float s = 0.f;
    for (int j = 0; j < 100; ++j) s += __expf(row[j] - mx);
    rst[(0 * 16 + lb) * 128 + tid] = mx;
    rst[(1 * 16 + lb) * 128 + tid] = s;
  } else if (tid >= 128 && tid < 228) {
    int j = tid - 128;
    const float* colp = ms + (long)lb * 128 * 128 + j;
    float mx = colp[0];
    for (int i = 1; i < 100; ++i) mx = fmaxf(mx, colp[i * 128]);
    float s = 0.f;
    for (int i = 0; i < 100; ++i) s += __expf(colp[i * 128] - mx);
    rst[(2 * 16 + lb) * 128 + j] = mx;
    rst[(3 * 16 + lb) * 128 + j] = s;
  }
}

// --- r1/r2 mixing + final channel softmax -----------------------------------
__global__ __launch_bounds__(256) void fuse_apply_kernel(const float* __restrict__ ms,
                                                         const float* __restrict__ rst,
                                                         const float* __restrict__ q1,
                                                         const float* __restrict__ q2,
                                                         const float* __restrict__ qsa,
                                                         float* __restrict__ qout) {
  __shared__ float pr[100], pc[100];
  __shared__ float red1[4], red2[4];
  int lb = blockIdx.x, qc = blockIdx.y, tid = threadIdx.x;
  for (int ii = 0; ii < 10; ++ii) {
    int i = qc * 10 + ii;
    long r = lb * 100 + i;
    if (tid < 100) {
      float rm = rst[(0 * 16 + lb) * 128 + i], rs = rst[(1 * 16 + lb) * 128 + i];
      pr[tid] = __expf(ms[(long)(lb * 128 + i) * 128 + tid] - rm) / rs;
    } else if (tid >= 128 && tid < 228) {
      int i2 = tid - 128;
      float cm = rst[(2 * 16 + lb) * 128 + i], cs = rst[(3 * 16 + lb) * 128 + i];
      pc[i2] = __expf(ms[(long)(lb * 128 + i2) * 128 + i] - cm) / cs;
    }
    __syncthreads();
    float acc1 = 0.f, acc2 = 0.f;
    for (int j = 0; j < 100; ++j) acc1 = fmaf(pr[j], q2[(long)(lb * 100 + j) * 256 + tid], acc1);
    for (int j = 0; j < 100; ++j) acc2 = fmaf(pc[j], q1[(long)(lb * 100 + j) * 256 + tid], acc2);
    float z = qsa[r * 256 + tid] + q1[r * 256 + tid] + acc1 + q2[r * 256 + tid] + acc2;
    float v = z;
    for (int off = 32; off; off >>= 1) v = fmaxf(v, __shfl_xor(v, off));
    int w = tid >> 6;
    if ((tid & 63) == 0) red1[w] = v;
    __syncthreads();
    float zm = fmaxf(fmaxf(red1[0], red1[1]), fmaxf(red1[2], red1[3]));
    float e = __expf(z - zm);
    float sv = e;
    for (int off = 32; off; off >>= 1) sv += __shfl_xor(sv, off);
    if ((tid & 63) == 0) red2[w] = sv;
    __syncthreads();
    float es = red2[0] + red2[1] + red2[2] + red2[3];
    qout[r * 256 + tid] = e / es;
    __syncthreads();
  }
}

// ---------------------------------------------------------------------------
extern "C" void kernel_launch(void* const* d_in, const int* in_sizes, int n_in,
                              void* d_out, int out_size, void* d_ws, size_t ws_size,
                              hipStream_t stream) {
  (void)in_sizes; (void)n_in; (void)out_size; (void)ws_size;
  const float* feats[2][4] = {
      {(const float*)d_in[0], (const float*)d_in[1], (const float*)d_in[2], (const float*)d_in[3]},
      {(const float*)d_in[4], (const float*)d_in[5], (const float*)d_in[6], (const float*)d_in[7]}};
  const float* qe   = (const float*)d_in[8];
  const float* ng   = (const float*)d_in[9];
  const float* nb   = (const float*)d_in[10];
  const float* wq   = (const float*)d_in[11];
  const float* wk   = (const float*)d_in[12];
  const float* wv   = (const float*)d_in[13];
  const float* wp   = (const float*)d_in[14];
  const float* bp   = (const float*)d_in[15];
  const float* swqkv= (const float*)d_in[16];
  const float* swp  = (const float*)d_in[17];
  const float* sbp  = (const float*)d_in[18];

  float* ws = (float*)d_ws;
  unsigned short* KHp  = (unsigned short*)(ws + O_KH);
  unsigned short* KLp  = (unsigned short*)(ws + O_KL);
  unsigned short* VTHp = (unsigned short*)(ws + O_VTH);
  unsigned short* VTLp = (unsigned short*)(ws + O_VTL);
  float* QBUFp = ws + O_QBUF;
  float* QKVp  = ws + O_QKV;
  float* QSAp  = ws + O_QSA;
  float* QHATp = ws + O_QHAT;
  float* QNp   = ws + O_QN;
  float* SAOp  = ws + O_SAO;
  float* OCAp  = ws + O_OCA;
  float* Q12p  = ws + O_Q12;
  unsigned short* QHp  = (unsigned short*)(ws + O_QH);
  unsigned short* QLp  = (unsigned short*)(ws + O_QL);
  unsigned short* WTHp = (unsigned short*)(ws + O_WTH);
  unsigned short* WTLp = (unsigned short*)(ws + O_WTL);
  float* WQp   = ws + O_WQ;
  float* BKVp  = ws + O_BKV;
  float* BQp   = ws + O_BQ;
  float* POp   = ws + O_PO;
  float* PMp   = ws + O_PM;
  float* PLp   = ws + O_PL;
  float* PO2p  = ws + O_PO2;
  float* PM2p  = ws + O_PM2;
  float* PL2p  = ws + O_PL2;
  float* MSp   = ws + O_MS;
  float* RSTp  = ws + O_RST;
  float* STATSp= ws + O_STATS;
  unsigned short* XHp  = (unsigned short*)(ws + O_XH);
  unsigned short* XLp  = (unsigned short*)(ws + O_XL);

  const int HWs[4] = {4096, 1024, 256, 64};
  const int VOs[4] = {0, 16384, 20480, 21504};

  fold_w2_kernel<<<4608, 256, 0, stream>>>(ng, wk, wv, wq, WTHp, WTLp, WQp);
  fold_b_kernel<<<18, 256, 0, stream>>>(nb, wk, wv, wq, BKVp, BQp);
  for (int v = 0; v < 2; ++v)
    for (int l = 0; l < 4; ++l)
      ln_stats_kernel<<<dim3(HWs[l] / 64, 4), 256, 0, stream>>>(
          feats[v][l], STATSp, v * 21760 + VOs[l], HWs[l]);
  // FIX: pass un-offset XHp/XLp — vbase already places the view.
  for (int v = 0; v < 2; ++v)
    ln_split_x_kernel<<<340, 256, 0, stream>>>(
        feats[v][0], feats[v][1], feats[v][2], feats[v][3], STATSp, v * 21760, XHp, XLp);
  init_q_kernel<<<1600, 256, 0, stream>>>(qe, QBUFp);

  const int4 saStart = make_int4(0, 32, 64, 96);
  const int4 saNch   = make_int4(1, 1, 1, 1);
  const int4 saNk    = make_int4(100, 100, 100, 100);
  const int4 saKoff  = make_int4(0, 400, 800, 1200);
  const int4 saKstrb = make_int4(100, 100, 100, 100);

  for (int d = 0; d < 6; ++d) {
    // --- self attention ---
    gemm256_kernel<<<dim3(12, 25), 256, 0, stream>>>(QBUFp, swqkv + (long)d * 196608, nullptr,
                                                     QKVp, 1600, 768);
    flash_kernel<<<128, 256, 0, stream>>>(QKVp, 768, QKVp + 256, QKVp + 512, 768,
                                          saStart, saNch, saNk, saKoff, saKstrb, POp, PMp, PLp);
    combine_kernel<<<dim3(128, 13), 256, 0, stream>>>(POp, PMp, PLp, saStart, saNch, SAOp, 256);
    gemm256_kernel<<<dim3(4, 25), 256, 0, stream>>>(SAOp, swp + (long)d * 65536, sbp + d * 256,
                                                    QSAp, 1600, 256);
    // --- cross-attention query projection + split ---
    row_ln_kernel<<<1600, 256, 0, stream>>>(QSAp, QHATp);
    gemm256_kernel<<<dim3(4, 25), 256, 0, stream>>>(QHATp, WQp + (long)d * 65536, BQp + d * 256,
                                                    QNp, 1600, 256);
    split_q_kernel<<<1632, 256, 0, stream>>>(QNp, QHp, QLp);
    // --- cross attention, both views per dispatch ---
    gemm_kv4_kernel<<<dim3(4, 340, 2), 256, 0, stream>>>(
        XHp, XLp, WTHp + (long)d * 131072, WTLp + (long)d * 131072, BKVp + d * 512,
        KHp, KLp, VTHp, VTLp);
    flash_ca2_kernel<<<768, 256, 0, stream>>>(QHp, QLp, KHp, KLp, VTHp, VTLp,
                                              PO2p, PM2p, PL2p);
    combine2_kernel<<<1024, 256, 0, stream>>>(PO2p, PM2p, PL2p, OCAp);
    gemm256_kernel<<<dim3(4, 50), 256, 0, stream>>>(OCAp, wp + (long)d * 65536, bp + d * 256,
                                                    Q12p, 3200, 256);
    // --- matching fusion + channel softmax ---
    fuse_ms_kernel<<<dim3(16, 16), 256, 0, stream>>>(Q12p, Q12p + 409600, MSp);
    fuse_stats_kernel<<<16, 256, 0, stream>>>(MSp, RSTp);
    fuse_apply_kernel<<<dim3(16, 10), 256, 0, stream>>>(MSp, RSTp, Q12p, Q12p + 409600,
                                                        QSAp, QBUFp);
  }
  hipMemcpyAsync(d_out, QBUFp, 409600 * sizeof(float), hipMemcpyDeviceToDevice, stream);
}

// Round 9
// 1930.910 us; speedup vs baseline: 1.4441x; 1.1941x over previous
//
#include <hip/hip_runtime.h>

// ---------------------------------------------------------------------------
// VolumeAttention: 4 feature levels x 6 decoder depths, B=4, NQ=100, C=256, H=8
// Round 9:
//  - gemm_kv5: BN=256/block grid(2,340,2); K half computed with SWAPPED MFMA
//    operands (A=W, B=X) so lane holds 4 consecutive n -> ushort4 K stores
//    (was 128 scalar 2B stores/thread = ~half the kernel). V half unchanged.
//  - fuse_apply flattened: one q-row per block, grid (16,100).
// ---------------------------------------------------------------------------

#define DI __device__ __forceinline__
#define MFMA16(a, b, c) __builtin_amdgcn_mfma_f32_16x16x32_bf16(a, b, c, 0, 0, 0)

typedef __attribute__((ext_vector_type(8))) short bf16x8;
typedef __attribute__((ext_vector_type(8))) unsigned short u16x8;
typedef __attribute__((ext_vector_type(4))) float f32x4;

constexpr long KVV = 5570560;   // ushorts per view (21760*256)

// ws offsets in floats
constexpr long O_KH    = 0;                        // [2][21760][256] ushort hi
constexpr long O_KL    = O_KH   + 5570560;         // [2][21760][256] ushort lo
constexpr long O_VTH   = O_KL   + 5570560;         // [2][256][21760] ushort hi
constexpr long O_VTL   = O_VTH  + 5570560;         // [2][256][21760] ushort lo
constexpr long O_QBUF  = O_VTL  + 5570560;         // [1600][256]
constexpr long O_QKV   = O_QBUF + 409600;          // [1600][768]
constexpr long O_QSA   = O_QKV  + 1228800;         // [1600][256]
constexpr long O_QHAT  = O_QSA  + 409600;          // [1600][256]
constexpr long O_QN    = O_QHAT + 409600;          // [1600][256]
constexpr long O_SAO   = O_QN   + 409600;          // [1600][256]
constexpr long O_OCA   = O_SAO  + 409600;          // [2][1600][256]
constexpr long O_Q12   = O_OCA  + 819200;          // [2][1600][256]
constexpr long O_QH    = O_Q12  + 819200;          // [1632][256] ushort hi
constexpr long O_QL    = O_QH   + 208896;          // [1632][256] ushort lo
constexpr long O_WTH   = O_QL   + 208896;          // [6][512][256] ushort hi
constexpr long O_WTL   = O_WTH  + 393216;          // [6][512][256] ushort lo
constexpr long O_WQ    = O_WTL  + 393216;          // [6][256][256] fp32
constexpr long O_BKV   = O_WQ   + 393216;          // [6][512]
constexpr long O_BQ    = O_BKV  + 3072;            // [6][256]
constexpr long O_PO    = O_BQ   + 1536;            // [128][3200] SA partials
constexpr long O_PM    = O_PO   + 409600;          // [128][128]
constexpr long O_PL    = O_PM   + 16384;           // [128][128]
constexpr long O_PO2   = O_PL   + 16384;           // [3072][1024] CA partials
constexpr long O_PM2   = O_PO2  + 3145728;         // [3072][32]
constexpr long O_PL2   = O_PM2  + 98304;           // [3072][32]
constexpr long O_MS    = O_PL2  + 98304;           // [16][128][128]
constexpr long O_RST   = O_MS   + 262144;          // [4][16][128]
constexpr long O_STATS = O_RST  + 8192;            // [43520][2]
constexpr long O_XH    = O_STATS + 87040;          // [2][21760][256] ushort hi
constexpr long O_XL    = O_XH   + 5570560;         // [2][21760][256] ushort lo
constexpr long WS_FLOATS = O_XL + 5570560;         // ~176 MB

DI int sel4(int4 v, int i) { return i == 0 ? v.x : (i == 1 ? v.y : (i == 2 ? v.z : v.w)); }
DI float dot4(float4 a, float4 b) {
  float s = a.x * b.x;
  s = fmaf(a.y, b.y, s); s = fmaf(a.z, b.z, s); s = fmaf(a.w, b.w, s);
  return s;
}
DI unsigned short bf_rne(float x) {
  unsigned u = __float_as_uint(x);
  u += 0x7fffu + ((u >> 16) & 1u);
  return (unsigned short)(u >> 16);
}
DI float bf2f(unsigned short h) { return __uint_as_float(((unsigned)h) << 16); }

// --- fold LN affine into projections; KV weights -> transposed split-bf16 --
__global__ void fold_w2_kernel(const float* __restrict__ ng, const float* __restrict__ wk,
                               const float* __restrict__ wv, const float* __restrict__ wq,
                               unsigned short* __restrict__ WTh, unsigned short* __restrict__ WTl,
                               float* __restrict__ wqo) {
  long idx = (long)blockIdx.x * 256 + threadIdx.x;
  const long T1 = 6L * 512 * 256;
  if (idx < T1) {
    int d = idx / (512 * 256); int r = idx % (512 * 256); int n = r / 256; int k = r % 256;
    float g = ng[d * 256 + k];
    float w = (n < 256) ? wk[((long)(d * 256 + k)) * 256 + n]
                        : wv[((long)(d * 256 + k)) * 256 + (n - 256)];
    w *= g;
    unsigned short h = bf_rne(w);
    WTh[idx] = h;
    WTl[idx] = bf_rne(w - bf2f(h));
  } else {
    long j = idx - T1;
    if (j < 6L * 256 * 256) {
      int d = j / 65536; int r = j % 65536; int c = r / 256; int n = r % 256;
      wqo[j] = ng[d * 256 + c] * wq[((long)(d * 256 + c)) * 256 + n];
    }
  }
}

__global__ void fold_b_kernel(const float* __restrict__ nb, const float* __restrict__ wk,
                              const float* __restrict__ wv, const float* __restrict__ wq,
                              float* __restrict__ bkvo, float* __restrict__ bqo) {
  int idx = blockIdx.x * 256 + threadIdx.x;
  if (idx >= 6 * 768) return;
  int d = idx / 768, j = idx % 768;
  float s = 0.f;
  if (j < 256) {
    for (int c = 0; c < 256; ++c) s = fmaf(nb[d * 256 + c], wk[(d * 256 + c) * 256 + j], s);
    bkvo[d * 512 + j] = s;
  } else if (j < 512) {
    int n = j - 256;
    for (int c = 0; c < 256; ++c) s = fmaf(nb[d * 256 + c], wv[(d * 256 + c) * 256 + n], s);
    bkvo[d * 512 + j] = s;
  } else {
    int n = j - 512;
    for (int c = 0; c < 256; ++c) s = fmaf(nb[d * 256 + c], wq[(d * 256 + c) * 256 + n], s);
    bqo[d * 256 + n] = s;
  }
}

// --- per-token LN statistics of feature maps ------------------------------
__global__ __launch_bounds__(256) void ln_stats_kernel(const float* __restrict__ feat,
                                                       float* __restrict__ stats,
                                                       int rowBase, int HW) {
  __shared__ float sred[4][64];
  __shared__ float qred[4][64];
  int b = blockIdx.y, t0 = blockIdx.x * 64;
  int tx = threadIdx.x & 63, ty = threadIdx.x >> 6;
  const float* fb = feat + (long)b * 256 * HW;
  float s = 0.f, q = 0.f;
  for (int k = 0; k < 64; ++k) {
    int c = ty * 64 + k;
    float v = fb[(long)c * HW + t0 + tx];
    s += v; q += v * v;
  }
  sred[ty][tx] = s; qred[ty][tx] = q;
  __syncthreads();
  if (ty == 0) {
    float ts = sred[0][tx] + sred[1][tx] + sred[2][tx] + sred[3][tx];
    float tq = qred[0][tx] + qred[1][tx] + qred[2][tx] + qred[3][tx];
    float m = ts * (1.f / 256.f);
    float var = tq * (1.f / 256.f) - m * m;
    int row = rowBase + b * HW + t0 + tx;
    stats[row * 2 + 0] = m;
    stats[row * 2 + 1] = rsqrtf(var + 1e-5f);
  }
}

// --- build LN-normalized split-bf16 X [tok][256] once per call -------------
// NOTE: dst uses vbase; callers must pass UN-offset Xh/Xl.
__global__ __launch_bounds__(256) void ln_split_x_kernel(
    const float* __restrict__ f0, const float* __restrict__ f1,
    const float* __restrict__ f2, const float* __restrict__ f3,
    const float* __restrict__ stats, int vbase,
    unsigned short* __restrict__ Xh, unsigned short* __restrict__ Xl) {
  __shared__ unsigned short Th[64][66], Tl[64][66];
  int m0 = blockIdx.x * 64;
  const float* fp; int HW, rel;
  if (m0 < 16384)      { fp = f0; HW = 4096; rel = m0; }
  else if (m0 < 20480) { fp = f1; HW = 1024; rel = m0 - 16384; }
  else if (m0 < 21504) { fp = f2; HW = 256;  rel = m0 - 20480; }
  else                 { fp = f3; HW = 64;   rel = m0 - 21504; }
  int b = rel / HW, t0 = rel % HW;
  const float* fb = fp + (long)b * 256 * HW + t0;
  int t = threadIdx.x & 63, cg4 = threadIdx.x >> 6;
  float mean = stats[(vbase + m0 + t) * 2 + 0];
  float rstd = stats[(vbase + m0 + t) * 2 + 1];
  int r = threadIdx.x >> 2, s = (threadIdx.x & 3) * 16;
  for (int cgo = 0; cgo < 4; ++cgo) {
    if (cgo) __syncthreads();
#pragma unroll
    for (int i = 0; i < 16; ++i) {
      int c = cgo * 64 + cg4 * 16 + i;
      float x = (fb[(long)c * HW + t] - mean) * rstd;
      unsigned short hi = bf_rne(x);
      Th[t][cg4 * 16 + i] = hi;
      Tl[t][cg4 * 16 + i] = bf_rne(x - bf2f(hi));
    }
    __syncthreads();
    union { ushort2 u2[8]; u16x8 v8[2]; } th, tl;
#pragma unroll
    for (int k = 0; k < 8; ++k) {
      th.u2[k] = *(const ushort2*)&Th[r][s + 2 * k];
      tl.u2[k] = *(const ushort2*)&Tl[r][s + 2 * k];
    }
    long dst = (long)(vbase + m0 + r) * 256 + cgo * 64 + s;
    *(u16x8*)&Xh[dst] = th.v8[0];
    *(u16x8*)&Xh[dst + 8] = th.v8[1];
    *(u16x8*)&Xl[dst] = tl.v8[0];
    *(u16x8*)&Xl[dst + 8] = tl.v8[1];
  }
}

__global__ void init_q_kernel(const float* __restrict__ qe, float* __restrict__ qb) {
  int idx = blockIdx.x * 256 + threadIdx.x;
  if (idx < 1600 * 256) {
    int row = idx >> 8, c = idx & 255;
    qb[idx] = qe[(row % 100) * 256 + c];
  }
}

// --- split/scale Q for CA flash: Qh/Ql [1632][256], pad rows zeroed --------
__global__ void split_q_kernel(const float* __restrict__ qn,
                               unsigned short* __restrict__ Qh,
                               unsigned short* __restrict__ Ql) {
  int idx = blockIdx.x * 256 + threadIdx.x;
  if (idx >= 1632 * 256) return;
  float v = (idx < 1600 * 256) ? qn[idx] * 0.17677669529663689f : 0.f;
  unsigned short hi = bf_rne(v);
  Qh[idx] = hi;
  Ql[idx] = bf_rne(v - bf2f(hi));
}

// --- generic fp32 GEMM: C[M,N] = A[M,256] @ W[256,N] (+bias) --------------
__global__ __launch_bounds__(256) void gemm256_kernel(const float* __restrict__ A,
                                                      const float* __restrict__ W,
                                                      const float* __restrict__ bias,
                                                      float* __restrict__ Co, int M, int N) {
  __shared__ float As[32][68];
  __shared__ float Ws[32][68];
  int tid = threadIdx.x;
  int tm = tid & 15, tn = tid >> 4;
  int m0 = blockIdx.y * 64, n0 = blockIdx.x * 64;
  float acc[4][4] = {};
  for (int kt = 0; kt < 8; ++kt) {
    __syncthreads();
#pragma unroll
    for (int it = 0; it < 2; ++it) {
      int i = tid + it * 256;
      int r = i >> 3, c4 = (i & 7) * 4;
      float4 f = *(const float4*)&A[(long)(m0 + r) * 256 + kt * 32 + c4];
      As[c4 + 0][r] = f.x; As[c4 + 1][r] = f.y; As[c4 + 2][r] = f.z; As[c4 + 3][r] = f.w;
    }
#pragma unroll
    for (int it = 0; it < 2; ++it) {
      int i = tid + it * 256;
      int r = i >> 4, c4 = (i & 15) * 4;
      *(float4*)&Ws[r][c4] = *(const float4*)&W[(long)(kt * 32 + r) * N + n0 + c4];
    }
    __syncthreads();
#pragma unroll
    for (int k = 0; k < 32; ++k) {
      float4 a4 = *(const float4*)&As[k][4 * tm];
      float4 b4 = *(const float4*)&Ws[k][4 * tn];
      float av[4] = {a4.x, a4.y, a4.z, a4.w};
      float bv[4] = {b4.x, b4.y, b4.z, b4.w};
#pragma unroll
      for (int i = 0; i < 4; ++i)
#pragma unroll
        for (int j = 0; j < 4; ++j) acc[i][j] = fmaf(av[i], bv[j], acc[i][j]);
    }
  }
  float bv4[4] = {0.f, 0.f, 0.f, 0.f};
  if (bias) {
#pragma unroll
    for (int j = 0; j < 4; ++j) bv4[j] = bias[n0 + 4 * tn + j];
  }
#pragma unroll
  for (int i = 0; i < 4; ++i) {
    int row = m0 + 4 * tm + i;
    float4 o;
    o.x = acc[i][0] + bv4[0]; o.y = acc[i][1] + bv4[1];
    o.z = acc[i][2] + bv4[2]; o.w = acc[i][3] + bv4[3];
    *(float4*)&Co[(long)row * N + n0 + 4 * tn] = o;
  }
}

// --- KV projection v5: BN=256/block; K half swapped-operand -----------------
// grid (2 nh, 340 m-tiles, 2 views); 4 waves; wave w owns n-sub w*16 of each
// 64-n block. nh=0: K, D=mfma(W,X) -> lane holds 4 consecutive n -> ushort4.
// nh=1: V, D=mfma(X,W) -> lane holds 4 consecutive tokens -> V^T ushort4.
__global__ __launch_bounds__(256) void gemm_kv5_kernel(
    const unsigned short* __restrict__ Xh, const unsigned short* __restrict__ Xl,
    const unsigned short* __restrict__ Wh, const unsigned short* __restrict__ Wl,
    const float* __restrict__ bias,
    unsigned short* __restrict__ Kh, unsigned short* __restrict__ Kl,
    unsigned short* __restrict__ VTh, unsigned short* __restrict__ VTl) {
  int nh = blockIdx.x;
  int m0 = blockIdx.y * 64;
  int v = blockIdx.z;
  int tid = threadIdx.x;
  int w = tid >> 6, lane = tid & 63;
  int fr = lane & 15, g = lane >> 4;
  const unsigned short* Xhb = Xh + (long)v * KVV;
  const unsigned short* Xlb = Xl + (long)v * KVV;
  f32x4 acc[4][4];
#pragma unroll
  for (int c4 = 0; c4 < 4; ++c4)
#pragma unroll
    for (int mt = 0; mt < 4; ++mt)
#pragma unroll
      for (int r = 0; r < 4; ++r) acc[c4][mt][r] = 0.f;
  for (int ks = 0; ks < 8; ++ks) {
    int k0 = ks * 32 + 8 * g;
    bf16x8 xh_[4], xl_[4], wh_[4], wl_[4];
#pragma unroll
    for (int mt = 0; mt < 4; ++mt) {
      long ar = (long)(m0 + mt * 16 + fr) * 256 + k0;
      xh_[mt] = *(const bf16x8*)&Xhb[ar];
      xl_[mt] = *(const bf16x8*)&Xlb[ar];
    }
#pragma unroll
    for (int c4 = 0; c4 < 4; ++c4) {
      long br = (long)(nh * 256 + c4 * 64 + w * 16 + fr) * 256 + k0;
      wh_[c4] = *(const bf16x8*)&Wh[br];
      wl_[c4] = *(const bf16x8*)&Wl[br];
    }
    if (nh == 0) {
#pragma unroll
      for (int c4 = 0; c4 < 4; ++c4)
#pragma unroll
        for (int mt = 0; mt < 4; ++mt) {
          acc[c4][mt] = MFMA16(wh_[c4], xh_[mt], acc[c4][mt]);
          acc[c4][mt] = MFMA16(wh_[c4], xl_[mt], acc[c4][mt]);
          acc[c4][mt] = MFMA16(wl_[c4], xh_[mt], acc[c4][mt]);
        }
    } else {
#pragma unroll
      for (int c4 = 0; c4 < 4; ++c4)
#pragma unroll
        for (int mt = 0; mt < 4; ++mt) {
          acc[c4][mt] = MFMA16(xh_[mt], wh_[c4], acc[c4][mt]);
          acc[c4][mt] = MFMA16(xl_[mt], wh_[c4], acc[c4][mt]);
          acc[c4][mt] = MFMA16(xh_[mt], wl_[c4], acc[c4][mt]);
        }
    }
  }
  long kvoff = (long)v * KVV;
  if (nh == 0) {
    // K: D[row=n_loc 4g+r][col=token fr] -> ushort4 along n
#pragma unroll
    for (int c4 = 0; c4 < 4; ++c4) {
      int nb = c4 * 64 + w * 16 + 4 * g;
      float4 bv4 = *(const float4*)&bias[nb];
#pragma unroll
      for (int mt = 0; mt < 4; ++mt) {
        int token = m0 + mt * 16 + fr;
        float v0 = acc[c4][mt][0] + bv4.x;
        float v1 = acc[c4][mt][1] + bv4.y;
        float v2 = acc[c4][mt][2] + bv4.z;
        float v3 = acc[c4][mt][3] + bv4.w;
        ushort4 uh, ul;
        uh.x = bf_rne(v0); ul.x = bf_rne(v0 - bf2f(uh.x));
        uh.y = bf_rne(v1); ul.y = bf_rne(v1 - bf2f(uh.y));
        uh.z = bf_rne(v2); ul.z = bf_rne(v2 - bf2f(uh.z));
        uh.w = bf_rne(v3); ul.w = bf_rne(v3 - bf2f(uh.w));
        long off = kvoff + (long)token * 256 + nb;
        *(ushort4*)&Kh[off] = uh;
        *(ushort4*)&Kl[off] = ul;
      }
    }
  } else {
    // V: D[row=token_loc 4g+r][col=n fr] -> V^T ushort4 along tokens
#pragma unroll
    for (int c4 = 0; c4 < 4; ++c4) {
      int nv = c4 * 64 + w * 16 + fr;
      float bv = bias[256 + nv];
#pragma unroll
      for (int mt = 0; mt < 4; ++mt) {
        float v0 = acc[c4][mt][0] + bv;
        float v1 = acc[c4][mt][1] + bv;
        float v2 = acc[c4][mt][2] + bv;
        float v3 = acc[c4][mt][3] + bv;
        ushort4 uh, ul;
        uh.x = bf_rne(v0); ul.x = bf_rne(v0 - bf2f(uh.x));
        uh.y = bf_rne(v1); ul.y = bf_rne(v1 - bf2f(uh.y));
        uh.z = bf_rne(v2); ul.z = bf_rne(v2 - bf2f(uh.z));
        uh.w = bf_rne(v3); ul.w = bf_rne(v3 - bf2f(uh.w));
        long off = kvoff + (long)nv * 21760 + m0 + mt * 16 + 4 * g;
        *(ushort4*)&VTh[off] = uh;
        *(ushort4*)&VTl[off] = ul;
      }
    }
  }
}

// --- row LayerNorm (no affine) ---------------------------------------------
__global__ __launch_bounds__(256) void row_ln_kernel(const float* __restrict__ in,
                                                     float* __restrict__ out) {
  __shared__ float s1[4], s2[4];
  long r = blockIdx.x;
  float x = in[r * 256 + threadIdx.x];
  float vs = x, vq = x * x;
  for (int o = 32; o; o >>= 1) { vs += __shfl_xor(vs, o); vq += __shfl_xor(vq, o); }
  int w = threadIdx.x >> 6;
  if ((threadIdx.x & 63) == 0) { s1[w] = vs; s2[w] = vq; }
  __syncthreads();
  float ts = s1[0] + s1[1] + s1[2] + s1[3];
  float tq = s2[0] + s2[1] + s2[2] + s2[3];
  float m = ts * (1.f / 256.f);
  float var = tq * (1.f / 256.f) - m * m;
  out[r * 256 + threadIdx.x] = (x - m) * rsqrtf(var + 1e-5f);
}

// --- SA flash (VALU path) ---------------------------------------------------
__global__ __launch_bounds__(256) void flash_kernel(const float* __restrict__ qp, int qld,
                                                    const float* __restrict__ kb,
                                                    const float* __restrict__ vb, int kvld,
                                                    int4 startv, int4 nchv, int4 nkv,
                                                    int4 koffv, int4 kstrbv,
                                                    float* __restrict__ po,
                                                    float* __restrict__ pm,
                                                    float* __restrict__ pl) {
  __shared__ float Kt[32][36];
  __shared__ float Vt[32][36];
  int bid = blockIdx.x;
  int s1 = startv.y, s2 = startv.z, s3 = startv.w;
  int l = (bid < s1) ? 0 : (bid < s2) ? 1 : (bid < s3) ? 2 : 3;
  int r = bid - sel4(startv, l);
  int nc = sel4(nchv, l);
  int b = r / (8 * nc);
  int h = (r / nc) & 7;
  int ch = r % nc;
  int Nk = sel4(nkv, l);
  int qr0 = (l * 4 + b) * 100;
  int kr0 = sel4(koffv, l) + b * sel4(kstrbv, l);
  int j0 = ch * 128;
  int jn = min(128, Nk - j0);
  int tiles = (jn + 31) >> 5;
  int tid = threadIdx.x;
  int qi = tid >> 1, half = tid & 1, ho = half * 16, jb = half * 16;
  const float SC = 0.17677669529663689f;
  float4 q8[8];
  if (qi < 100) {
    const float* qrow = qp + (long)(qr0 + qi) * qld + h * 32;
#pragma unroll
    for (int k = 0; k < 8; ++k) {
      float4 f = *(const float4*)&qrow[4 * k];
      q8[k] = make_float4(f.x * SC, f.y * SC, f.z * SC, f.w * SC);
    }
  } else {
#pragma unroll
    for (int k = 0; k < 8; ++k) q8[k] = make_float4(0.f, 0.f, 0.f, 0.f);
  }
  float m = -1e30f, lsum = 0.f;
  float o[16];
#pragma unroll
  for (int i = 0; i < 16; ++i) o[i] = 0.f;

  for (int kt = 0; kt < tiles; ++kt) {
    __syncthreads();
    {
      int rr = tid >> 3, c4 = (tid & 7) * 4;
      int jr = kt * 32 + rr;
      float4 kf = make_float4(0.f, 0.f, 0.f, 0.f), vf = kf;
      if (jr < jn) {
        long g = (long)(kr0 + j0 + jr) * kvld + h * 32 + c4;
        kf = *(const float4*)&kb[g];
        vf = *(const float4*)&vb[g];
      }
      *(float4*)&Kt[rr][c4 ^ (rr & 16)] = kf;
      *(float4*)&Vt[rr][c4] = vf;
    }
    __syncthreads();
    float sv[16];
#pragma unroll
    for (int j = 0; j < 16; ++j) {
      float s = 0.f;
#pragma unroll
      for (int k4 = 0; k4 < 8; ++k4) {
        float4 kv = *(const float4*)&Kt[jb + j][(4 * k4) ^ jb];
        s = fmaf(q8[k4].x, kv.x, s); s = fmaf(q8[k4].y, kv.y, s);
        s = fmaf(q8[k4].z, kv.z, s); s = fmaf(q8[k4].w, kv.w, s);
      }
      int jglob = j0 + kt * 32 + jb + j;
      sv[j] = (jglob < Nk) ? s : -1e30f;
    }
    float tmax = sv[0];
#pragma unroll
    for (int j = 1; j < 16; ++j) tmax = fmaxf(tmax, sv[j]);
    tmax = fmaxf(tmax, __shfl_xor(tmax, 1));
    float mnew = fmaxf(m, tmax);
    float scale = __expf(m - mnew);
    float p[16]; float psum = 0.f;
#pragma unroll
    for (int j = 0; j < 16; ++j) {
      int jglob = j0 + kt * 32 + jb + j;
      float e = (jglob < Nk) ? __expf(sv[j] - mnew) : 0.f;
      p[j] = e; psum += e;
    }
    psum += __shfl_xor(psum, 1);
    lsum = lsum * scale + psum;
    m = mnew;
#pragma unroll
    for (int i = 0; i < 16; ++i) o[i] *= scale;
    float pO[16];
#pragma unroll
    for (int j = 0; j < 16; ++j) pO[j] = __shfl_xor(p[j], 1);
    int jbO = jb ^ 16;
#pragma unroll
    for (int j = 0; j < 16; ++j) {
      float pj = p[j];
      const float* vrow = &Vt[jb + j][ho];
#pragma unroll
      for (int k = 0; k < 4; ++k) {
        float4 v4 = *(const float4*)&vrow[4 * k];
        o[4 * k + 0] = fmaf(pj, v4.x, o[4 * k + 0]);
        o[4 * k + 1] = fmaf(pj, v4.y, o[4 * k + 1]);
        o[4 * k + 2] = fmaf(pj, v4.z, o[4 * k + 2]);
        o[4 * k + 3] = fmaf(pj, v4.w, o[4 * k + 3]);
      }
    }
#pragma unroll
    for (int j = 0; j < 16; ++j) {
      float pj = pO[j];
      const float* vrow = &Vt[jbO + j][ho];
#pragma unroll
      for (int k = 0; k < 4; ++k) {
        float4 v4 = *(const float4*)&vrow[4 * k];
        o[4 * k + 0] = fmaf(pj, v4.x, o[4 * k + 0]);
        o[4 * k + 1] = fmaf(pj, v4.y, o[4 * k + 1]);
        o[4 * k + 2] = fmaf(pj, v4.z, o[4 * k + 2]);
        o[4 * k + 3] = fmaf(pj, v4.w, o[4 * k + 3]);
      }
    }
  }
  if (qi < 100) {
    float* pod = po + (long)bid * 3200 + qi * 32 + ho;
#pragma unroll
    for (int k = 0; k < 4; ++k)
      *(float4*)&pod[4 * k] = make_float4(o[4 * k], o[4 * k + 1], o[4 * k + 2], o[4 * k + 3]);
    if (half == 0) { pm[bid * 128 + qi] = m; pl[bid * 128 + qi] = lsum; }
  }
}

// --- SA combine -------------------------------------------------------------
__global__ __launch_bounds__(256) void combine_kernel(const float* __restrict__ po,
                                                      const float* __restrict__ pm,
                                                      const float* __restrict__ pl,
                                                      int4 startv, int4 nchv,
                                                      float* __restrict__ outp, int outld) {
  int bid = blockIdx.x;
  int l = bid >> 5, rr = bid & 31, b = rr >> 3, h = rr & 7;
  int nc = sel4(nchv, l);
  int sb = sel4(startv, l) + (b * 8 + h) * nc;
  int qr0 = (l * 4 + b) * 100;
  int idx = blockIdx.y * 256 + threadIdx.x;
  if (idx >= 3200) return;
  int qi = idx >> 5, hd = idx & 31;
  float mstar = -1e30f;
  for (int c = 0; c < nc; ++c) mstar = fmaxf(mstar, pm[(sb + c) * 128 + qi]);
  float Lt = 0.f, val = 0.f;
  for (int c = 0; c < nc; ++c) {
    float w = __expf(pm[(sb + c) * 128 + qi] - mstar);
    Lt = fmaf(w, pl[(sb + c) * 128 + qi], Lt);
    val = fmaf(w, po[(long)(sb + c) * 3200 + qi * 32 + hd], val);
  }
  outp[(long)(qr0 + qi) * outld + h * 32 + hd] = val / Lt;
}

// --- CA flash v2 (both views): barrier-free, LDS-free, register P -----------
__global__ __launch_bounds__(256) void flash_ca2_kernel(
    const unsigned short* __restrict__ Qh, const unsigned short* __restrict__ Ql,
    const unsigned short* __restrict__ Kh, const unsigned short* __restrict__ Kl,
    const unsigned short* __restrict__ VTh, const unsigned short* __restrict__ VTl,
    float* __restrict__ po, float* __restrict__ pm, float* __restrict__ pl) {
  int tid = threadIdx.x;
  int uu = blockIdx.x * 4 + (tid >> 6);
  int v = uu / 1536;
  int u = uu - v * 1536;
  int lane = tid & 63;
  int fr = lane & 15, g = lane >> 4;
  int base, lognc, koff, kstr, ntile, l;
  if (u < 1024)      { base = 0;    lognc = 3; koff = 0;     kstr = 4096; ntile = 16; l = 0; }
  else if (u < 1280) { base = 1024; lognc = 1; koff = 16384; kstr = 1024; ntile = 16; l = 1; }
  else if (u < 1408) { base = 1280; lognc = 0; koff = 20480; kstr = 256;  ntile = 8;  l = 2; }
  else               { base = 1408; lognc = 0; koff = 21504; kstr = 64;   ntile = 2;  l = 3; }
  int r = u - base;
  int qg = r & 3; r >>= 2;
  int ch = r & ((1 << lognc) - 1); r >>= lognc;
  int h = r & 7, b = r >> 3;
  long kvoff = (long)v * KVV;
  long qoff = ((long)((l * 4 + b) * 100 + qg * 32)) * 256 + h * 32 + 8 * g;
  bf16x8 qh0 = *(const bf16x8*)&Qh[qoff + fr * 256];
  bf16x8 qh1 = *(const bf16x8*)&Qh[qoff + (16 + fr) * 256];
  bf16x8 ql0 = *(const bf16x8*)&Ql[qoff + fr * 256];
  bf16x8 ql1 = *(const bf16x8*)&Ql[qoff + (16 + fr) * 256];
  int kbase = koff + b * kstr + ch * 512;
  int kperm = 8 * (fr >> 2) + (fr & 3);
  long vr0 = kvoff + (long)(h * 32 + fr) * 21760;
  long vr1 = kvoff + (long)(h * 32 + 16 + fr) * 21760;
  f32x4 o00 = {0.f, 0.f, 0.f, 0.f}, o01 = o00, o10 = o00, o11 = o00;
  float m0r = -1e30f, m1r = -1e30f, l0r = 0.f, l1r = 0.f;

  for (int kt = 0; kt < ntile; ++kt) {
    int tok0 = kbase + kt * 32;
    long ka = kvoff + (long)(tok0 + kperm) * 256 + h * 32 + 8 * g;
    bf16x8 kh0 = *(const bf16x8*)&Kh[ka];
    bf16x8 kl0 = *(const bf16x8*)&Kl[ka];
    bf16x8 kh1 = *(const bf16x8*)&Kh[ka + 1024];
    bf16x8 kl1 = *(const bf16x8*)&Kl[ka + 1024];
    bf16x8 vh0 = *(const bf16x8*)&VTh[vr0 + tok0 + 8 * g];
    bf16x8 vl0 = *(const bf16x8*)&VTl[vr0 + tok0 + 8 * g];
    bf16x8 vh1 = *(const bf16x8*)&VTh[vr1 + tok0 + 8 * g];
    bf16x8 vl1 = *(const bf16x8*)&VTl[vr1 + tok0 + 8 * g];
    f32x4 zz = {0.f, 0.f, 0.f, 0.f};
    f32x4 s00 = zz, s01 = zz, s10 = zz, s11 = zz;
    s00 = MFMA16(kh0, qh0, s00); s00 = MFMA16(kl0, qh0, s00); s00 = MFMA16(kh0, ql0, s00);
    s01 = MFMA16(kh1, qh0, s01); s01 = MFMA16(kl1, qh0, s01); s01 = MFMA16(kh1, ql0, s01);
    s10 = MFMA16(kh0, qh1, s10); s10 = MFMA16(kl0, qh1, s10); s10 = MFMA16(kh0, ql1, s10);
    s11 = MFMA16(kh1, qh1, s11); s11 = MFMA16(kl1, qh1, s11); s11 = MFMA16(kh1, ql1, s11);
    {
      float t0 = fmaxf(fmaxf(s00[0], s00[1]), fmaxf(s00[2], s00[3]));
      float t1 = fmaxf(fmaxf(s01[0], s01[1]), fmaxf(s01[2], s01[3]));
      float tm = fmaxf(t0, t1);
      tm = fmaxf(tm, __shfl_xor(tm, 16));
      tm = fmaxf(tm, __shfl_xor(tm, 32));
      float mn = fmaxf(m0r, tm);
      float sc = __expf(m0r - mn); m0r = mn;
      float p[8]; float ps = 0.f;
#pragma unroll
      for (int i = 0; i < 4; ++i) { p[i] = __expf(s00[i] - mn); ps += p[i]; }
#pragma unroll
      for (int i = 0; i < 4; ++i) { p[4 + i] = __expf(s01[i] - mn); ps += p[4 + i]; }
      l0r = l0r * sc + ps;
      union { bf16x8 v; unsigned short us[8]; } ph, plo;
#pragma unroll
      for (int e = 0; e < 8; ++e) {
        unsigned short hi = bf_rne(p[e]);
        ph.us[e] = hi;
        plo.us[e] = bf_rne(p[e] - bf2f(hi));
      }
#pragma unroll
      for (int i = 0; i < 4; ++i) { o00[i] *= sc; o01[i] *= sc; }
      o00 = MFMA16(vh0, ph.v, o00); o00 = MFMA16(vl0, ph.v, o00); o00 = MFMA16(vh0, plo.v, o00);
      o01 = MFMA16(vh1, ph.v, o01); o01 = MFMA16(vl1, ph.v, o01); o01 = MFMA16(vh1, plo.v, o01);
    }
    {
      float t0 = fmaxf(fmaxf(s10[0], s10[1]), fmaxf(s10[2], s10[3]));
      float t1 = fmaxf(fmaxf(s11[0], s11[1]), fmaxf(s11[2], s11[3]));
      float tm = fmaxf(t0, t1);
      tm = fmaxf(tm, __shfl_xor(tm, 16));
      tm = fmaxf(tm, __shfl_xor(tm, 32));
      float mn = fmaxf(m1r, tm);
      float sc = __expf(m1r - mn); m1r = mn;
      float p[8]; float ps = 0.f;
#pragma unroll
      for (int i = 0; i < 4; ++i) { p[i] = __expf(s10[i] - mn); ps += p[i]; }
#pragma unroll
      for (int i = 0; i < 4; ++i) { p[4 + i] = __expf(s11[i] - mn); ps += p[4 + i]; }
      l1r = l1r * sc + ps;
      union { bf16x8 v; unsigned short us[8]; } ph, plo;
#pragma unroll
      for (int e = 0; e < 8; ++e) {
        unsigned short hi = bf_rne(p[e]);
        ph.us[e] = hi;
        plo.us[e] = bf_rne(p[e] - bf2f(hi));
      }
#pragma unroll
      for (int i = 0; i < 4; ++i) { o10[i] *= sc; o11[i] *= sc; }
      o10 = MFMA16(vh0, ph.v, o10); o10 = MFMA16(vl0, ph.v, o10); o10 = MFMA16(vh0, plo.v, o10);
      o11 = MFMA16(vh1, ph.v, o11); o11 = MFMA16(vl1, ph.v, o11); o11 = MFMA16(vh1, plo.v, o11);
    }
  }
  l0r += __shfl_xor(l0r, 16); l0r += __shfl_xor(l0r, 32);
  l1r += __shfl_xor(l1r, 16); l1r += __shfl_xor(l1r, 32);
  long pob = (long)uu * 1024;
  *(f32x4*)&po[pob + fr * 32 + 4 * g] = o00;
  *(f32x4*)&po[pob + fr * 32 + 16 + 4 * g] = o01;
  *(f32x4*)&po[pob + (16 + fr) * 32 + 4 * g] = o10;
  *(f32x4*)&po[pob + (16 + fr) * 32 + 16 + 4 * g] = o11;
  if (g == 0) {
    pm[uu * 32 + fr] = m0r;       pl[uu * 32 + fr] = l0r;
    pm[uu * 32 + 16 + fr] = m1r;  pl[uu * 32 + 16 + fr] = l1r;
  }
}

// --- CA combine v2 (both views): unit = (v,l,b,h,qg), 1024 blocks -----------
__global__ __launch_bounds__(256) void combine2_kernel(const float* __restrict__ po,
                                                       const float* __restrict__ pm,
                                                       const float* __restrict__ pl,
                                                       float* __restrict__ oca) {
  int gu = blockIdx.x;
  int v = gu >> 9;
  int u = gu & 511;
  int l = u >> 7, ur = u & 127;
  int b = ur >> 5, h = (ur >> 2) & 7, qg = ur & 3;
  int nc, base;
  if (l == 0)      { nc = 8; base = 0; }
  else if (l == 1) { nc = 2; base = 1024; }
  else if (l == 2) { nc = 1; base = 1280; }
  else             { nc = 1; base = 1408; }
  int pu0 = v * 1536 + base + ((b * 8 + h) * nc) * 4 + qg;
  int qr0 = (l * 4 + b) * 100 + qg * 32;
  int qn = min(32, 100 - qg * 32);
  float* outp = oca + (long)v * 409600;
  for (int e = threadIdx.x; e < 1024; e += 256) {
    int qi = e >> 5, d = e & 31;
    if (qi >= qn) continue;
    float mstar = -1e30f;
    for (int c = 0; c < nc; ++c) mstar = fmaxf(mstar, pm[(pu0 + 4 * c) * 32 + qi]);
    float Lt = 0.f, val = 0.f;
    for (int c = 0; c < nc; ++c) {
      float w = __expf(pm[(pu0 + 4 * c) * 32 + qi] - mstar);
      Lt = fmaf(w, pl[(pu0 + 4 * c) * 32 + qi], Lt);
      val = fmaf(w, po[(long)(pu0 + 4 * c) * 1024 + qi * 32 + d], val);
    }
    outp[(long)(qr0 + qi) * 256 + h * 32 + d] = val / Lt;
  }
}

// --- ms = q1 @ q2^T ---------------------------------------------------------
__global__ __launch_bounds__(256) void fuse_ms_kernel(const float* __restrict__ q1,
                                                      const float* __restrict__ q2,
                                                      float* __restrict__ ms) {
  __shared__ float a[32][132];
  __shared__ float bsh[32][132];
  int lb = blockIdx.x;
  int it = blockIdx.y >> 2, jt = blockIdx.y & 3;
  int tid = threadIdx.x;
  int ti = tid & 15, tj = tid >> 4;
  float acc[2][2] = {};
  for (int chalf = 0; chalf < 2; ++chalf) {
    __syncthreads();
#pragma unroll
    for (int k = 0; k < 4; ++k) {
      int i = tid + k * 256;
      int rr = i >> 5, c4 = (i & 31) * 4;
      int row1 = it * 32 + rr, row2 = jt * 32 + rr;
      float4 fa = make_float4(0.f, 0.f, 0.f, 0.f), fb = fa;
      if (row1 < 100) fa = *(const float4*)&q1[(long)(lb * 100 + row1) * 256 + chalf * 128 + c4];
      if (row2 < 100) fb = *(const float4*)&q2[(long)(lb * 100 + row2) * 256 + chalf * 128 + c4];
      *(float4*)&a[rr][c4] = fa;
      *(float4*)&bsh[rr][c4] = fb;
    }
    __syncthreads();
#pragma unroll
    for (int k4 = 0; k4 < 32; ++k4) {
      float4 a0 = *(const float4*)&a[2 * ti][4 * k4];
      float4 a1 = *(const float4*)&a[2 * ti + 1][4 * k4];
      float4 b0 = *(const float4*)&bsh[2 * tj][4 * k4];
      float4 b1 = *(const float4*)&bsh[2 * tj + 1][4 * k4];
      acc[0][0] += dot4(a0, b0); acc[0][1] += dot4(a0, b1);
      acc[1][0] += dot4(a1, b0); acc[1][1] += dot4(a1, b1);
    }
  }
#pragma unroll
  for (int i = 0; i < 2; ++i)
#pragma unroll
    for (int j = 0; j < 2; ++j)
      ms[(long)(lb * 128 + it * 32 + 2 * ti + i) * 128 + jt * 32 + 2 * tj + j] = acc[i][j];
}

// --- row & column softmax stats of ms --------------------------------------
__global__ void fuse_stats_kernel(const float* __restrict__ ms, float* __restrict__ rst) {
  int lb = blockIdx.x, tid = threadIdx.x;
  if (tid < 100) {
    const float* row = ms + (long)(lb * 128 + tid) * 128;
    float mx = row[0];
    for (int j = 1; j < 100; ++j) mx = fmaxf(mx, row[j]);
    float s = 0.f;
    for (int j = 0; j < 100; ++j) s += __expf(row[j] - mx);
    rst[(0 * 16 + lb) * 128 + tid] = mx;
    rst[(1 * 16 + lb) * 128 + tid] = s;
  } else if (tid >= 128 && tid < 228) {
    int j = tid - 128;
    const float* colp = ms + (long)lb * 128 * 128 + j;
    float mx = colp[0];
    for (int i = 1; i < 100; ++i) mx = fmaxf(mx, colp[i * 128]);
    float s = 0.f;
    for (int i = 0; i < 100; ++i) s += __expf(colp[i * 128] - mx);
    rst[(2 * 16 + lb) * 128 + j] = mx;
    rst[(3 * 16 + lb) * 128 + j] = s;
  }
}

// --- r1/r2 mixing + final channel softmax (one q-row per block) -------------
__global__ __launch_bounds__(256) void fuse_apply_kernel(const float* __restrict__ ms,
                                                         const float* __restrict__ rst,
                                                         const float* __restrict__ q1,
                                                         const float* __restrict__ q2,
                                                         const float* __restrict__ qsa,
                                                         float* __restrict__ qout) {
  __shared__ float pr[100], pc[100];
  __shared__ float red1[4], red2[4];
  int lb = blockIdx.x, i = blockIdx.y, tid = threadIdx.x;
  long r = lb * 100 + i;
  if (tid < 100) {
    float rm = rst[(0 * 16 + lb) * 128 + i], rs = rst[(1 * 16 + lb) * 128 + i];
    pr[tid] = __expf(ms[(long)(lb * 128 + i) * 128 + tid] - rm) / rs;
  } else if (tid >= 128 && tid < 228) {
    int i2 = tid - 128;
    float cm = rst[(2 * 16 + lb) * 128 + i], cs = rst[(3 * 16 + lb) * 128 + i];
    pc[i2] = __expf(ms[(long)(lb * 128 + i2) * 128 + i] - cm) / cs;
  }
  __syncthreads();
  float acc1 = 0.f, acc2 = 0.f;
  for (int j = 0; j < 100; ++j) acc1 = fmaf(pr[j], q2[(long)(lb * 100 + j) * 256 + tid], acc1);
  for (int j = 0; j < 100; ++j) acc2 = fmaf(pc[j], q1[(long)(lb * 100 + j) * 256 + tid], acc2);
  float z = qsa[r * 256 + tid] + q1[r * 256 + tid] + acc1 + q2[r * 256 + tid] + acc2;
  float v = z;
  for (int off = 32; off; off >>= 1) v = fmaxf(v, __shfl_xor(v, off));
  int w = tid >> 6;
  if ((tid & 63) == 0) red1[w] = v;
  __syncthreads();
  float zm = fmaxf(fmaxf(red1[0], red1[1]), fmaxf(red1[2], red1[3]));
  float e = __expf(z - zm);
  float sv = e;
  for (int off = 32; off; off >>= 1) sv += __shfl_xor(sv, off);
  if ((tid & 63) == 0) red2[w] = sv;
  __syncthreads();
  float es = red2[0] + red2[1] + red2[2] + red2[3];
  qout[r * 256 + tid] = e / es;
}

// ---------------------------------------------------------------------------
extern "C" void kernel_launch(void* const* d_in, const int* in_sizes, int n_in,
                              void* d_out, int out_size, void* d_ws, size_t ws_size,
                              hipStream_t stream) {
  (void)in_sizes; (void)n_in; (void)out_size; (void)ws_size;
  const float* feats[2][4] = {
      {(const float*)d_in[0], (const float*)d_in[1], (const float*)d_in[2], (const float*)d_in[3]},
      {(const float*)d_in[4], (const float*)d_in[5], (const float*)d_in[6], (const float*)d_in[7]}};
  const float* qe   = (const float*)d_in[8];
  const float* ng   = (const float*)d_in[9];
  const float* nb   = (const float*)d_in[10];
  const float* wq   = (const float*)d_in[11];
  const float* wk   = (const float*)d_in[12];
  const float* wv   = (const float*)d_in[13];
  const float* wp   = (const float*)d_in[14];
  const float* bp   = (const float*)d_in[15];
  const float* swqkv= (const float*)d_in[16];
  const float* swp  = (const float*)d_in[17];
  const float* sbp  = (const float*)d_in[18];

  float* ws = (float*)d_ws;
  unsigned short* KHp  = (unsigned short*)(ws + O_KH);
  unsigned short* KLp  = (unsigned short*)(ws + O_KL);
  unsigned short* VTHp = (unsigned short*)(ws + O_VTH);
  unsigned short* VTLp = (unsigned short*)(ws + O_VTL);
  float* QBUFp = ws + O_QBUF;
  float* QKVp  = ws + O_QKV;
  float* QSAp  = ws + O_QSA;
  float* QHATp = ws + O_QHAT;
  float* QNp   = ws + O_QN;
  float* SAOp  = ws + O_SAO;
  float* OCAp  = ws + O_OCA;
  float* Q12p  = ws + O_Q12;
  unsigned short* QHp  = (unsigned short*)(ws + O_QH);
  unsigned short* QLp  = (unsigned short*)(ws + O_QL);
  unsigned short* WTHp = (unsigned short*)(ws + O_WTH);
  unsigned short* WTLp = (unsigned short*)(ws + O_WTL);
  float* WQp   = ws + O_WQ;
  float* BKVp  = ws + O_BKV;
  float* BQp   = ws + O_BQ;
  float* POp   = ws + O_PO;
  float* PMp   = ws + O_PM;
  float* PLp   = ws + O_PL;
  float* PO2p  = ws + O_PO2;
  float* PM2p  = ws + O_PM2;
  float* PL2p  = ws + O_PL2;
  float* MSp   = ws + O_MS;
  float* RSTp  = ws + O_RST;
  float* STATSp= ws + O_STATS;
  unsigned short* XHp  = (unsigned short*)(ws + O_XH);
  unsigned short* XLp  = (unsigned short*)(ws + O_XL);

  const int HWs[4] = {4096, 1024, 256, 64};
  const int VOs[4] = {0, 16384, 20480, 21504};

  fold_w2_kernel<<<4608, 256, 0, stream>>>(ng, wk, wv, wq, WTHp, WTLp, WQp);
  fold_b_kernel<<<18, 256, 0, stream>>>(nb, wk, wv, wq, BKVp, BQp);
  for (int v = 0; v < 2; ++v)
    for (int l = 0; l < 4; ++l)
      ln_stats_kernel<<<dim3(HWs[l] / 64, 4), 256, 0, stream>>>(
          feats[v][l], STATSp, v * 21760 + VOs[l], HWs[l]);
  for (int v = 0; v < 2; ++v)
    ln_split_x_kernel<<<340, 256, 0, stream>>>(
        feats[v][0], feats[v][1], feats[v][2], feats[v][3], STATSp, v * 21760, XHp, XLp);
  init_q_kernel<<<1600, 256, 0, stream>>>(qe, QBUFp);

  const int4 saStart = make_int4(0, 32, 64, 96);
  const int4 saNch   = make_int4(1, 1, 1, 1);
  const int4 saNk    = make_int4(100, 100, 100, 100);
  const int4 saKoff  = make_int4(0, 400, 800, 1200);
  const int4 saKstrb = make_int4(100, 100, 100, 100);

  for (int d = 0; d < 6; ++d) {
    // --- self attention ---
    gemm256_kernel<<<dim3(12, 25), 256, 0, stream>>>(QBUFp, swqkv + (long)d * 196608, nullptr,
                                                     QKVp, 1600, 768);
    flash_kernel<<<128, 256, 0, stream>>>(QKVp, 768, QKVp + 256, QKVp + 512, 768,
                                          saStart, saNch, saNk, saKoff, saKstrb, POp, PMp, PLp);
    combine_kernel<<<dim3(128, 13), 256, 0, stream>>>(POp, PMp, PLp, saStart, saNch, SAOp, 256);
    gemm256_kernel<<<dim3(4, 25), 256, 0, stream>>>(SAOp, swp + (long)d * 65536, sbp + d * 256,
                                                    QSAp, 1600, 256);
    // --- cross-attention query projection + split ---
    row_ln_kernel<<<1600, 256, 0, stream>>>(QSAp, QHATp);
    gemm256_kernel<<<dim3(4, 25), 256, 0, stream>>>(QHATp, WQp + (long)d * 65536, BQp + d * 256,
                                                    QNp, 1600, 256);
    split_q_kernel<<<1632, 256, 0, stream>>>(QNp, QHp, QLp);
    // --- cross attention, both views per dispatch ---
    gemm_kv5_kernel<<<dim3(2, 340, 2), 256, 0, stream>>>(
        XHp, XLp, WTHp + (long)d * 131072, WTLp + (long)d * 131072, BKVp + d * 512,
        KHp, KLp, VTHp, VTLp);
    flash_ca2_kernel<<<768, 256, 0, stream>>>(QHp, QLp, KHp, KLp, VTHp, VTLp,
                                              PO2p, PM2p, PL2p);
    combine2_kernel<<<1024, 256, 0, stream>>>(PO2p, PM2p, PL2p, OCAp);
    gemm256_kernel<<<dim3(4, 50), 256, 0, stream>>>(OCAp, wp + (long)d * 65536, bp + d * 256,
                                                    Q12p, 3200, 256);
    // --- matching fusion + channel softmax ---
    fuse_ms_kernel<<<dim3(16, 16), 256, 0, stream>>>(Q12p, Q12p + 409600, MSp);
    fuse_stats_kernel<<<16, 256, 0, stream>>>(MSp, RSTp);
    fuse_apply_kernel<<<dim3(16, 100), 256, 0, stream>>>(MSp, RSTp, Q12p, Q12p + 409600,
                                                         QSAp, QBUFp);
  }
  hipMemcpyAsync(d_out, QBUFp, 409600 * sizeof(float), hipMemcpyDeviceToDevice, stream);
}